// Round 5
// baseline (1006.366 us; speedup 1.0000x reference)
//
#include <hip/hip_runtime.h>
#include <cstdint>
#include <cstddef>

#define HW 4096
#define CDIM 768
#define PPIX 4356   // 66*66 padded pixels

typedef unsigned short u16;
typedef __attribute__((ext_vector_type(8))) short short8;
typedef __attribute__((ext_vector_type(4))) float f32x4;

__device__ __forceinline__ float bf2f(u16 u) { return __uint_as_float(((unsigned)u) << 16); }
__device__ __forceinline__ u16 f2bf(float f) {
    unsigned u = __float_as_uint(f);
    unsigned r = (u + 0x7fffu + ((u >> 16) & 1u)) >> 16;
    return (u16)r;
}
__device__ __forceinline__ float lof(unsigned u) { return __uint_as_float(u << 16); }
__device__ __forceinline__ float hif(unsigned u) { return __uint_as_float(u & 0xffff0000u); }
__device__ __forceinline__ int swz(int r) { return ((r >> 1) ^ (r >> 3)) & 3; }

__device__ __forceinline__ void gl16(const u16* g, u16* l) {
    __builtin_amdgcn_global_load_lds(
        (const __attribute__((address_space(1))) unsigned int*)g,
        (__attribute__((address_space(3))) unsigned int*)l, 16, 0, 0);
}

enum GMode { G_CONV = 0, G_PROJ = 2, G_SPAT = 3 };

struct ProjP {
    const u16* b1[5];
    const u16* b2[5];
    int ch[5];
    int choff[5];
};

// ---------------------------------------------------------------- 128x128 GEMM
// m97-shape: single LDS buffer (16KB), 2 barriers/step, 4 blocks/CU.
// Used for PROJ / SPAT (small-N) only; conv moved to k_conv256.
template <int MODE>
__launch_bounds__(256, 4)
__global__ void k_gemm128(const u16* __restrict__ xpad, const u16* __restrict__ blkA,
                          const u16* __restrict__ Wt, const float* __restrict__ bias,
                          u16* __restrict__ outb, float* __restrict__ outf, ProjP pp) {
    const int z = blockIdx.z;
    const int m0 = blockIdx.x * 128;
    const int n0 = blockIdx.y * 128;

    int Nrows, ntap, choff = 0, ldo = CDIM;
    const u16 *Az = nullptr, *Ac = nullptr, *B1 = nullptr, *B2 = nullptr;
    if constexpr (MODE == G_CONV) {
        Az = xpad + (size_t)z * PPIX * CDIM; B1 = Wt; Nrows = 768; ntap = 9;
    } else if constexpr (MODE == G_PROJ) {
        Ac = blkA + (size_t)z * HW * CDIM;
        Az = xpad + (size_t)z * PPIX * CDIM;
        B1 = pp.b1[z]; B2 = pp.b2[z];
        Nrows = pp.ch[z]; choff = pp.choff[z];
        ntap = B2 ? 2 : 1;
        if (n0 >= Nrows) return;
    } else { // G_SPAT
        Ac = blkA; B1 = Wt; Nrows = 384; ntap = 1; ldo = 384;
    }

    __shared__ __align__(16) u16 As[128 * 32];
    __shared__ __align__(16) u16 Bs[128 * 32];

    const int t = threadIdx.x;
    const int lane = t & 63;
    const int wid = t >> 6;
    const int wrow = (wid >> 1) * 64, wcol = (wid & 1) * 64;
    const int lm = lane & 15;
    const int quad = lane >> 4;

    const int rS = t >> 2;
    const int cs0 = (t & 3) ^ swz(rS);
    const int cs1 = (t & 3) ^ swz(64 + rS);

    // A base pointers (element units)
    const u16 *a0 = nullptr, *a1 = nullptr, *a0x = nullptr, *a1x = nullptr;
    if constexpr (MODE == G_CONV) {
        int p0 = m0 + rS, p1 = m0 + 64 + rS;
        a0 = Az + (size_t)(((p0 >> 6)) * 66 + (p0 & 63)) * CDIM + cs0 * 8;
        a1 = Az + (size_t)(((p1 >> 6)) * 66 + (p1 & 63)) * CDIM + cs1 * 8;
    } else if constexpr (MODE == G_PROJ) {
        int p0 = m0 + rS, p1 = m0 + 64 + rS;
        a0 = Ac + (size_t)p0 * CDIM + cs0 * 8;
        a1 = Ac + (size_t)p1 * CDIM + cs1 * 8;
        a0x = Az + (size_t)(((p0 >> 6) + 1) * 66 + (p0 & 63) + 1) * CDIM + cs0 * 8;
        a1x = Az + (size_t)(((p1 >> 6) + 1) * 66 + (p1 & 63) + 1) * CDIM + cs1 * 8;
    } else {
        a0 = Ac + (size_t)(m0 + rS) * CDIM + cs0 * 8;
        a1 = Ac + (size_t)(m0 + 64 + rS) * CDIM + cs1 * 8;
    }
    // B base pointers
    const u16* b0 = B1 + (size_t)(n0 + rS) * CDIM + cs0 * 8;
    const u16* b1p = B1 + (size_t)(n0 + 64 + rS) * CDIM + cs1 * 8;
    const u16 *c0 = nullptr, *c1 = nullptr;
    if constexpr (MODE == G_PROJ) {
        if (B2) {
            c0 = B2 + (size_t)(n0 + rS) * CDIM + cs0 * 8;
            c1 = B2 + (size_t)(n0 + 64 + rS) * CDIM + cs1 * 8;
        }
    }

    u16* dA0 = &As[(0 * 4 + wid) * 512];
    u16* dA1 = &As[(1 * 4 + wid) * 512];
    u16* dB0 = &Bs[(0 * 4 + wid) * 512];
    u16* dB1 = &Bs[(1 * 4 + wid) * 512];

    f32x4 acc[4][4];
#pragma unroll
    for (int i = 0; i < 4; i++)
#pragma unroll
        for (int j = 0; j < 4; j++) acc[i][j] = (f32x4){0.f, 0.f, 0.f, 0.f};

    const int totS = ntap * 24;
    int tap = 0;
    int tA = 0, tB = 0, kO = 0;

    for (int s = 0; s < totS; ++s) {
        __syncthreads();
        if constexpr (MODE == G_CONV) {
            gl16(a0 + tA + kO, dA0);
            gl16(a1 + tA + kO, dA1);
            gl16(b0 + tB + kO, dB0);
            gl16(b1p + tB + kO, dB1);
        } else if constexpr (MODE == G_PROJ) {
            if (tap == 0) {
                gl16(a0 + kO, dA0);
                gl16(a1 + kO, dA1);
                gl16(b0 + kO, dB0);
                gl16(b1p + kO, dB1);
            } else {
                gl16(a0x + kO, dA0);
                gl16(a1x + kO, dA1);
                gl16(c0 + kO, dB0);
                gl16(c1 + kO, dB1);
            }
        } else {
            gl16(a0 + kO, dA0);
            gl16(a1 + kO, dA1);
            gl16(b0 + kO, dB0);
            gl16(b1p + kO, dB1);
        }
        __syncthreads();
        short8 af[4], bf[4];
#pragma unroll
        for (int i = 0; i < 4; i++) {
            int rr = wrow + i * 16 + lm;
            af[i] = *(const short8*)&As[rr * 32 + ((quad ^ swz(rr)) * 8)];
        }
#pragma unroll
        for (int j = 0; j < 4; j++) {
            int rr = wcol + j * 16 + lm;
            bf[j] = *(const short8*)&Bs[rr * 32 + ((quad ^ swz(rr)) * 8)];
        }
#pragma unroll
        for (int i = 0; i < 4; i++)
#pragma unroll
            for (int j = 0; j < 4; j++)
                acc[i][j] = __builtin_amdgcn_mfma_f32_16x16x32_bf16(af[i], bf[j], acc[i][j], 0, 0, 0);
        // advance (tap fastest, then kk)
        tap++;
        if constexpr (MODE == G_CONV) {
            tA += (tap == 3 || tap == 6) ? 64 * CDIM : CDIM;
            tB += CDIM * CDIM;
            if (tap == 9) { tap = 0; tA = 0; tB = 0; kO += 32; }
        } else {
            if (tap == ntap) { tap = 0; kO += 32; }
        }
    }

    // ---- epilogue ----
    if constexpr (MODE == G_CONV) {
        u16* outz = outb + (size_t)z * HW * CDIM;
#pragma unroll
        for (int j = 0; j < 4; j++) {
            int gc = n0 + wcol + j * 16 + lm;
            float bv = bias[gc];
#pragma unroll
            for (int i = 0; i < 4; i++)
#pragma unroll
                for (int r = 0; r < 4; r++) {
                    int gr = m0 + wrow + i * 16 + quad * 4 + r;
                    outz[(size_t)gr * CDIM + gc] = f2bf(acc[i][j][r] + bv);
                }
        }
    } else {
#pragma unroll
        for (int j = 0; j < 4; j++) {
            int gc = n0 + wcol + j * 16 + lm;
            if (gc < Nrows) {
#pragma unroll
                for (int i = 0; i < 4; i++)
#pragma unroll
                    for (int r = 0; r < 4; r++) {
                        int gr = m0 + wrow + i * 16 + quad * 4 + r;
                        outf[(size_t)gr * ldo + choff + gc] = acc[i][j][r];
                    }
            }
        }
    }
}

// ---------------------------------------------------------------- conv GEMM (128x256, dbuf)
// Same pipeline shape as k_gdef: 512 thr, 8 waves (2x4), 1 barrier/step,
// double-buffered LDS, all staging via global_load_lds width-16.
__launch_bounds__(512, 4)
__global__ void k_conv256(const u16* __restrict__ xpad, const u16* __restrict__ Wt,
                          const float* __restrict__ bias, u16* __restrict__ outb) {
    const int z = blockIdx.z;
    const int m0 = blockIdx.x * 128;
    const int n0 = blockIdx.y * 256;
    const u16* Az = xpad + (size_t)z * PPIX * CDIM;

    __shared__ __align__(16) u16 As[2][128 * 32];
    __shared__ __align__(16) u16 Bs[2][256 * 32];

    const int t = threadIdx.x;
    const int lane = t & 63;
    const int wid = t >> 6;
    const int wrow = (wid >> 2) * 64, wcol = (wid & 3) * 64;
    const int lm = lane & 15;
    const int quad = lane >> 4;

    const int rA = t >> 2;
    const int cA = (t & 3) ^ swz(rA);
    const int rB0 = t >> 2;
    const int cB0 = (t & 3) ^ swz(rB0);
    const int rB1 = 128 + (t >> 2);
    const int cB1 = (t & 3) ^ swz(rB1);

    // A per-lane base at tap 0: pixel p -> padded idx (p>>6)*66 + (p&63)
    const int p0 = m0 + rA;
    const u16* aB = Az + (size_t)((p0 >> 6) * 66 + (p0 & 63)) * CDIM + cA * 8;
    const u16* bB0 = Wt + (size_t)(n0 + rB0) * CDIM + cB0 * 8;
    const u16* bB1 = Wt + (size_t)(n0 + rB1) * CDIM + cB1 * 8;

    f32x4 acc[4][4];
#pragma unroll
    for (int i = 0; i < 4; i++)
#pragma unroll
        for (int j = 0; j < 4; j++) acc[i][j] = (f32x4){0.f, 0.f, 0.f, 0.f};

    // prologue: stage step 0 (tap 0, k 0) into buf 0
    gl16(aB, &As[0][wid * 512]);
    gl16(bB0, &Bs[0][wid * 512]);
    gl16(bB1, &Bs[0][4096 + wid * 512]);

    int tap = 0, tA = 0, tB = 0, kO = 0;

    for (int s = 0; s < 216; ++s) {
        const int cur = s & 1;
        const int nxt = cur ^ 1;
        __syncthreads();
        const bool hasN = (s + 1 < 216);
        if (hasN) {
            // advance to step s+1 (tap fastest, then kk)
            tap++;
            tA += (tap == 3 || tap == 6) ? 64 * CDIM : CDIM;
            tB += CDIM * CDIM;
            if (tap == 9) { tap = 0; tA = 0; tB = 0; kO += 32; }
            gl16(aB + tA + kO, &As[nxt][wid * 512]);
            gl16(bB0 + tB + kO, &Bs[nxt][wid * 512]);
            gl16(bB1 + tB + kO, &Bs[nxt][4096 + wid * 512]);
        }
        short8 af[4];
#pragma unroll
        for (int i = 0; i < 4; i++) {
            int rr = wrow + i * 16 + lm;
            af[i] = *(const short8*)&As[cur][rr * 32 + ((quad ^ swz(rr)) * 8)];
        }
#pragma unroll
        for (int j = 0; j < 4; j++) {
            int rr = wcol + j * 16 + lm;
            short8 bf = *(const short8*)&Bs[cur][rr * 32 + ((quad ^ swz(rr)) * 8)];
#pragma unroll
            for (int i = 0; i < 4; i++)
                acc[i][j] = __builtin_amdgcn_mfma_f32_16x16x32_bf16(af[i], bf, acc[i][j], 0, 0, 0);
        }
    }

    u16* outz = outb + (size_t)z * HW * CDIM;
#pragma unroll
    for (int j = 0; j < 4; j++) {
        int gc = n0 + wcol + j * 16 + lm;
        float bv = bias[gc];
#pragma unroll
        for (int i = 0; i < 4; i++)
#pragma unroll
            for (int r = 0; r < 4; r++) {
                int gr = m0 + wrow + i * 16 + quad * 4 + r;
                outz[(size_t)gr * CDIM + gc] = f2bf(acc[i][j][r] + bv);
            }
    }
}

// ---------------------------------------------------------------- deform GEMM (128x256, K-split dbuf)
// R1-proven per-step schedule (scalar fmaf blend + v_perm pack, linear t*8
// As write, 32-elem rows) — do NOT restructure the blend dataflow (R3 lesson).
// K split into 2 halves (9 taps x 12 kk each, 108 steps) -> 960 blocks ->
// 3 blocks/CU resident (was grid-limited at 1.875). Halves write f32
// partials ph0/ph1; bias folded into half 0; sum folded into bn kernels.
__launch_bounds__(512, 4)
__global__ void k_gdef(const u16* __restrict__ xpad, const u16* __restrict__ Wt,
                       const int4* __restrict__ idx4, const float4* __restrict__ w4,
                       const float* __restrict__ bias, float* __restrict__ ph0,
                       float* __restrict__ ph1) {
    const int z = blockIdx.z;
    const int half = blockIdx.x >> 5;
    const int m0 = (blockIdx.x & 31) * 128;
    const int n0 = blockIdx.y * 256;
    const int kB = half * 768;   // byte offset into each gather row (12 chunks * 64B)
    const int kE = half * 384;   // element offset into B rows
    const u16* Az = xpad + (size_t)z * PPIX * CDIM;
    const int4* idxz = idx4 + (size_t)z * 9 * 4096;
    const float4* w4z = w4 + (size_t)z * 9 * 4096;

    __shared__ __align__(16) u16 As[2][128 * 32];
    __shared__ __align__(16) u16 Bs[2][256 * 32];

    const int t = threadIdx.x;
    const int lane = t & 63;
    const int wid = t >> 6;
    const int wrow = (wid >> 2) * 64, wcol = (wid & 3) * 64;
    const int lm = lane & 15;
    const int quad = lane >> 4;

    // staging coords: one 8-elem chunk of A per thread, two of B
    const int rA = t >> 2;
    const int cA = (t & 3) ^ swz(rA);
    const int rB0 = t >> 2;
    const int cB0 = (t & 3) ^ swz(rB0);
    const int rB1 = 128 + (t >> 2);
    const int cB1 = (t & 3) ^ swz(rB1);

    f32x4 acc[4][4];
#pragma unroll
    for (int i = 0; i < 4; i++)
#pragma unroll
        for (int j = 0; j < 4; j++) acc[i][j] = (f32x4){0.f, 0.f, 0.f, 0.f};

    const u16* bP0;
    const u16* bP1;
    int dOff[4];
    float4 wv;

    auto setupSub = [&](int sn) {
        const u16* Bb = Wt + (size_t)sn * CDIM * CDIM;
        bP0 = Bb + (size_t)(n0 + rB0) * CDIM + cB0 * 8;
        bP1 = Bb + (size_t)(n0 + rB1) * CDIM + cB1 * 8;
        int4 iv = idxz[sn * 4096 + m0 + rA];
        wv = w4z[sn * 4096 + m0 + rA];
        dOff[0] = (iv.x + cA * 8) * 2;
        dOff[1] = (iv.y + cA * 8) * 2;
        dOff[2] = (iv.z + cA * 8) * 2;
        dOff[3] = (iv.w + cA * 8) * 2;
    };

    auto blend4 = [&](const uint4* L) -> uint4 {
        auto bl = [&](unsigned a, unsigned b, unsigned c2, unsigned d) -> unsigned {
            float lo = fmaf(wv.x, lof(a), fmaf(wv.y, lof(b), fmaf(wv.z, lof(c2), wv.w * lof(d))));
            float hi = fmaf(wv.x, hif(a), fmaf(wv.y, hif(b), fmaf(wv.z, hif(c2), wv.w * hif(d))));
            // dst = (hi & 0xffff0000) | (lo >> 16) in one v_perm_b32
            return __builtin_amdgcn_perm(__float_as_uint(hi), __float_as_uint(lo), 0x07060302u);
        };
        uint4 o;
        o.x = bl(L[0].x, L[1].x, L[2].x, L[3].x);
        o.y = bl(L[0].y, L[1].y, L[2].y, L[3].y);
        o.z = bl(L[0].z, L[1].z, L[2].z, L[3].z);
        o.w = bl(L[0].w, L[1].w, L[2].w, L[3].w);
        return o;
    };

    setupSub(0);
    int stagedSub = 0;

    {   // prologue: stage step 0 (tap 0, kn 0 of this half) into buf 0
        uint4 L[4];
#pragma unroll
        for (int k = 0; k < 4; k++)
            L[k] = *(const uint4*)((const char*)Az + dOff[k] + kB);
        gl16(bP0 + kE, &Bs[0][wid * 512]);
        gl16(bP1 + kE, &Bs[0][4096 + wid * 512]);
        uint4 o = blend4(L);
        *(uint4*)&As[0][t * 8] = o;
    }

    for (int s = 0; s < 108; ++s) {
        const int cur = s & 1;
        const int nxt = cur ^ 1;
        __syncthreads();
        const bool hasN = (s + 1 < 108);
        uint4 L[4];
        if (hasN) {
            int kn = (s + 1) - stagedSub * 12;
            if (kn == 12) { setupSub(++stagedSub); kn = 0; }
            const int cb = kB + kn * 64;  // byte advance along K
#pragma unroll
            for (int k = 0; k < 4; k++)
                L[k] = *(const uint4*)((const char*)Az + dOff[k] + cb);
            gl16(bP0 + kE + kn * 32, &Bs[nxt][wid * 512]);
            gl16(bP1 + kE + kn * 32, &Bs[nxt][4096 + wid * 512]);
        }
        short8 af[4];
#pragma unroll
        for (int i = 0; i < 4; i++) {
            int rr = wrow + i * 16 + lm;
            af[i] = *(const short8*)&As[cur][rr * 32 + ((quad ^ swz(rr)) * 8)];
        }
#pragma unroll
        for (int j = 0; j < 4; j++) {
            int rr = wcol + j * 16 + lm;
            short8 bf = *(const short8*)&Bs[cur][rr * 32 + ((quad ^ swz(rr)) * 8)];
#pragma unroll
            for (int i = 0; i < 4; i++)
                acc[i][j] = __builtin_amdgcn_mfma_f32_16x16x32_bf16(af[i], bf, acc[i][j], 0, 0, 0);
        }
        if (hasN) {
            uint4 o = blend4(L);
            *(uint4*)&As[nxt][t * 8] = o;
        }
    }

    float* outz = (half ? ph1 : ph0) + (size_t)z * HW * CDIM;
#pragma unroll
    for (int j = 0; j < 4; j++) {
        int gc = n0 + wcol + j * 16 + lm;
        float bv = half ? 0.f : bias[gc];
#pragma unroll
        for (int i = 0; i < 4; i++)
#pragma unroll
            for (int r = 0; r < 4; r++) {
                int gr = m0 + wrow + i * 16 + quad * 4 + r;
                outz[(size_t)gr * CDIM + gc] = acc[i][j][r] + bv;
            }
    }
}

// ---------------------------------------------------------------- prep kernels
struct Ptr5 { const float* p[5]; };

__global__ void k_prep_xpad(Ptr5 xs, u16* __restrict__ xpad) {
    int z = blockIdx.y;
    int pidx = blockIdx.x;
    int ph = pidx / 66, pw = pidx - ph * 66;
    int e0 = threadIdx.x * 4;
    u16* d = xpad + ((size_t)z * PPIX + pidx) * CDIM + e0;
    if (ph == 0 || ph == 65 || pw == 0 || pw == 65) {
        *(uint2*)d = make_uint2(0, 0);
        return;
    }
    const float* s = xs.p[z] + ((size_t)((ph - 1) * 64 + (pw - 1))) * CDIM + e0;
    float4 v = *(const float4*)s;
    u16 o[4] = {f2bf(v.x), f2bf(v.y), f2bf(v.z), f2bf(v.w)};
    *(uint2*)d = *(uint2*)o;
}

__global__ void k_prep_wt(const float* __restrict__ cw, u16* __restrict__ Wt) {
    int o = blockIdx.x;
    for (int c = threadIdx.x; c < 768; c += 256) {
        const float* s = cw + ((size_t)o * 768 + c) * 9;
#pragma unroll
        for (int k = 0; k < 9; k++)
            Wt[(size_t)k * 768 * 768 + (size_t)o * 768 + c] = f2bf(s[k]);
    }
}

struct WbP { const float* src[9]; u16* dst[9]; int n[9]; };

__global__ void k_prep_wb(WbP wp) {
    int m = blockIdx.y;
    int i = (blockIdx.x * 256 + threadIdx.x) * 4;
    if (i >= wp.n[m]) return;
    float4 v = *(const float4*)(wp.src[m] + i);
    u16* d = wp.dst[m] + i;
    d[0] = f2bf(v.x); d[1] = f2bf(v.y); d[2] = f2bf(v.z); d[3] = f2bf(v.w);
}

// ---------------------------------------------------------------- offset / mask
// 4 pixels per wave (weights loaded once, shared across 4 dot products) ->
// weight L2 traffic /4 (was L2-BW bound: 83KB x 20480 waves ~ 1.7GB).
__global__ void k_offmask1(const u16* __restrict__ om, const float* __restrict__ off_w,
                           const float* __restrict__ off_b, const float* __restrict__ msk_w,
                           const float* __restrict__ msk_b, float* __restrict__ offs,
                           float* __restrict__ msoft) {
    int z = blockIdx.y;
    int wid = threadIdx.x >> 6, lane = threadIdx.x & 63;
    int p0 = blockIdx.x * 16 + wid * 4;
    const u16* rbase = om + (size_t)z * HW * CDIM + (size_t)p0 * CDIM;
    float v[4][12];
#pragma unroll
    for (int pp = 0; pp < 4; pp++)
#pragma unroll
        for (int j = 0; j < 12; j++) v[pp][j] = bf2f(rbase[pp * CDIM + lane + 64 * j]);
    float lg[4][9];
    for (int qq = 0; qq < 27; qq++) {
        const float* wr = (qq < 18) ? (off_w + qq * 768) : (msk_w + (qq - 18) * 768);
        float w[12];
#pragma unroll
        for (int j = 0; j < 12; j++) w[j] = wr[lane + 64 * j];
        float s[4] = {0.f, 0.f, 0.f, 0.f};
#pragma unroll
        for (int pp = 0; pp < 4; pp++)
#pragma unroll
            for (int j = 0; j < 12; j++) s[pp] = fmaf(v[pp][j], w[j], s[pp]);
#pragma unroll
        for (int pp = 0; pp < 4; pp++)
#pragma unroll
            for (int o = 32; o > 0; o >>= 1) s[pp] += __shfl_xor(s[pp], o, 64);
        if (qq < 18) {
            if (lane == qq) {
#pragma unroll
                for (int pp = 0; pp < 4; pp++)
                    offs[((size_t)z * HW + p0 + pp) * 18 + qq] = s[pp] + off_b[qq];
            }
        } else {
#pragma unroll
            for (int pp = 0; pp < 4; pp++) lg[pp][qq - 18] = s[pp] + msk_b[qq - 18];
        }
    }
#pragma unroll
    for (int pp = 0; pp < 4; pp++) {
        float mx = -1e30f;
#pragma unroll
        for (int j = 0; j < 9; j++) mx = fmaxf(mx, lg[pp][j]);
        float sum = 0.f;
#pragma unroll
        for (int j = 0; j < 9; j++) { lg[pp][j] = expf(lg[pp][j] - mx); sum += lg[pp][j]; }
        float inv = 1.f / sum;
#pragma unroll
        for (int j = 0; j < 9; j++)
            if (lane == j) msoft[(size_t)z * 36864 + (p0 + pp) * 9 + j] = lg[pp][j] * inv;
    }
}

__device__ __forceinline__ int cidx(int y, int x) {
    int yc = min(max(y, 0), 63), xc = min(max(x, 0), 63);
    return ((yc + 1) * 66 + (xc + 1)) * CDIM;
}
__device__ __forceinline__ float cval(int y, int x) {
    return (y >= 0 && y < 64 && x >= 0 && x < 64) ? 1.f : 0.f;
}

__global__ void k_offmask2(const float* __restrict__ offs, const float* __restrict__ msoft,
                           int4* __restrict__ idx4o, float4* __restrict__ w4o) {
    int id = blockIdx.x * 256 + threadIdx.x;
    int z = id / 36864, r = id % 36864, k = r >> 12, p = r & 4095;
    const float* ofz = offs + ((size_t)z * HW + p) * 18;
    float dy = ofz[2 * k], dx = ofz[2 * k + 1];
    float mk = msoft[(size_t)z * 36864 + k * 4096 + p];
    int h = p >> 6, w = p & 63;
    float py = (float)(h - 1 + k / 3) + dy;
    float px = (float)(w - 1 + k % 3) + dx;
    float y0f = floorf(py), x0f = floorf(px);
    int y0 = (int)y0f, x0 = (int)x0f;
    float wy1 = py - y0f, wx1 = px - x0f, wy0 = 1.f - wy1, wx0 = 1.f - wx1;
    idx4o[id] = make_int4(cidx(y0, x0), cidx(y0, x0 + 1), cidx(y0 + 1, x0), cidx(y0 + 1, x0 + 1));
    w4o[id] = make_float4(wy0 * wx0 * cval(y0, x0) * mk, wy0 * wx1 * cval(y0, x0 + 1) * mk,
                          wy1 * wx0 * cval(y0 + 1, x0) * mk, wy1 * wx1 * cval(y0 + 1, x0 + 1) * mk);
}

// ---------------------------------------------------------------- batchnorm
// reads f32 partial halves ph0+ph1 (sum folded in), float4 loads,
// LDS reduce -> per-segment partials; k_bnfinal sums 4 segs.
__global__ void k_bnstats2(const float* __restrict__ ph0, const float* __restrict__ ph1,
                           float* __restrict__ pb1, float* __restrict__ pb2) {
    const int z = blockIdx.z, seg = blockIdx.y;
    const int cx = threadIdx.x & 7, py = threadIdx.x >> 3;   // 8 cx x 32 py
    const int c0 = blockIdx.x * 64 + cx * 8;
    const float* b0 = ph0 + ((size_t)z * HW + seg * 1024) * CDIM + c0;
    const float* b1 = ph1 + ((size_t)z * HW + seg * 1024) * CDIM + c0;
    float s1[8] = {0.f, 0.f, 0.f, 0.f, 0.f, 0.f, 0.f, 0.f};
    float s2[8] = {0.f, 0.f, 0.f, 0.f, 0.f, 0.f, 0.f, 0.f};
    for (int p = py; p < 1024; p += 32) {
        float4 x0 = *(const float4*)(b0 + (size_t)p * CDIM);
        float4 x1 = *(const float4*)(b0 + (size_t)p * CDIM + 4);
        float4 y0 = *(const float4*)(b1 + (size_t)p * CDIM);
        float4 y1 = *(const float4*)(b1 + (size_t)p * CDIM + 4);
        float f[8] = {x0.x + y0.x, x0.y + y0.y, x0.z + y0.z, x0.w + y0.w,
                      x1.x + y1.x, x1.y + y1.y, x1.z + y1.z, x1.w + y1.w};
#pragma unroll
        for (int e = 0; e < 8; e++) { s1[e] += f[e]; s2[e] += f[e] * f[e]; }
    }
    __shared__ float l1[32][64], l2[32][64];
#pragma unroll
    for (int e = 0; e < 8; e++) {
        l1[py][cx * 8 + e] = s1[e];
        l2[py][cx * 8 + e] = s2[e];
    }
    __syncthreads();
    if (threadIdx.x < 64) {
        float a = 0.f, b = 0.f;
        for (int y = 0; y < 32; y++) { a += l1[y][threadIdx.x]; b += l2[y][threadIdx.x]; }
        int ch = blockIdx.x * 64 + threadIdx.x;
        pb1[(z * 4 + seg) * 768 + ch] = a;
        pb2[(z * 4 + seg) * 768 + ch] = b;
    }
}

__global__ void k_bnfinal(const float* __restrict__ pb1, const float* __restrict__ pb2,
                          float* __restrict__ mu, float* __restrict__ rs) {
    int i = blockIdx.x * 256 + threadIdx.x;
    if (i >= 3840) return;
    int z = i / 768, ch = i % 768;
    float a = 0.f, b = 0.f;
#pragma unroll
    for (int s = 0; s < 4; s++) {
        a += pb1[(z * 4 + s) * 768 + ch];
        b += pb2[(z * 4 + s) * 768 + ch];
    }
    float m = a / 4096.f;
    float var = b / 4096.f - m * m;
    mu[i] = m;
    rs[i] = rsqrtf(var + 1e-5f);
}

__global__ void k_bnapply(const float* __restrict__ ph0, const float* __restrict__ ph1,
                          const float* __restrict__ mu, const float* __restrict__ rs,
                          const float* __restrict__ g, const float* __restrict__ b,
                          u16* __restrict__ blk) {
    size_t i = ((size_t)blockIdx.x * 256 + threadIdx.x) * 8;
    int c = (int)(i % CDIM);
    int z = (int)(i / ((size_t)HW * CDIM));
    const float* muz = mu + z * 768;
    const float* rsz = rs + z * 768;
    float4 x0 = *(const float4*)(ph0 + i);
    float4 x1 = *(const float4*)(ph0 + i + 4);
    float4 y0 = *(const float4*)(ph1 + i);
    float4 y1 = *(const float4*)(ph1 + i + 4);
    float f[8] = {x0.x + y0.x, x0.y + y0.y, x0.z + y0.z, x0.w + y0.w,
                  x1.x + y1.x, x1.y + y1.y, x1.z + y1.z, x1.w + y1.w};
    u16 o[8];
#pragma unroll
    for (int e = 0; e < 8; e++) {
        int ce = c + e;
        float v = (f[e] - muz[ce]) * rsz[ce] * g[ce] + b[ce];
        o[e] = f2bf(fmaxf(v, 0.f));
    }
    *(uint4*)(blk + i) = *(uint4*)o;
}

// ---------------------------------------------------------------- CAM
__global__ void k_q(const float* __restrict__ X, const float* __restrict__ chq,
                    float* __restrict__ q) {
    int wid = threadIdx.x >> 6, lane = threadIdx.x & 63;
    int p = blockIdx.x * 4 + wid;
    const float* xr = X + (size_t)p * CDIM;
    float s = 0.f;
#pragma unroll
    for (int j = 0; j < 12; j++) s += xr[lane + 64 * j] * chq[lane + 64 * j];
#pragma unroll
    for (int o = 32; o > 0; o >>= 1) s += __shfl_xor(s, o, 64);
    if (lane == 0) q[p] = s;
}

__global__ void k_soft4096(const float* __restrict__ q, float* __restrict__ sqn,
                           float* __restrict__ xq) {
    __shared__ float red[4];
    int tid = threadIdx.x, lane = tid & 63, wid = tid >> 6;
    float m = -1e30f;
    for (int i = tid; i < 4096; i += 256) m = fmaxf(m, q[i]);
    for (int o = 32; o > 0; o >>= 1) m = fmaxf(m, __shfl_xor(m, o, 64));
    if (lane == 0) red[wid] = m;
    __syncthreads();
    float bm = fmaxf(fmaxf(red[0], red[1]), fmaxf(red[2], red[3]));
    __syncthreads();
    float s = 0.f;
    for (int i = tid; i < 4096; i += 256) {
        float e = expf(q[i] - bm);
        sqn[i] = e; s += e;
    }
    for (int o = 32; o > 0; o >>= 1) s += __shfl_xor(s, o, 64);
    if (lane == 0) red[wid] = s;
    __syncthreads();
    float inv = 1.f / (red[0] + red[1] + red[2] + red[3]);
    for (int i = tid; i < 4096; i += 256) sqn[i] *= inv;
    for (int c = tid; c < 768; c += 256) xq[c] = 0.f;
}

__global__ void k_xq(const float* __restrict__ X, const float* __restrict__ sqn,
                     float* __restrict__ xq) {
    int p0 = blockIdx.x * 128;
    for (int c = threadIdx.x; c < 768; c += 256) {
        float a = 0.f;
        for (int p = p0; p < p0 + 128; p++) a += sqn[p] * X[(size_t)p * CDIM + c];
        atomicAdd(&xq[c], a);
    }
}

// wvq[o] = chv[o][:] . xq   (384 rows, wave per row)
__global__ void k_gemv384(const float* __restrict__ chv, const float* __restrict__ xq,
                          float* __restrict__ wvq) {
    int wid = threadIdx.x >> 6, lane = threadIdx.x & 63;
    int o = blockIdx.x * 4 + wid;
    const float* r = chv + (size_t)o * 768;
    float s = 0.f;
#pragma unroll
    for (int j = 0; j < 12; j++) s += r[lane + 64 * j] * xq[lane + 64 * j];
#pragma unroll
    for (int off = 32; off > 0; off >>= 1) s += __shfl_xor(s, off, 64);
    if (lane == 0) wvq[o] = s;
}

// wzv[c] = chz[c][:] . wvq   (768 rows, wave per row)
__global__ void k_gemv768(const float* __restrict__ chz, const float* __restrict__ wvq,
                          float* __restrict__ wzv) {
    int wid = threadIdx.x >> 6, lane = threadIdx.x & 63;
    int c = blockIdx.x * 4 + wid;
    const float* r = chz + (size_t)c * 384;
    float s = 0.f;
#pragma unroll
    for (int j = 0; j < 6; j++) s += r[lane + 64 * j] * wvq[lane + 64 * j];
#pragma unroll
    for (int off = 32; off > 0; off >>= 1) s += __shfl_xor(s, off, 64);
    if (lane == 0) wzv[c] = s;
}

// LN(768) + sigmoid -> sgate
__global__ void k_lngate(const float* __restrict__ wzv, const float* __restrict__ lng,
                         const float* __restrict__ lnb, float* __restrict__ sgate) {
    __shared__ float red[8];
    int tid = threadIdx.x, lane = tid & 63, wid = tid >> 6;
    float a = wzv[tid], b = wzv[tid + 256], c = wzv[tid + 512];
    float s1 = a + b + c, s2 = a * a + b * b + c * c;
    for (int o = 32; o > 0; o >>= 1) { s1 += __shfl_xor(s1, o, 64); s2 += __shfl_xor(s2, o, 64); }
    if (lane == 0) { red[wid] = s1; red[4 + wid] = s2; }
    __syncthreads();
    s1 = red[0] + red[1] + red[2] + red[3];
    s2 = red[4] + red[5] + red[6] + red[7];
    float mean = s1 / 768.f, var = s2 / 768.f - mean * mean, rstd = rsqrtf(var + 1e-5f);
    for (int cc = tid; cc < 768; cc += 256) {
        float tv = (wzv[cc] - mean) * rstd * lng[cc] + lnb[cc];
        sgate[cc] = 1.f / (1.f + expf(-tv));
    }
}

__global__ void k_xatt(const float* __restrict__ X, const float* __restrict__ sgate,
                       u16* __restrict__ xatt) {
    size_t i = ((size_t)blockIdx.x * 256 + threadIdx.x) * 4;
    int c = (int)(i % CDIM);
    float4 v = *(const float4*)(X + i);
    u16 o[4] = {f2bf(v.x * sgate[c]), f2bf(v.y * sgate[c + 1]),
                f2bf(v.z * sgate[c + 2]), f2bf(v.w * sgate[c + 3])};
    *(uint2*)(xatt + i) = *(uint2*)o;
}

// column max over P2[4096][384] — 24 blocks x 16 cols, coalesced
__global__ void k_colmax24(const float* __restrict__ P2, float* __restrict__ m2) {
    __shared__ float red[16][17];
    int col = blockIdx.x * 16 + threadIdx.x;
    float m = -1e30f;
    for (int p = threadIdx.y; p < 4096; p += 16) m = fmaxf(m, P2[(size_t)p * 384 + col]);
    red[threadIdx.y][threadIdx.x] = m;
    __syncthreads();
    if (threadIdx.y == 0) {
        for (int y = 1; y < 16; y++) m = fmaxf(m, red[y][threadIdx.x]);
        m2[col] = m;
    }
}

// softmax over 384 -> sq2
__global__ void k_sm384(const float* __restrict__ m2, float* __restrict__ sq2) {
    __shared__ float red[6];
    int tid = threadIdx.x, lane = tid & 63, wid = tid >> 6;
    float v = m2[tid];
    float m = v;
    for (int o = 32; o > 0; o >>= 1) m = fmaxf(m, __shfl_xor(m, o, 64));
    if (lane == 0) red[wid] = m;
    __syncthreads();
    m = red[0];
    for (int w = 1; w < 6; w++) m = fmaxf(m, red[w]);
    __syncthreads();
    float e = expf(v - m);
    float s = e;
    for (int o = 32; o > 0; o >>= 1) s += __shfl_xor(s, o, 64);
    if (lane == 0) red[wid] = s;
    __syncthreads();
    float tot = 0.f;
    for (int w = 0; w < 6; w++) tot += red[w];
    sq2[tid] = e / tot;
}

// sv[c] = sum_o sq2[o] * spv[o][c]  — 12 blocks x 64 cols, 4-way o-split
__global__ void k_sv(const float* __restrict__ sq2, const float* __restrict__ spv,
                     float* __restrict__ sv) {
    __shared__ float part[4][64];
    int c = blockIdx.x * 64 + (threadIdx.x & 63);
    int seg = threadIdx.x >> 6;
    float a = 0.f;
    for (int o = seg * 96; o < seg * 96 + 96; o++) a += sq2[o] * spv[(size_t)o * 768 + c];
    part[seg][threadIdx.x & 63] = a;
    __syncthreads();
    if (seg == 0) sv[c] = part[0][threadIdx.x] + part[1][threadIdx.x] +
                          part[2][threadIdx.x] + part[3][threadIdx.x];
}

__global__ void k_final(const float* __restrict__ X, const float* __restrict__ x5,
                        const float* __restrict__ sgate, const float* __restrict__ sv,
                        const float* __restrict__ ng, const float* __restrict__ nb,
                        float* __restrict__ out) {
    int wid = threadIdx.x >> 6, lane = threadIdx.x & 63;
    int p = blockIdx.x * 4 + wid;
    const float* xr = X + (size_t)p * CDIM;
    const float* x5r = x5 + (size_t)p * CDIM;
    float xa[12];
    float d = 0.f;
#pragma unroll
    for (int j = 0; j < 12; j++) {
        int c = lane + 64 * j;
        float a = xr[c] * sgate[c];
        xa[j] = a;
        d += sv[c] * a;
    }
#pragma unroll
    for (int o = 32; o > 0; o >>= 1) d += __shfl_xor(d, o, 64);
    float wz2 = 1.f / (1.f + expf(-d));
    float s1 = 0.f, s2 = 0.f;
#pragma unroll
    for (int j = 0; j < 12; j++) {
        int c = lane + 64 * j;
        float y = wz2 * xa[j] + xr[c] + x5r[c];
        xa[j] = y;
        s1 += y; s2 += y * y;
    }
#pragma unroll
    for (int o = 32; o > 0; o >>= 1) { s1 += __shfl_xor(s1, o, 64); s2 += __shfl_xor(s2, o, 64); }
    float mean = s1 / 768.f, var = s2 / 768.f - mean * mean, rstd = rsqrtf(var + 1e-5f);
#pragma unroll
    for (int j = 0; j < 12; j++) {
        int c = lane + 64 * j;
        out[(size_t)p * CDIM + c] = (xa[j] - mean) * rstd * ng[c] + nb[c];
    }
}

// ---------------------------------------------------------------- launch
extern "C" void kernel_launch(void* const* d_in, const int* in_sizes, int n_in,
                              void* d_out, int out_size, void* d_ws, size_t ws_size,
                              hipStream_t stream) {
    const float* xin[5];
    for (int i = 0; i < 5; i++) xin[i] = (const float*)d_in[i];
    const float* conv_w = (const float*)d_in[5];
    const float* conv_b = (const float*)d_in[6];
    const float* off_w = (const float*)d_in[7];
    const float* off_b = (const float*)d_in[8];
    const float* msk_w = (const float*)d_in[9];
    const float* msk_b = (const float*)d_in[10];
    const float* bn_g = (const float*)d_in[11];
    const float* bn_b = (const float*)d_in[12];
    const float* chq_w = (const float*)d_in[13];
    const float* chv_w = (const float*)d_in[14];
    const float* chz_w = (const float*)d_in[15];
    const float* ln_g = (const float*)d_in[16];
    const float* ln_b = (const float*)d_in[17];
    const float* spq_w = (const float*)d_in[18];
    const float* spv_w = (const float*)d_in[19];
    const float* wsrc[8];
    for (int i = 0; i < 8; i++) wsrc[i] = (const float*)d_in[20 + i];
    const float* norm_g = (const float*)d_in[28];
    const float* norm_b = (const float*)d_in[29];
    float* out = (float*)d_out;

    char* wsb = (char*)d_ws;
    size_t off = 0;
    auto take = [&](size_t n) -> char* {
        char* p = wsb + off;
        off = (off + n + 255) & ~(size_t)255;
        return p;
    };
    u16* xpad = (u16*)take(5ll * PPIX * CDIM * 2);
    u16* Wt = (u16*)take(9ll * CDIM * CDIM * 2);
    u16* omblk = (u16*)take(5ll * HW * CDIM * 2);
    float* offs = (float*)take(5ll * HW * 18 * 4);
    float* msoft = (float*)take(5ll * 36864 * 4);
    int4* idx4 = (int4*)take(5ll * 9 * 4096 * 16);
    float4* w4 = (float4*)take(5ll * 9 * 4096 * 16);
    u16* dout = (u16*)take(5ll * HW * CDIM * 2);
    float* ph0 = (float*)take(5ll * HW * CDIM * 4);
    float* ph1 = (float*)take(5ll * HW * CDIM * 4);
    u16* wb = (u16*)take(1790ll * 768 * 2);
    float* Xcat = (float*)take((size_t)HW * CDIM * 4);
    float* mu = (float*)take(5 * 768 * 4);
    float* rs = (float*)take(5 * 768 * 4);
    float* pb1 = (float*)take(5 * 4 * 768 * 4);
    float* pb2 = (float*)take(5 * 4 * 768 * 4);
    float* qv = (float*)take(4096 * 4);
    float* sqn = (float*)take(4096 * 4);
    float* xq = (float*)take(768 * 4);
    float* wvq = (float*)take(384 * 4);
    float* wzv = (float*)take(768 * 4);
    float* sgate = (float*)take(768 * 4);
    float* m2 = (float*)take(384 * 4);
    float* sq2 = (float*)take(384 * 4);
    float* sv = (float*)take(768 * 4);
    u16* xatt = dout;
    float* P2 = (float*)((char*)dout + 8388608);
    u16* blk = omblk;
    (void)ws_size; (void)in_sizes; (void)n_in; (void)out_size;

    int rows[9] = {30, 100, 150, 150, 220, 220, 268, 268, 384};
    int roff[9]; int acc = 0;
    for (int i = 0; i < 9; i++) { roff[i] = acc; acc += rows[i]; }
    u16* spqb = wb + (size_t)roff[8] * 768;

    WbP wp;
    for (int i = 0; i < 8; i++) { wp.src[i] = wsrc[i]; wp.dst[i] = wb + (size_t)roff[i] * 768; wp.n[i] = rows[i] * 768; }
    wp.src[8] = spq_w; wp.dst[8] = spqb; wp.n[8] = rows[8] * 768;

    ProjP pp;
    pp.b1[0] = wb + (size_t)roff[0] * 768; pp.b2[0] = nullptr;
    pp.b1[1] = wb + (size_t)roff[1] * 768; pp.b2[1] = nullptr;
    pp.b1[2] = wb + (size_t)roff[2] * 768; pp.b2[2] = wb + (size_t)roff[3] * 768;
    pp.b1[3] = wb + (size_t)roff[4] * 768; pp.b2[3] = wb + (size_t)roff[5] * 768;
    pp.b1[4] = wb + (size_t)roff[6] * 768; pp.b2[4] = wb + (size_t)roff[7] * 768;
    int chs[5] = {30, 100, 150, 220, 268};
    int cof[5] = {0, 30, 130, 280, 500};
    for (int i = 0; i < 5; i++) { pp.ch[i] = chs[i]; pp.choff[i] = cof[i]; }
    ProjP pdum = {};

    Ptr5 xs;
    for (int i = 0; i < 5; i++) xs.p[i] = xin[i];

    // ---- prep ----
    k_prep_xpad<<<dim3(PPIX, 5), 192, 0, stream>>>(xs, xpad);
    k_prep_wt<<<dim3(768), 256, 0, stream>>>(conv_w, Wt);
    k_prep_wb<<<dim3(288, 9), 256, 0, stream>>>(wp);

    // ---- heavy path ----
    k_conv256<<<dim3(32, 3, 5), 512, 0, stream>>>(xpad, Wt, conv_b, omblk);
    k_offmask1<<<dim3(256, 5), 256, 0, stream>>>(omblk, off_w, off_b, msk_w, msk_b, offs, msoft);
    k_offmask2<<<dim3(720), 256, 0, stream>>>(offs, msoft, idx4, w4);
    k_gdef<<<dim3(64, 3, 5), 512, 0, stream>>>(xpad, Wt, idx4, w4, conv_b, ph0, ph1);
    k_bnstats2<<<dim3(12, 4, 5), 256, 0, stream>>>(ph0, ph1, pb1, pb2);
    k_bnfinal<<<dim3(15), 256, 0, stream>>>(pb1, pb2, mu, rs);
    k_bnapply<<<dim3(7680), 256, 0, stream>>>(ph0, ph1, mu, rs, bn_g, bn_b, blk);
    k_gemm128<G_PROJ><<<dim3(32, 3, 5), 256, 0, stream>>>(xpad, blk, nullptr, nullptr,
                                                          nullptr, Xcat, pp);

    // ---- CAM ----
    k_q<<<dim3(1024), 256, 0, stream>>>(Xcat, chq_w, qv);
    k_soft4096<<<dim3(1), 256, 0, stream>>>(qv, sqn, xq);
    k_xq<<<dim3(32), 256, 0, stream>>>(Xcat, sqn, xq);
    k_gemv384<<<dim3(96), 256, 0, stream>>>(chv_w, xq, wvq);
    k_gemv768<<<dim3(192), 256, 0, stream>>>(chz_w, wvq, wzv);
    k_lngate<<<dim3(1), 256, 0, stream>>>(wzv, ln_g, ln_b, sgate);
    k_xatt<<<dim3(3072), 256, 0, stream>>>(Xcat, sgate, xatt);
    k_gemm128<G_SPAT><<<dim3(32, 3, 1), 256, 0, stream>>>(xpad, xatt, spqb, nullptr,
                                                          nullptr, P2, pdum);
    k_colmax24<<<dim3(24), dim3(16, 16), 0, stream>>>(P2, m2);
    k_sm384<<<dim3(1), 384, 0, stream>>>(m2, sq2);
    k_sv<<<dim3(12), 256, 0, stream>>>(sq2, spv_w, sv);

    // ---- residual + final LayerNorm ----
    k_final<<<dim3(1024), 256, 0, stream>>>(Xcat, xin[4], sgate, sv, norm_g, norm_b, out);
}

// Round 6
// 982.189 us; speedup vs baseline: 1.0246x; 1.0246x over previous
//
#include <hip/hip_runtime.h>
#include <cstdint>
#include <cstddef>

#define HW 4096
#define CDIM 768
#define PPIX 4356   // 66*66 padded pixels

typedef unsigned short u16;
typedef __attribute__((ext_vector_type(8))) short short8;
typedef __attribute__((ext_vector_type(4))) float f32x4;

__device__ __forceinline__ float bf2f(u16 u) { return __uint_as_float(((unsigned)u) << 16); }
__device__ __forceinline__ u16 f2bf(float f) {
    unsigned u = __float_as_uint(f);
    unsigned r = (u + 0x7fffu + ((u >> 16) & 1u)) >> 16;
    return (u16)r;
}
__device__ __forceinline__ float lof(unsigned u) { return __uint_as_float(u << 16); }
__device__ __forceinline__ float hif(unsigned u) { return __uint_as_float(u & 0xffff0000u); }
__device__ __forceinline__ int swz(int r) { return ((r >> 1) ^ (r >> 3)) & 3; }

__device__ __forceinline__ void gl16(const u16* g, u16* l) {
    __builtin_amdgcn_global_load_lds(
        (const __attribute__((address_space(1))) unsigned int*)g,
        (__attribute__((address_space(3))) unsigned int*)l, 16, 0, 0);
}

enum GMode { G_CONV = 0, G_PROJ = 2, G_SPAT = 3 };

struct ProjP {
    const u16* b1[5];
    const u16* b2[5];
    int ch[5];
    int choff[5];
};

// ---------------------------------------------------------------- 128x128 GEMM
// m97-shape: single LDS buffer (16KB), 2 barriers/step, 4 blocks/CU.
// Used for PROJ / SPAT (small-N) only.
template <int MODE>
__launch_bounds__(256, 4)
__global__ void k_gemm128(const u16* __restrict__ xpad, const u16* __restrict__ blkA,
                          const u16* __restrict__ Wt, const float* __restrict__ bias,
                          u16* __restrict__ outb, float* __restrict__ outf, ProjP pp) {
    const int z = blockIdx.z;
    const int m0 = blockIdx.x * 128;
    const int n0 = blockIdx.y * 128;

    int Nrows, ntap, choff = 0, ldo = CDIM;
    const u16 *Az = nullptr, *Ac = nullptr, *B1 = nullptr, *B2 = nullptr;
    if constexpr (MODE == G_CONV) {
        Az = xpad + (size_t)z * PPIX * CDIM; B1 = Wt; Nrows = 768; ntap = 9;
    } else if constexpr (MODE == G_PROJ) {
        Ac = blkA + (size_t)z * HW * CDIM;
        Az = xpad + (size_t)z * PPIX * CDIM;
        B1 = pp.b1[z]; B2 = pp.b2[z];
        Nrows = pp.ch[z]; choff = pp.choff[z];
        ntap = B2 ? 2 : 1;
        if (n0 >= Nrows) return;
    } else { // G_SPAT
        Ac = blkA; B1 = Wt; Nrows = 384; ntap = 1; ldo = 384;
    }

    __shared__ __align__(16) u16 As[128 * 32];
    __shared__ __align__(16) u16 Bs[128 * 32];

    const int t = threadIdx.x;
    const int lane = t & 63;
    const int wid = t >> 6;
    const int wrow = (wid >> 1) * 64, wcol = (wid & 1) * 64;
    const int lm = lane & 15;
    const int quad = lane >> 4;

    const int rS = t >> 2;
    const int cs0 = (t & 3) ^ swz(rS);
    const int cs1 = (t & 3) ^ swz(64 + rS);

    // A base pointers (element units)
    const u16 *a0 = nullptr, *a1 = nullptr, *a0x = nullptr, *a1x = nullptr;
    if constexpr (MODE == G_CONV) {
        int p0 = m0 + rS, p1 = m0 + 64 + rS;
        a0 = Az + (size_t)(((p0 >> 6)) * 66 + (p0 & 63)) * CDIM + cs0 * 8;
        a1 = Az + (size_t)(((p1 >> 6)) * 66 + (p1 & 63)) * CDIM + cs1 * 8;
    } else if constexpr (MODE == G_PROJ) {
        int p0 = m0 + rS, p1 = m0 + 64 + rS;
        a0 = Ac + (size_t)p0 * CDIM + cs0 * 8;
        a1 = Ac + (size_t)p1 * CDIM + cs1 * 8;
        a0x = Az + (size_t)(((p0 >> 6) + 1) * 66 + (p0 & 63) + 1) * CDIM + cs0 * 8;
        a1x = Az + (size_t)(((p1 >> 6) + 1) * 66 + (p1 & 63) + 1) * CDIM + cs1 * 8;
    } else {
        a0 = Ac + (size_t)(m0 + rS) * CDIM + cs0 * 8;
        a1 = Ac + (size_t)(m0 + 64 + rS) * CDIM + cs1 * 8;
    }
    // B base pointers
    const u16* b0 = B1 + (size_t)(n0 + rS) * CDIM + cs0 * 8;
    const u16* b1p = B1 + (size_t)(n0 + 64 + rS) * CDIM + cs1 * 8;
    const u16 *c0 = nullptr, *c1 = nullptr;
    if constexpr (MODE == G_PROJ) {
        if (B2) {
            c0 = B2 + (size_t)(n0 + rS) * CDIM + cs0 * 8;
            c1 = B2 + (size_t)(n0 + 64 + rS) * CDIM + cs1 * 8;
        }
    }

    u16* dA0 = &As[(0 * 4 + wid) * 512];
    u16* dA1 = &As[(1 * 4 + wid) * 512];
    u16* dB0 = &Bs[(0 * 4 + wid) * 512];
    u16* dB1 = &Bs[(1 * 4 + wid) * 512];

    f32x4 acc[4][4];
#pragma unroll
    for (int i = 0; i < 4; i++)
#pragma unroll
        for (int j = 0; j < 4; j++) acc[i][j] = (f32x4){0.f, 0.f, 0.f, 0.f};

    const int totS = ntap * 24;
    int tap = 0;
    int tA = 0, tB = 0, kO = 0;

    for (int s = 0; s < totS; ++s) {
        __syncthreads();
        if constexpr (MODE == G_CONV) {
            gl16(a0 + tA + kO, dA0);
            gl16(a1 + tA + kO, dA1);
            gl16(b0 + tB + kO, dB0);
            gl16(b1p + tB + kO, dB1);
        } else if constexpr (MODE == G_PROJ) {
            if (tap == 0) {
                gl16(a0 + kO, dA0);
                gl16(a1 + kO, dA1);
                gl16(b0 + kO, dB0);
                gl16(b1p + kO, dB1);
            } else {
                gl16(a0x + kO, dA0);
                gl16(a1x + kO, dA1);
                gl16(c0 + kO, dB0);
                gl16(c1 + kO, dB1);
            }
        } else {
            gl16(a0 + kO, dA0);
            gl16(a1 + kO, dA1);
            gl16(b0 + kO, dB0);
            gl16(b1p + kO, dB1);
        }
        __syncthreads();
        short8 af[4], bf[4];
#pragma unroll
        for (int i = 0; i < 4; i++) {
            int rr = wrow + i * 16 + lm;
            af[i] = *(const short8*)&As[rr * 32 + ((quad ^ swz(rr)) * 8)];
        }
#pragma unroll
        for (int j = 0; j < 4; j++) {
            int rr = wcol + j * 16 + lm;
            bf[j] = *(const short8*)&Bs[rr * 32 + ((quad ^ swz(rr)) * 8)];
        }
#pragma unroll
        for (int i = 0; i < 4; i++)
#pragma unroll
            for (int j = 0; j < 4; j++)
                acc[i][j] = __builtin_amdgcn_mfma_f32_16x16x32_bf16(af[i], bf[j], acc[i][j], 0, 0, 0);
        // advance (tap fastest, then kk)
        tap++;
        if constexpr (MODE == G_CONV) {
            tA += (tap == 3 || tap == 6) ? 64 * CDIM : CDIM;
            tB += CDIM * CDIM;
            if (tap == 9) { tap = 0; tA = 0; tB = 0; kO += 32; }
        } else {
            if (tap == ntap) { tap = 0; kO += 32; }
        }
    }

    // ---- epilogue ----
    if constexpr (MODE == G_CONV) {
        u16* outz = outb + (size_t)z * HW * CDIM;
#pragma unroll
        for (int j = 0; j < 4; j++) {
            int gc = n0 + wcol + j * 16 + lm;
            float bv = bias[gc];
#pragma unroll
            for (int i = 0; i < 4; i++)
#pragma unroll
                for (int r = 0; r < 4; r++) {
                    int gr = m0 + wrow + i * 16 + quad * 4 + r;
                    outz[(size_t)gr * CDIM + gc] = f2bf(acc[i][j][r] + bv);
                }
        }
    } else {
#pragma unroll
        for (int j = 0; j < 4; j++) {
            int gc = n0 + wcol + j * 16 + lm;
            if (gc < Nrows) {
#pragma unroll
                for (int i = 0; i < 4; i++)
#pragma unroll
                    for (int r = 0; r < 4; r++) {
                        int gr = m0 + wrow + i * 16 + quad * 4 + r;
                        outf[(size_t)gr * ldo + choff + gc] = acc[i][j][r];
                    }
            }
        }
    }
}

// XCD-aware bijective swizzle for 480-block GEMMs (480 % 8 == 0, 60/XCD).
// Consecutive works share B panel + xpad(z) -> each XCD L2 keeps one chunk.
__device__ __forceinline__ void xcd_decode(int bid, int& m0, int& n0, int& z) {
    int work = (bid & 7) * 60 + (bid >> 3);
    z = work / 96;
    int rem = work - z * 96;
    n0 = (rem >> 5) * 256;
    m0 = (rem & 31) * 128;
}

// ---------------------------------------------------------------- conv GEMM (128x256, dbuf)
// 512 thr, 8 waves (2x4), 1 barrier/step, double-buffered LDS, gl16 staging.
__launch_bounds__(512, 4)
__global__ void k_conv256(const u16* __restrict__ xpad, const u16* __restrict__ Wt,
                          const float* __restrict__ bias, u16* __restrict__ outb) {
    int m0, n0, z;
    xcd_decode(blockIdx.x, m0, n0, z);
    const u16* Az = xpad + (size_t)z * PPIX * CDIM;

    __shared__ __align__(16) u16 As[2][128 * 32];
    __shared__ __align__(16) u16 Bs[2][256 * 32];

    const int t = threadIdx.x;
    const int lane = t & 63;
    const int wid = t >> 6;
    const int wrow = (wid >> 2) * 64, wcol = (wid & 3) * 64;
    const int lm = lane & 15;
    const int quad = lane >> 4;

    const int rA = t >> 2;
    const int cA = (t & 3) ^ swz(rA);
    const int rB0 = t >> 2;
    const int cB0 = (t & 3) ^ swz(rB0);
    const int rB1 = 128 + (t >> 2);
    const int cB1 = (t & 3) ^ swz(rB1);

    // A per-lane base at tap 0: pixel p -> padded idx (p>>6)*66 + (p&63)
    const int p0 = m0 + rA;
    const u16* aB = Az + (size_t)((p0 >> 6) * 66 + (p0 & 63)) * CDIM + cA * 8;
    const u16* bB0 = Wt + (size_t)(n0 + rB0) * CDIM + cB0 * 8;
    const u16* bB1 = Wt + (size_t)(n0 + rB1) * CDIM + cB1 * 8;

    f32x4 acc[4][4];
#pragma unroll
    for (int i = 0; i < 4; i++)
#pragma unroll
        for (int j = 0; j < 4; j++) acc[i][j] = (f32x4){0.f, 0.f, 0.f, 0.f};

    // prologue: stage step 0 (tap 0, k 0) into buf 0
    gl16(aB, &As[0][wid * 512]);
    gl16(bB0, &Bs[0][wid * 512]);
    gl16(bB1, &Bs[0][4096 + wid * 512]);

    int tap = 0, tA = 0, tB = 0, kO = 0;

    for (int s = 0; s < 216; ++s) {
        const int cur = s & 1;
        const int nxt = cur ^ 1;
        __syncthreads();
        const bool hasN = (s + 1 < 216);
        if (hasN) {
            // advance to step s+1 (tap fastest, then kk)
            tap++;
            tA += (tap == 3 || tap == 6) ? 64 * CDIM : CDIM;
            tB += CDIM * CDIM;
            if (tap == 9) { tap = 0; tA = 0; tB = 0; kO += 32; }
            gl16(aB + tA + kO, &As[nxt][wid * 512]);
            gl16(bB0 + tB + kO, &Bs[nxt][wid * 512]);
            gl16(bB1 + tB + kO, &Bs[nxt][4096 + wid * 512]);
        }
        short8 af[4];
#pragma unroll
        for (int i = 0; i < 4; i++) {
            int rr = wrow + i * 16 + lm;
            af[i] = *(const short8*)&As[cur][rr * 32 + ((quad ^ swz(rr)) * 8)];
        }
#pragma unroll
        for (int j = 0; j < 4; j++) {
            int rr = wcol + j * 16 + lm;
            short8 bf = *(const short8*)&Bs[cur][rr * 32 + ((quad ^ swz(rr)) * 8)];
#pragma unroll
            for (int i = 0; i < 4; i++)
                acc[i][j] = __builtin_amdgcn_mfma_f32_16x16x32_bf16(af[i], bf, acc[i][j], 0, 0, 0);
        }
    }

    u16* outz = outb + (size_t)z * HW * CDIM;
#pragma unroll
    for (int j = 0; j < 4; j++) {
        int gc = n0 + wcol + j * 16 + lm;
        float bv = bias[gc];
#pragma unroll
        for (int i = 0; i < 4; i++)
#pragma unroll
            for (int r = 0; r < 4; r++) {
                int gr = m0 + wrow + i * 16 + quad * 4 + r;
                outz[(size_t)gr * CDIM + gc] = f2bf(acc[i][j][r] + bv);
            }
    }
}

// ---------------------------------------------------------------- deform GEMM (128x256, dbuf)
// R1/R4-proven schedule: scalar fmaf blend + v_perm pack, linear t*8 As
// write, 32-elem rows. Do NOT restructure the blend dataflow (R3 lesson).
// Occupancy is REGISTER-limited: 64 VGPR + 64 AGPR = 128 unified regs ->
// 16 waves/CU = 2 blocks, regardless of grid (R5 lesson — K-split was null).
__launch_bounds__(512, 4)
__global__ void k_gdef(const u16* __restrict__ xpad, const u16* __restrict__ Wt,
                       const int4* __restrict__ idx4, const float4* __restrict__ w4,
                       const float* __restrict__ bias, u16* __restrict__ outb) {
    int m0, n0, z;
    xcd_decode(blockIdx.x, m0, n0, z);
    const u16* Az = xpad + (size_t)z * PPIX * CDIM;
    const int4* idxz = idx4 + (size_t)z * 9 * 4096;
    const float4* w4z = w4 + (size_t)z * 9 * 4096;

    __shared__ __align__(16) u16 As[2][128 * 32];
    __shared__ __align__(16) u16 Bs[2][256 * 32];

    const int t = threadIdx.x;
    const int lane = t & 63;
    const int wid = t >> 6;
    const int wrow = (wid >> 2) * 64, wcol = (wid & 3) * 64;
    const int lm = lane & 15;
    const int quad = lane >> 4;

    // staging coords: one 8-elem chunk of A per thread, two of B
    const int rA = t >> 2;
    const int cA = (t & 3) ^ swz(rA);
    const int rB0 = t >> 2;
    const int cB0 = (t & 3) ^ swz(rB0);
    const int rB1 = 128 + (t >> 2);
    const int cB1 = (t & 3) ^ swz(rB1);

    f32x4 acc[4][4];
#pragma unroll
    for (int i = 0; i < 4; i++)
#pragma unroll
        for (int j = 0; j < 4; j++) acc[i][j] = (f32x4){0.f, 0.f, 0.f, 0.f};

    const u16* bP0;
    const u16* bP1;
    int dOff[4];
    float4 wv;

    auto setupSub = [&](int sn) {
        const u16* Bb = Wt + (size_t)sn * CDIM * CDIM;
        bP0 = Bb + (size_t)(n0 + rB0) * CDIM + cB0 * 8;
        bP1 = Bb + (size_t)(n0 + rB1) * CDIM + cB1 * 8;
        int4 iv = idxz[sn * 4096 + m0 + rA];
        wv = w4z[sn * 4096 + m0 + rA];
        dOff[0] = (iv.x + cA * 8) * 2;
        dOff[1] = (iv.y + cA * 8) * 2;
        dOff[2] = (iv.z + cA * 8) * 2;
        dOff[3] = (iv.w + cA * 8) * 2;
    };

    auto blend4 = [&](const uint4* L) -> uint4 {
        auto bl = [&](unsigned a, unsigned b, unsigned c2, unsigned d) -> unsigned {
            float lo = fmaf(wv.x, lof(a), fmaf(wv.y, lof(b), fmaf(wv.z, lof(c2), wv.w * lof(d))));
            float hi = fmaf(wv.x, hif(a), fmaf(wv.y, hif(b), fmaf(wv.z, hif(c2), wv.w * hif(d))));
            // dst = (hi & 0xffff0000) | (lo >> 16) in one v_perm_b32
            return __builtin_amdgcn_perm(__float_as_uint(hi), __float_as_uint(lo), 0x07060302u);
        };
        uint4 o;
        o.x = bl(L[0].x, L[1].x, L[2].x, L[3].x);
        o.y = bl(L[0].y, L[1].y, L[2].y, L[3].y);
        o.z = bl(L[0].z, L[1].z, L[2].z, L[3].z);
        o.w = bl(L[0].w, L[1].w, L[2].w, L[3].w);
        return o;
    };

    setupSub(0);
    int stagedSub = 0;

    {   // prologue: stage step 0 into buf 0
        uint4 L[4];
#pragma unroll
        for (int k = 0; k < 4; k++)
            L[k] = *(const uint4*)((const char*)Az + dOff[k]);
        gl16(bP0, &Bs[0][wid * 512]);
        gl16(bP1, &Bs[0][4096 + wid * 512]);
        uint4 o = blend4(L);
        *(uint4*)&As[0][t * 8] = o;
    }

    for (int s = 0; s < 216; ++s) {
        const int cur = s & 1;
        const int nxt = cur ^ 1;
        __syncthreads();
        const bool hasN = (s + 1 < 216);
        uint4 L[4];
        if (hasN) {
            int kn = (s + 1) - stagedSub * 24;
            if (kn == 24) { setupSub(++stagedSub); kn = 0; }
            const int cb = kn * 64;  // byte advance along K
#pragma unroll
            for (int k = 0; k < 4; k++)
                L[k] = *(const uint4*)((const char*)Az + dOff[k] + cb);
            gl16(bP0 + kn * 32, &Bs[nxt][wid * 512]);
            gl16(bP1 + kn * 32, &Bs[nxt][4096 + wid * 512]);
        }
        short8 af[4];
#pragma unroll
        for (int i = 0; i < 4; i++) {
            int rr = wrow + i * 16 + lm;
            af[i] = *(const short8*)&As[cur][rr * 32 + ((quad ^ swz(rr)) * 8)];
        }
#pragma unroll
        for (int j = 0; j < 4; j++) {
            int rr = wcol + j * 16 + lm;
            short8 bf = *(const short8*)&Bs[cur][rr * 32 + ((quad ^ swz(rr)) * 8)];
#pragma unroll
            for (int i = 0; i < 4; i++)
                acc[i][j] = __builtin_amdgcn_mfma_f32_16x16x32_bf16(af[i], bf, acc[i][j], 0, 0, 0);
        }
        if (hasN) {
            uint4 o = blend4(L);
            *(uint4*)&As[nxt][t * 8] = o;
        }
    }

    u16* outz = outb + (size_t)z * HW * CDIM;
#pragma unroll
    for (int j = 0; j < 4; j++) {
        int gc = n0 + wcol + j * 16 + lm;
        float bv = bias[gc];
#pragma unroll
        for (int i = 0; i < 4; i++)
#pragma unroll
            for (int r = 0; r < 4; r++) {
                int gr = m0 + wrow + i * 16 + quad * 4 + r;
                outz[(size_t)gr * CDIM + gc] = f2bf(acc[i][j][r] + bv);
            }
    }
}

// ---------------------------------------------------------------- prep kernels
struct Ptr5 { const float* p[5]; };

__global__ void k_prep_xpad(Ptr5 xs, u16* __restrict__ xpad) {
    int z = blockIdx.y;
    int pidx = blockIdx.x;
    int ph = pidx / 66, pw = pidx - ph * 66;
    int e0 = threadIdx.x * 4;
    u16* d = xpad + ((size_t)z * PPIX + pidx) * CDIM + e0;
    if (ph == 0 || ph == 65 || pw == 0 || pw == 65) {
        *(uint2*)d = make_uint2(0, 0);
        return;
    }
    const float* s = xs.p[z] + ((size_t)((ph - 1) * 64 + (pw - 1))) * CDIM + e0;
    float4 v = *(const float4*)s;
    u16 o[4] = {f2bf(v.x), f2bf(v.y), f2bf(v.z), f2bf(v.w)};
    *(uint2*)d = *(uint2*)o;
}

__global__ void k_prep_wt(const float* __restrict__ cw, u16* __restrict__ Wt) {
    int o = blockIdx.x;
    for (int c = threadIdx.x; c < 768; c += 256) {
        const float* s = cw + ((size_t)o * 768 + c) * 9;
#pragma unroll
        for (int k = 0; k < 9; k++)
            Wt[(size_t)k * 768 * 768 + (size_t)o * 768 + c] = f2bf(s[k]);
    }
}

struct WbP { const float* src[9]; u16* dst[9]; int n[9]; };

__global__ void k_prep_wb(WbP wp) {
    int m = blockIdx.y;
    int i = (blockIdx.x * 256 + threadIdx.x) * 4;
    if (i >= wp.n[m]) return;
    float4 v = *(const float4*)(wp.src[m] + i);
    u16* d = wp.dst[m] + i;
    d[0] = f2bf(v.x); d[1] = f2bf(v.y); d[2] = f2bf(v.z); d[3] = f2bf(v.w);
}

// ---------------------------------------------------------------- offset / mask
// 4 pixels per wave (weights loaded once, shared across 4 dot products) ->
// weight L2 traffic /4 (saved ~49us vs 1px/wave, R5 tally).
__global__ void k_offmask1(const u16* __restrict__ om, const float* __restrict__ off_w,
                           const float* __restrict__ off_b, const float* __restrict__ msk_w,
                           const float* __restrict__ msk_b, float* __restrict__ offs,
                           float* __restrict__ msoft) {
    int z = blockIdx.y;
    int wid = threadIdx.x >> 6, lane = threadIdx.x & 63;
    int p0 = blockIdx.x * 16 + wid * 4;
    const u16* rbase = om + (size_t)z * HW * CDIM + (size_t)p0 * CDIM;
    float v[4][12];
#pragma unroll
    for (int pp = 0; pp < 4; pp++)
#pragma unroll
        for (int j = 0; j < 12; j++) v[pp][j] = bf2f(rbase[pp * CDIM + lane + 64 * j]);
    float lg[4][9];
    for (int qq = 0; qq < 27; qq++) {
        const float* wr = (qq < 18) ? (off_w + qq * 768) : (msk_w + (qq - 18) * 768);
        float w[12];
#pragma unroll
        for (int j = 0; j < 12; j++) w[j] = wr[lane + 64 * j];
        float s[4] = {0.f, 0.f, 0.f, 0.f};
#pragma unroll
        for (int pp = 0; pp < 4; pp++)
#pragma unroll
            for (int j = 0; j < 12; j++) s[pp] = fmaf(v[pp][j], w[j], s[pp]);
#pragma unroll
        for (int pp = 0; pp < 4; pp++)
#pragma unroll
            for (int o = 32; o > 0; o >>= 1) s[pp] += __shfl_xor(s[pp], o, 64);
        if (qq < 18) {
            if (lane == qq) {
#pragma unroll
                for (int pp = 0; pp < 4; pp++)
                    offs[((size_t)z * HW + p0 + pp) * 18 + qq] = s[pp] + off_b[qq];
            }
        } else {
#pragma unroll
            for (int pp = 0; pp < 4; pp++) lg[pp][qq - 18] = s[pp] + msk_b[qq - 18];
        }
    }
#pragma unroll
    for (int pp = 0; pp < 4; pp++) {
        float mx = -1e30f;
#pragma unroll
        for (int j = 0; j < 9; j++) mx = fmaxf(mx, lg[pp][j]);
        float sum = 0.f;
#pragma unroll
        for (int j = 0; j < 9; j++) { lg[pp][j] = expf(lg[pp][j] - mx); sum += lg[pp][j]; }
        float inv = 1.f / sum;
#pragma unroll
        for (int j = 0; j < 9; j++)
            if (lane == j) msoft[(size_t)z * 36864 + (p0 + pp) * 9 + j] = lg[pp][j] * inv;
    }
}

__device__ __forceinline__ int cidx(int y, int x) {
    int yc = min(max(y, 0), 63), xc = min(max(x, 0), 63);
    return ((yc + 1) * 66 + (xc + 1)) * CDIM;
}
__device__ __forceinline__ float cval(int y, int x) {
    return (y >= 0 && y < 64 && x >= 0 && x < 64) ? 1.f : 0.f;
}

__global__ void k_offmask2(const float* __restrict__ offs, const float* __restrict__ msoft,
                           int4* __restrict__ idx4o, float4* __restrict__ w4o) {
    int id = blockIdx.x * 256 + threadIdx.x;
    int z = id / 36864, r = id % 36864, k = r >> 12, p = r & 4095;
    const float* ofz = offs + ((size_t)z * HW + p) * 18;
    float dy = ofz[2 * k], dx = ofz[2 * k + 1];
    float mk = msoft[(size_t)z * 36864 + k * 4096 + p];
    int h = p >> 6, w = p & 63;
    float py = (float)(h - 1 + k / 3) + dy;
    float px = (float)(w - 1 + k % 3) + dx;
    float y0f = floorf(py), x0f = floorf(px);
    int y0 = (int)y0f, x0 = (int)x0f;
    float wy1 = py - y0f, wx1 = px - x0f, wy0 = 1.f - wy1, wx0 = 1.f - wx1;
    idx4o[id] = make_int4(cidx(y0, x0), cidx(y0, x0 + 1), cidx(y0 + 1, x0), cidx(y0 + 1, x0 + 1));
    w4o[id] = make_float4(wy0 * wx0 * cval(y0, x0) * mk, wy0 * wx1 * cval(y0, x0 + 1) * mk,
                          wy1 * wx0 * cval(y0 + 1, x0) * mk, wy1 * wx1 * cval(y0 + 1, x0 + 1) * mk);
}

// ---------------------------------------------------------------- batchnorm
// vectorized stats: 12 ch-groups x 4 row-segs x 5 z blocks, uint4 loads,
// LDS reduce -> per-segment partials; k_bnfinal sums 4 segs.
__global__ void k_bnstats2(const u16* __restrict__ dout, float* __restrict__ pb1,
                           float* __restrict__ pb2) {
    const int z = blockIdx.z, seg = blockIdx.y;
    const int cx = threadIdx.x & 7, py = threadIdx.x >> 3;   // 8 cx x 32 py
    const int c0 = blockIdx.x * 64 + cx * 8;
    const u16* base = dout + (size_t)z * HW * CDIM + (size_t)(seg * 1024) * CDIM + c0;
    float s1[8] = {0.f, 0.f, 0.f, 0.f, 0.f, 0.f, 0.f, 0.f};
    float s2[8] = {0.f, 0.f, 0.f, 0.f, 0.f, 0.f, 0.f, 0.f};
    for (int p = py; p < 1024; p += 32) {
        uint4 v = *(const uint4*)(base + (size_t)p * CDIM);
        const u16* u = (const u16*)&v;
#pragma unroll
        for (int e = 0; e < 8; e++) {
            float f = bf2f(u[e]);
            s1[e] += f; s2[e] += f * f;
        }
    }
    __shared__ float l1[32][64], l2[32][64];
#pragma unroll
    for (int e = 0; e < 8; e++) {
        l1[py][cx * 8 + e] = s1[e];
        l2[py][cx * 8 + e] = s2[e];
    }
    __syncthreads();
    if (threadIdx.x < 64) {
        float a = 0.f, b = 0.f;
        for (int y = 0; y < 32; y++) { a += l1[y][threadIdx.x]; b += l2[y][threadIdx.x]; }
        int ch = blockIdx.x * 64 + threadIdx.x;
        pb1[(z * 4 + seg) * 768 + ch] = a;
        pb2[(z * 4 + seg) * 768 + ch] = b;
    }
}

__global__ void k_bnfinal(const float* __restrict__ pb1, const float* __restrict__ pb2,
                          float* __restrict__ mu, float* __restrict__ rs) {
    int i = blockIdx.x * 256 + threadIdx.x;
    if (i >= 3840) return;
    int z = i / 768, ch = i % 768;
    float a = 0.f, b = 0.f;
#pragma unroll
    for (int s = 0; s < 4; s++) {
        a += pb1[(z * 4 + s) * 768 + ch];
        b += pb2[(z * 4 + s) * 768 + ch];
    }
    float m = a / 4096.f;
    float var = b / 4096.f - m * m;
    mu[i] = m;
    rs[i] = rsqrtf(var + 1e-5f);
}

__global__ void k_bnapply(const u16* __restrict__ dout, const float* __restrict__ mu,
                          const float* __restrict__ rs, const float* __restrict__ g,
                          const float* __restrict__ b, u16* __restrict__ blk) {
    size_t i = ((size_t)blockIdx.x * 256 + threadIdx.x) * 8;
    int c = (int)(i % CDIM);
    int z = (int)(i / ((size_t)HW * CDIM));
    const float* muz = mu + z * 768;
    const float* rsz = rs + z * 768;
    uint4 in = *(const uint4*)(dout + i);
    const u16* u = (const u16*)&in;
    u16 o[8];
#pragma unroll
    for (int e = 0; e < 8; e++) {
        int ce = c + e;
        float v = (bf2f(u[e]) - muz[ce]) * rsz[ce] * g[ce] + b[ce];
        o[e] = f2bf(fmaxf(v, 0.f));
    }
    *(uint4*)(blk + i) = *(uint4*)o;
}

// ---------------------------------------------------------------- CAM
__global__ void k_q(const float* __restrict__ X, const float* __restrict__ chq,
                    float* __restrict__ q) {
    int wid = threadIdx.x >> 6, lane = threadIdx.x & 63;
    int p = blockIdx.x * 4 + wid;
    const float* xr = X + (size_t)p * CDIM;
    float s = 0.f;
#pragma unroll
    for (int j = 0; j < 12; j++) s += xr[lane + 64 * j] * chq[lane + 64 * j];
#pragma unroll
    for (int o = 32; o > 0; o >>= 1) s += __shfl_xor(s, o, 64);
    if (lane == 0) q[p] = s;
}

__global__ void k_soft4096(const float* __restrict__ q, float* __restrict__ sqn,
                           float* __restrict__ xq) {
    __shared__ float red[4];
    int tid = threadIdx.x, lane = tid & 63, wid = tid >> 6;
    float m = -1e30f;
    for (int i = tid; i < 4096; i += 256) m = fmaxf(m, q[i]);
    for (int o = 32; o > 0; o >>= 1) m = fmaxf(m, __shfl_xor(m, o, 64));
    if (lane == 0) red[wid] = m;
    __syncthreads();
    float bm = fmaxf(fmaxf(red[0], red[1]), fmaxf(red[2], red[3]));
    __syncthreads();
    float s = 0.f;
    for (int i = tid; i < 4096; i += 256) {
        float e = expf(q[i] - bm);
        sqn[i] = e; s += e;
    }
    for (int o = 32; o > 0; o >>= 1) s += __shfl_xor(s, o, 64);
    if (lane == 0) red[wid] = s;
    __syncthreads();
    float inv = 1.f / (red[0] + red[1] + red[2] + red[3]);
    for (int i = tid; i < 4096; i += 256) sqn[i] *= inv;
    for (int c = tid; c < 768; c += 256) xq[c] = 0.f;
}

__global__ void k_xq(const float* __restrict__ X, const float* __restrict__ sqn,
                     float* __restrict__ xq) {
    int p0 = blockIdx.x * 128;
    for (int c = threadIdx.x; c < 768; c += 256) {
        float a = 0.f;
        for (int p = p0; p < p0 + 128; p++) a += sqn[p] * X[(size_t)p * CDIM + c];
        atomicAdd(&xq[c], a);
    }
}

// wvq[o] = chv[o][:] . xq   (384 rows, wave per row)
__global__ void k_gemv384(const float* __restrict__ chv, const float* __restrict__ xq,
                          float* __restrict__ wvq) {
    int wid = threadIdx.x >> 6, lane = threadIdx.x & 63;
    int o = blockIdx.x * 4 + wid;
    const float* r = chv + (size_t)o * 768;
    float s = 0.f;
#pragma unroll
    for (int j = 0; j < 12; j++) s += r[lane + 64 * j] * xq[lane + 64 * j];
#pragma unroll
    for (int off = 32; off > 0; off >>= 1) s += __shfl_xor(s, off, 64);
    if (lane == 0) wvq[o] = s;
}

// wzv[c] = chz[c][:] . wvq   (768 rows, wave per row)
__global__ void k_gemv768(const float* __restrict__ chz, const float* __restrict__ wvq,
                          float* __restrict__ wzv) {
    int wid = threadIdx.x >> 6, lane = threadIdx.x & 63;
    int c = blockIdx.x * 4 + wid;
    const float* r = chz + (size_t)c * 384;
    float s = 0.f;
#pragma unroll
    for (int j = 0; j < 6; j++) s += r[lane + 64 * j] * wvq[lane + 64 * j];
#pragma unroll
    for (int off = 32; off > 0; off >>= 1) s += __shfl_xor(s, off, 64);
    if (lane == 0) wzv[c] = s;
}

// LN(768) + sigmoid -> sgate
__global__ void k_lngate(const float* __restrict__ wzv, const float* __restrict__ lng,
                         const float* __restrict__ lnb, float* __restrict__ sgate) {
    __shared__ float red[8];
    int tid = threadIdx.x, lane = tid & 63, wid = tid >> 6;
    float a = wzv[tid], b = wzv[tid + 256], c = wzv[tid + 512];
    float s1 = a + b + c, s2 = a * a + b * b + c * c;
    for (int o = 32; o > 0; o >>= 1) { s1 += __shfl_xor(s1, o, 64); s2 += __shfl_xor(s2, o, 64); }
    if (lane == 0) { red[wid] = s1; red[4 + wid] = s2; }
    __syncthreads();
    s1 = red[0] + red[1] + red[2] + red[3];
    s2 = red[4] + red[5] + red[6] + red[7];
    float mean = s1 / 768.f, var = s2 / 768.f - mean * mean, rstd = rsqrtf(var + 1e-5f);
    for (int cc = tid; cc < 768; cc += 256) {
        float tv = (wzv[cc] - mean) * rstd * lng[cc] + lnb[cc];
        sgate[cc] = 1.f / (1.f + expf(-tv));
    }
}

__global__ void k_xatt(const float* __restrict__ X, const float* __restrict__ sgate,
                       u16* __restrict__ xatt) {
    size_t i = ((size_t)blockIdx.x * 256 + threadIdx.x) * 4;
    int c = (int)(i % CDIM);
    float4 v = *(const float4*)(X + i);
    u16 o[4] = {f2bf(v.x * sgate[c]), f2bf(v.y * sgate[c + 1]),
                f2bf(v.z * sgate[c + 2]), f2bf(v.w * sgate[c + 3])};
    *(uint2*)(xatt + i) = *(uint2*)o;
}

// column max over P2[4096][384] — 24 blocks x 16 cols, coalesced
__global__ void k_colmax24(const float* __restrict__ P2, float* __restrict__ m2) {
    __shared__ float red[16][17];
    int col = blockIdx.x * 16 + threadIdx.x;
    float m = -1e30f;
    for (int p = threadIdx.y; p < 4096; p += 16) m = fmaxf(m, P2[(size_t)p * 384 + col]);
    red[threadIdx.y][threadIdx.x] = m;
    __syncthreads();
    if (threadIdx.y == 0) {
        for (int y = 1; y < 16; y++) m = fmaxf(m, red[y][threadIdx.x]);
        m2[col] = m;
    }
}

// softmax over 384 -> sq2
__global__ void k_sm384(const float* __restrict__ m2, float* __restrict__ sq2) {
    __shared__ float red[6];
    int tid = threadIdx.x, lane = tid & 63, wid = tid >> 6;
    float v = m2[tid];
    float m = v;
    for (int o = 32; o > 0; o >>= 1) m = fmaxf(m, __shfl_xor(m, o, 64));
    if (lane == 0) red[wid] = m;
    __syncthreads();
    m = red[0];
    for (int w = 1; w < 6; w++) m = fmaxf(m, red[w]);
    __syncthreads();
    float e = expf(v - m);
    float s = e;
    for (int o = 32; o > 0; o >>= 1) s += __shfl_xor(s, o, 64);
    if (lane == 0) red[wid] = s;
    __syncthreads();
    float tot = 0.f;
    for (int w = 0; w < 6; w++) tot += red[w];
    sq2[tid] = e / tot;
}

// sv[c] = sum_o sq2[o] * spv[o][c]  — 12 blocks x 64 cols, 4-way o-split
__global__ void k_sv(const float* __restrict__ sq2, const float* __restrict__ spv,
                     float* __restrict__ sv) {
    __shared__ float part[4][64];
    int c = blockIdx.x * 64 + (threadIdx.x & 63);
    int seg = threadIdx.x >> 6;
    float a = 0.f;
    for (int o = seg * 96; o < seg * 96 + 96; o++) a += sq2[o] * spv[(size_t)o * 768 + c];
    part[seg][threadIdx.x & 63] = a;
    __syncthreads();
    if (seg == 0) sv[c] = part[0][threadIdx.x] + part[1][threadIdx.x] +
                          part[2][threadIdx.x] + part[3][threadIdx.x];
}

__global__ void k_final(const float* __restrict__ X, const float* __restrict__ x5,
                        const float* __restrict__ sgate, const float* __restrict__ sv,
                        const float* __restrict__ ng, const float* __restrict__ nb,
                        float* __restrict__ out) {
    int wid = threadIdx.x >> 6, lane = threadIdx.x & 63;
    int p = blockIdx.x * 4 + wid;
    const float* xr = X + (size_t)p * CDIM;
    const float* x5r = x5 + (size_t)p * CDIM;
    float xa[12];
    float d = 0.f;
#pragma unroll
    for (int j = 0; j < 12; j++) {
        int c = lane + 64 * j;
        float a = xr[c] * sgate[c];
        xa[j] = a;
        d += sv[c] * a;
    }
#pragma unroll
    for (int o = 32; o > 0; o >>= 1) d += __shfl_xor(d, o, 64);
    float wz2 = 1.f / (1.f + expf(-d));
    float s1 = 0.f, s2 = 0.f;
#pragma unroll
    for (int j = 0; j < 12; j++) {
        int c = lane + 64 * j;
        float y = wz2 * xa[j] + xr[c] + x5r[c];
        xa[j] = y;
        s1 += y; s2 += y * y;
    }
#pragma unroll
    for (int o = 32; o > 0; o >>= 1) { s1 += __shfl_xor(s1, o, 64); s2 += __shfl_xor(s2, o, 64); }
    float mean = s1 / 768.f, var = s2 / 768.f - mean * mean, rstd = rsqrtf(var + 1e-5f);
#pragma unroll
    for (int j = 0; j < 12; j++) {
        int c = lane + 64 * j;
        out[(size_t)p * CDIM + c] = (xa[j] - mean) * rstd * ng[c] + nb[c];
    }
}

// ---------------------------------------------------------------- launch
extern "C" void kernel_launch(void* const* d_in, const int* in_sizes, int n_in,
                              void* d_out, int out_size, void* d_ws, size_t ws_size,
                              hipStream_t stream) {
    const float* xin[5];
    for (int i = 0; i < 5; i++) xin[i] = (const float*)d_in[i];
    const float* conv_w = (const float*)d_in[5];
    const float* conv_b = (const float*)d_in[6];
    const float* off_w = (const float*)d_in[7];
    const float* off_b = (const float*)d_in[8];
    const float* msk_w = (const float*)d_in[9];
    const float* msk_b = (const float*)d_in[10];
    const float* bn_g = (const float*)d_in[11];
    const float* bn_b = (const float*)d_in[12];
    const float* chq_w = (const float*)d_in[13];
    const float* chv_w = (const float*)d_in[14];
    const float* chz_w = (const float*)d_in[15];
    const float* ln_g = (const float*)d_in[16];
    const float* ln_b = (const float*)d_in[17];
    const float* spq_w = (const float*)d_in[18];
    const float* spv_w = (const float*)d_in[19];
    const float* wsrc[8];
    for (int i = 0; i < 8; i++) wsrc[i] = (const float*)d_in[20 + i];
    const float* norm_g = (const float*)d_in[28];
    const float* norm_b = (const float*)d_in[29];
    float* out = (float*)d_out;

    char* wsb = (char*)d_ws;
    size_t off = 0;
    auto take = [&](size_t n) -> char* {
        char* p = wsb + off;
        off = (off + n + 255) & ~(size_t)255;
        return p;
    };
    u16* xpad = (u16*)take(5ll * PPIX * CDIM * 2);
    u16* Wt = (u16*)take(9ll * CDIM * CDIM * 2);
    u16* omblk = (u16*)take(5ll * HW * CDIM * 2);
    float* offs = (float*)take(5ll * HW * 18 * 4);
    float* msoft = (float*)take(5ll * 36864 * 4);
    int4* idx4 = (int4*)take(5ll * 9 * 4096 * 16);
    float4* w4 = (float4*)take(5ll * 9 * 4096 * 16);
    u16* dout = (u16*)take(5ll * HW * CDIM * 2);
    u16* wb = (u16*)take(1790ll * 768 * 2);
    float* Xcat = (float*)take((size_t)HW * CDIM * 4);
    float* mu = (float*)take(5 * 768 * 4);
    float* rs = (float*)take(5 * 768 * 4);
    float* pb1 = (float*)take(5 * 4 * 768 * 4);
    float* pb2 = (float*)take(5 * 4 * 768 * 4);
    float* qv = (float*)take(4096 * 4);
    float* sqn = (float*)take(4096 * 4);
    float* xq = (float*)take(768 * 4);
    float* wvq = (float*)take(384 * 4);
    float* wzv = (float*)take(768 * 4);
    float* sgate = (float*)take(768 * 4);
    float* m2 = (float*)take(384 * 4);
    float* sq2 = (float*)take(384 * 4);
    float* sv = (float*)take(768 * 4);
    u16* xatt = dout;
    float* P2 = (float*)((char*)dout + 8388608);
    u16* blk = omblk;
    (void)ws_size; (void)in_sizes; (void)n_in; (void)out_size;

    int rows[9] = {30, 100, 150, 150, 220, 220, 268, 268, 384};
    int roff[9]; int acc = 0;
    for (int i = 0; i < 9; i++) { roff[i] = acc; acc += rows[i]; }
    u16* spqb = wb + (size_t)roff[8] * 768;

    WbP wp;
    for (int i = 0; i < 8; i++) { wp.src[i] = wsrc[i]; wp.dst[i] = wb + (size_t)roff[i] * 768; wp.n[i] = rows[i] * 768; }
    wp.src[8] = spq_w; wp.dst[8] = spqb; wp.n[8] = rows[8] * 768;

    ProjP pp;
    pp.b1[0] = wb + (size_t)roff[0] * 768; pp.b2[0] = nullptr;
    pp.b1[1] = wb + (size_t)roff[1] * 768; pp.b2[1] = nullptr;
    pp.b1[2] = wb + (size_t)roff[2] * 768; pp.b2[2] = wb + (size_t)roff[3] * 768;
    pp.b1[3] = wb + (size_t)roff[4] * 768; pp.b2[3] = wb + (size_t)roff[5] * 768;
    pp.b1[4] = wb + (size_t)roff[6] * 768; pp.b2[4] = wb + (size_t)roff[7] * 768;
    int chs[5] = {30, 100, 150, 220, 268};
    int cof[5] = {0, 30, 130, 280, 500};
    for (int i = 0; i < 5; i++) { pp.ch[i] = chs[i]; pp.choff[i] = cof[i]; }
    ProjP pdum = {};

    Ptr5 xs;
    for (int i = 0; i < 5; i++) xs.p[i] = xin[i];

    // ---- prep ----
    k_prep_xpad<<<dim3(PPIX, 5), 192, 0, stream>>>(xs, xpad);
    k_prep_wt<<<dim3(768), 256, 0, stream>>>(conv_w, Wt);
    k_prep_wb<<<dim3(288, 9), 256, 0, stream>>>(wp);

    // ---- heavy path ----
    k_conv256<<<dim3(480), 512, 0, stream>>>(xpad, Wt, conv_b, omblk);
    k_offmask1<<<dim3(256, 5), 256, 0, stream>>>(omblk, off_w, off_b, msk_w, msk_b, offs, msoft);
    k_offmask2<<<dim3(720), 256, 0, stream>>>(offs, msoft, idx4, w4);
    k_gdef<<<dim3(480), 512, 0, stream>>>(xpad, Wt, idx4, w4, conv_b, dout);
    k_bnstats2<<<dim3(12, 4, 5), 256, 0, stream>>>(dout, pb1, pb2);
    k_bnfinal<<<dim3(15), 256, 0, stream>>>(pb1, pb2, mu, rs);
    k_bnapply<<<dim3(7680), 256, 0, stream>>>(dout, mu, rs, bn_g, bn_b, blk);
    k_gemm128<G_PROJ><<<dim3(32, 3, 5), 256, 0, stream>>>(xpad, blk, nullptr, nullptr,
                                                          nullptr, Xcat, pp);

    // ---- CAM ----
    k_q<<<dim3(1024), 256, 0, stream>>>(Xcat, chq_w, qv);
    k_soft4096<<<dim3(1), 256, 0, stream>>>(qv, sqn, xq);
    k_xq<<<dim3(32), 256, 0, stream>>>(Xcat, sqn, xq);
    k_gemv384<<<dim3(96), 256, 0, stream>>>(chv_w, xq, wvq);
    k_gemv768<<<dim3(192), 256, 0, stream>>>(chz_w, wvq, wzv);
    k_lngate<<<dim3(1), 256, 0, stream>>>(wzv, ln_g, ln_b, sgate);
    k_xatt<<<dim3(3072), 256, 0, stream>>>(Xcat, sgate, xatt);
    k_gemm128<G_SPAT><<<dim3(32, 3, 1), 256, 0, stream>>>(xpad, xatt, spqb, nullptr,
                                                          nullptr, P2, pdum);
    k_colmax24<<<dim3(24), dim3(16, 16), 0, stream>>>(P2, m2);
    k_sm384<<<dim3(1), 384, 0, stream>>>(m2, sq2);
    k_sv<<<dim3(12), 256, 0, stream>>>(sq2, spv_w, sv);

    // ---- residual + final LayerNorm ----
    k_final<<<dim3(1024), 256, 0, stream>>>(Xcat, xin[4], sgate, sv, norm_g, norm_b, out);
}

// Round 8
// 859.816 us; speedup vs baseline: 1.1704x; 1.1423x over previous
//
#include <hip/hip_runtime.h>
#include <cstdint>
#include <cstddef>

#define HW 4096
#define CDIM 768
#define PPIX 4356   // 66*66 padded pixels

typedef unsigned short u16;
typedef __attribute__((ext_vector_type(8))) short short8;
typedef __attribute__((ext_vector_type(4))) float f32x4;

__device__ __forceinline__ float bf2f(u16 u) { return __uint_as_float(((unsigned)u) << 16); }
__device__ __forceinline__ u16 f2bf(float f) {
    unsigned u = __float_as_uint(f);
    unsigned r = (u + 0x7fffu + ((u >> 16) & 1u)) >> 16;
    return (u16)r;
}
__device__ __forceinline__ float lof(unsigned u) { return __uint_as_float(u << 16); }
__device__ __forceinline__ float hif(unsigned u) { return __uint_as_float(u & 0xffff0000u); }
__device__ __forceinline__ int swz(int r) { return ((r >> 1) ^ (r >> 3)) & 3; }

__device__ __forceinline__ void gl16(const u16* g, u16* l) {
    __builtin_amdgcn_global_load_lds(
        (const __attribute__((address_space(1))) unsigned int*)g,
        (__attribute__((address_space(3))) unsigned int*)l, 16, 0, 0);
}

enum GMode { G_CONV = 0, G_PROJ = 2, G_SPAT = 3 };

struct ProjP {
    const u16* b1[5];
    const u16* b2[5];
    int ch[5];
    int choff[5];
};

// ---------------------------------------------------------------- 128x128 GEMM
// m97-shape: single LDS buffer (16KB), 2 barriers/step, 4 blocks/CU.
// Used for PROJ / SPAT (small-N) only.
template <int MODE>
__launch_bounds__(256, 4)
__global__ void k_gemm128(const u16* __restrict__ xpad, const u16* __restrict__ blkA,
                          const u16* __restrict__ Wt, const float* __restrict__ bias,
                          u16* __restrict__ outb, float* __restrict__ outf, ProjP pp) {
    const int z = blockIdx.z;
    const int m0 = blockIdx.x * 128;
    const int n0 = blockIdx.y * 128;

    int Nrows, ntap, choff = 0, ldo = CDIM;
    const u16 *Az = nullptr, *Ac = nullptr, *B1 = nullptr, *B2 = nullptr;
    if constexpr (MODE == G_CONV) {
        Az = xpad + (size_t)z * PPIX * CDIM; B1 = Wt; Nrows = 768; ntap = 9;
    } else if constexpr (MODE == G_PROJ) {
        Ac = blkA + (size_t)z * HW * CDIM;
        Az = xpad + (size_t)z * PPIX * CDIM;
        B1 = pp.b1[z]; B2 = pp.b2[z];
        Nrows = pp.ch[z]; choff = pp.choff[z];
        ntap = B2 ? 2 : 1;
        if (n0 >= Nrows) return;
    } else { // G_SPAT
        Ac = blkA; B1 = Wt; Nrows = 384; ntap = 1; ldo = 384;
    }

    __shared__ __align__(16) u16 As[128 * 32];
    __shared__ __align__(16) u16 Bs[128 * 32];

    const int t = threadIdx.x;
    const int lane = t & 63;
    const int wid = t >> 6;
    const int wrow = (wid >> 1) * 64, wcol = (wid & 1) * 64;
    const int lm = lane & 15;
    const int quad = lane >> 4;

    const int rS = t >> 2;
    const int cs0 = (t & 3) ^ swz(rS);
    const int cs1 = (t & 3) ^ swz(64 + rS);

    // A base pointers (element units)
    const u16 *a0 = nullptr, *a1 = nullptr, *a0x = nullptr, *a1x = nullptr;
    if constexpr (MODE == G_CONV) {
        int p0 = m0 + rS, p1 = m0 + 64 + rS;
        a0 = Az + (size_t)(((p0 >> 6)) * 66 + (p0 & 63)) * CDIM + cs0 * 8;
        a1 = Az + (size_t)(((p1 >> 6)) * 66 + (p1 & 63)) * CDIM + cs1 * 8;
    } else if constexpr (MODE == G_PROJ) {
        int p0 = m0 + rS, p1 = m0 + 64 + rS;
        a0 = Ac + (size_t)p0 * CDIM + cs0 * 8;
        a1 = Ac + (size_t)p1 * CDIM + cs1 * 8;
        a0x = Az + (size_t)(((p0 >> 6) + 1) * 66 + (p0 & 63) + 1) * CDIM + cs0 * 8;
        a1x = Az + (size_t)(((p1 >> 6) + 1) * 66 + (p1 & 63) + 1) * CDIM + cs1 * 8;
    } else {
        a0 = Ac + (size_t)(m0 + rS) * CDIM + cs0 * 8;
        a1 = Ac + (size_t)(m0 + 64 + rS) * CDIM + cs1 * 8;
    }
    // B base pointers
    const u16* b0 = B1 + (size_t)(n0 + rS) * CDIM + cs0 * 8;
    const u16* b1p = B1 + (size_t)(n0 + 64 + rS) * CDIM + cs1 * 8;
    const u16 *c0 = nullptr, *c1 = nullptr;
    if constexpr (MODE == G_PROJ) {
        if (B2) {
            c0 = B2 + (size_t)(n0 + rS) * CDIM + cs0 * 8;
            c1 = B2 + (size_t)(n0 + 64 + rS) * CDIM + cs1 * 8;
        }
    }

    u16* dA0 = &As[(0 * 4 + wid) * 512];
    u16* dA1 = &As[(1 * 4 + wid) * 512];
    u16* dB0 = &Bs[(0 * 4 + wid) * 512];
    u16* dB1 = &Bs[(1 * 4 + wid) * 512];

    f32x4 acc[4][4];
#pragma unroll
    for (int i = 0; i < 4; i++)
#pragma unroll
        for (int j = 0; j < 4; j++) acc[i][j] = (f32x4){0.f, 0.f, 0.f, 0.f};

    const int totS = ntap * 24;
    int tap = 0;
    int tA = 0, tB = 0, kO = 0;

    for (int s = 0; s < totS; ++s) {
        __syncthreads();
        if constexpr (MODE == G_CONV) {
            gl16(a0 + tA + kO, dA0);
            gl16(a1 + tA + kO, dA1);
            gl16(b0 + tB + kO, dB0);
            gl16(b1p + tB + kO, dB1);
        } else if constexpr (MODE == G_PROJ) {
            if (tap == 0) {
                gl16(a0 + kO, dA0);
                gl16(a1 + kO, dA1);
                gl16(b0 + kO, dB0);
                gl16(b1p + kO, dB1);
            } else {
                gl16(a0x + kO, dA0);
                gl16(a1x + kO, dA1);
                gl16(c0 + kO, dB0);
                gl16(c1 + kO, dB1);
            }
        } else {
            gl16(a0 + kO, dA0);
            gl16(a1 + kO, dA1);
            gl16(b0 + kO, dB0);
            gl16(b1p + kO, dB1);
        }
        __syncthreads();
        short8 af[4], bf[4];
#pragma unroll
        for (int i = 0; i < 4; i++) {
            int rr = wrow + i * 16 + lm;
            af[i] = *(const short8*)&As[rr * 32 + ((quad ^ swz(rr)) * 8)];
        }
#pragma unroll
        for (int j = 0; j < 4; j++) {
            int rr = wcol + j * 16 + lm;
            bf[j] = *(const short8*)&Bs[rr * 32 + ((quad ^ swz(rr)) * 8)];
        }
#pragma unroll
        for (int i = 0; i < 4; i++)
#pragma unroll
            for (int j = 0; j < 4; j++)
                acc[i][j] = __builtin_amdgcn_mfma_f32_16x16x32_bf16(af[i], bf[j], acc[i][j], 0, 0, 0);
        // advance (tap fastest, then kk)
        tap++;
        if constexpr (MODE == G_CONV) {
            tA += (tap == 3 || tap == 6) ? 64 * CDIM : CDIM;
            tB += CDIM * CDIM;
            if (tap == 9) { tap = 0; tA = 0; tB = 0; kO += 32; }
        } else {
            if (tap == ntap) { tap = 0; kO += 32; }
        }
    }

    // ---- epilogue ----
    if constexpr (MODE == G_CONV) {
        u16* outz = outb + (size_t)z * HW * CDIM;
#pragma unroll
        for (int j = 0; j < 4; j++) {
            int gc = n0 + wcol + j * 16 + lm;
            float bv = bias[gc];
#pragma unroll
            for (int i = 0; i < 4; i++)
#pragma unroll
                for (int r = 0; r < 4; r++) {
                    int gr = m0 + wrow + i * 16 + quad * 4 + r;
                    outz[(size_t)gr * CDIM + gc] = f2bf(acc[i][j][r] + bv);
                }
        }
    } else {
#pragma unroll
        for (int j = 0; j < 4; j++) {
            int gc = n0 + wcol + j * 16 + lm;
            if (gc < Nrows) {
#pragma unroll
                for (int i = 0; i < 4; i++)
#pragma unroll
                    for (int r = 0; r < 4; r++) {
                        int gr = m0 + wrow + i * 16 + quad * 4 + r;
                        outf[(size_t)gr * ldo + choff + gc] = acc[i][j][r];
                    }
            }
        }
    }
}

// XCD-aware bijective swizzle for 480-block GEMMs (480 % 8 == 0, 60/XCD).
__device__ __forceinline__ void xcd_decode(int bid, int& m0, int& n0, int& z) {
    int work = (bid & 7) * 60 + (bid >> 3);
    z = work / 96;
    int rem = work - z * 96;
    n0 = (rem >> 5) * 256;
    m0 = (rem & 31) * 128;
}

// ---------------------------------------------------------------- folded offset/mask weights
// OMW[t][q][c] = sum_o OW27[q][o] * Wt[t][o][c]  (q<18: off_w row, else msk_w).
// OW staged in LDS in 256-o chunks (9.2KB — 64KB static LDS limit, R7 lesson).
__global__ void k_fold(const u16* __restrict__ Wt, const float* __restrict__ off_w,
                       const float* __restrict__ msk_w, u16* __restrict__ OMW) {
    const int cb = blockIdx.x, tp = blockIdx.y, qg = blockIdx.z;
    const int q0 = qg * 9;
    __shared__ float ow[256 * 9];
    const int c = cb * 256 + threadIdx.x;
    const u16* wcol = Wt + (size_t)tp * 768 * 768 + c;
    float acc[9];
#pragma unroll
    for (int qi = 0; qi < 9; qi++) acc[qi] = 0.f;
    for (int ob = 0; ob < 768; ob += 256) {
        __syncthreads();
#pragma unroll
        for (int qi = 0; qi < 9; qi++) {
            int q = q0 + qi;
            const float* src = (q < 18) ? (off_w + (size_t)q * 768)
                                        : (msk_w + (size_t)(q - 18) * 768);
            ow[threadIdx.x * 9 + qi] = src[ob + threadIdx.x];
        }
        __syncthreads();
#pragma unroll 4
        for (int oo = 0; oo < 256; oo++) {
            float w = bf2f(wcol[(size_t)(ob + oo) * 768]);
#pragma unroll
            for (int qi = 0; qi < 9; qi++) acc[qi] = fmaf(w, ow[oo * 9 + qi], acc[qi]);
        }
    }
#pragma unroll
    for (int qi = 0; qi < 9; qi++)
        OMW[((size_t)tp * 32 + q0 + qi) * 768 + c] = f2bf(acc[qi]);
    if (qg == 2) {
        for (int q = 27; q < 32; q++) OMW[((size_t)tp * 32 + q) * 768 + c] = 0;
    }
}

// bb[q] = OW27[q] . conv_b + (off_b|msk_b)[q]   (27 rows, wave per row)
__global__ void k_bias27(const float* __restrict__ off_w, const float* __restrict__ msk_w,
                         const float* __restrict__ conv_b, const float* __restrict__ off_b,
                         const float* __restrict__ msk_b, float* __restrict__ bb) {
    int wid = threadIdx.x >> 6, lane = threadIdx.x & 63;
    int q = blockIdx.x * 4 + wid;
    if (q >= 27) return;
    const float* r = (q < 18) ? (off_w + (size_t)q * 768) : (msk_w + (size_t)(q - 18) * 768);
    float s = 0.f;
#pragma unroll
    for (int j = 0; j < 12; j++) s += r[lane + 64 * j] * conv_b[lane + 64 * j];
#pragma unroll
    for (int o = 32; o > 0; o >>= 1) s += __shfl_xor(s, o, 64);
    if (lane == 0) bb[q] = s + ((q < 18) ? off_b[q] : msk_b[q - 18]);
}

// ---------------------------------------------------------------- thin offset/mask conv
// Replaces conv256 (217 GF) + offmask1: 3x3 conv of xpad with OMW (27ch, 15 GF).
// Same dbuf/gl16/swizzle staging pattern as conv256. 512 thr, 8 waves x (16x32).
__launch_bounds__(512, 4)
__global__ void k_convOM(const u16* __restrict__ xpad, const u16* __restrict__ OMW,
                         const float* __restrict__ bb, float* __restrict__ offs,
                         float* __restrict__ mlog) {
    const int z = blockIdx.z;
    const int m0 = blockIdx.x * 128;
    const u16* Az = xpad + (size_t)z * PPIX * CDIM;

    __shared__ __align__(16) u16 As[2][128 * 32];
    __shared__ __align__(16) u16 Bs[2][32 * 32];

    const int t = threadIdx.x;
    const int lane = t & 63;
    const int wid = t >> 6;
    const int lm = lane & 15;
    const int quad = lane >> 4;

    const int rA = t >> 2;
    const int cA = (t & 3) ^ swz(rA);
    const int p0 = m0 + rA;
    const u16* aB = Az + (size_t)((p0 >> 6) * 66 + (p0 & 63)) * CDIM + cA * 8;

    // B rows 0..31 staged by threads 0..127 (waves 0,1 — wave-uniform branch)
    const int rB = t >> 2;
    const int cB = (t & 3) ^ swz(rB);
    const u16* bB = OMW + (size_t)rB * 768 + cB * 8;

    f32x4 acc[2];
    acc[0] = (f32x4){0.f, 0.f, 0.f, 0.f};
    acc[1] = (f32x4){0.f, 0.f, 0.f, 0.f};

    gl16(aB, &As[0][wid * 512]);
    if (t < 128) gl16(bB, &Bs[0][wid * 512]);

    int tap = 0, tA = 0, tB = 0, kO = 0;
    for (int s = 0; s < 216; ++s) {
        const int cur = s & 1, nxt = cur ^ 1;
        __syncthreads();
        const bool hasN = (s + 1 < 216);
        if (hasN) {
            tap++;
            tA += (tap == 3 || tap == 6) ? 64 * CDIM : CDIM;
            tB += 32 * 768;
            if (tap == 9) { tap = 0; tA = 0; tB = 0; kO += 32; }
            gl16(aB + tA + kO, &As[nxt][wid * 512]);
            if (t < 128) gl16(bB + tB + kO, &Bs[nxt][wid * 512]);
        }
        int ar = wid * 16 + lm;
        short8 af = *(const short8*)&As[cur][ar * 32 + ((quad ^ swz(ar)) * 8)];
#pragma unroll
        for (int j = 0; j < 2; j++) {
            int rr = j * 16 + lm;
            short8 bf = *(const short8*)&Bs[cur][rr * 32 + ((quad ^ swz(rr)) * 8)];
            acc[j] = __builtin_amdgcn_mfma_f32_16x16x32_bf16(af, bf, acc[j], 0, 0, 0);
        }
    }

#pragma unroll
    for (int j = 0; j < 2; j++) {
        int gc = j * 16 + lm;
        float bv = (gc < 27) ? bb[gc] : 0.f;
#pragma unroll
        for (int r = 0; r < 4; r++) {
            int gr = m0 + wid * 16 + quad * 4 + r;
            float v = acc[j][r] + bv;
            if (gc < 18) offs[((size_t)z * HW + gr) * 18 + gc] = v;
            else if (gc < 27) mlog[(size_t)z * 36864 + (size_t)gr * 9 + (gc - 18)] = v;
        }
    }
}

// ---------------------------------------------------------------- deform GEMM (128x256, dbuf)
// R1/R4-proven schedule: scalar fmaf blend + v_perm pack, linear t*8 As
// write, 32-elem rows. Do NOT restructure the blend dataflow (R3 lesson).
// Occupancy is REGISTER-limited: 64 VGPR + 64 AGPR = 128 unified regs ->
// 16 waves/CU = 2 blocks, regardless of grid (R5 lesson — K-split was null).
__launch_bounds__(512, 4)
__global__ void k_gdef(const u16* __restrict__ xpad, const u16* __restrict__ Wt,
                       const int4* __restrict__ idx4, const float4* __restrict__ w4,
                       const float* __restrict__ bias, u16* __restrict__ outb) {
    int m0, n0, z;
    xcd_decode(blockIdx.x, m0, n0, z);
    const u16* Az = xpad + (size_t)z * PPIX * CDIM;
    const int4* idxz = idx4 + (size_t)z * 9 * 4096;
    const float4* w4z = w4 + (size_t)z * 9 * 4096;

    __shared__ __align__(16) u16 As[2][128 * 32];
    __shared__ __align__(16) u16 Bs[2][256 * 32];

    const int t = threadIdx.x;
    const int lane = t & 63;
    const int wid = t >> 6;
    const int wrow = (wid >> 2) * 64, wcol = (wid & 3) * 64;
    const int lm = lane & 15;
    const int quad = lane >> 4;

    // staging coords: one 8-elem chunk of A per thread, two of B
    const int rA = t >> 2;
    const int cA = (t & 3) ^ swz(rA);
    const int rB0 = t >> 2;
    const int cB0 = (t & 3) ^ swz(rB0);
    const int rB1 = 128 + (t >> 2);
    const int cB1 = (t & 3) ^ swz(rB1);

    f32x4 acc[4][4];
#pragma unroll
    for (int i = 0; i < 4; i++)
#pragma unroll
        for (int j = 0; j < 4; j++) acc[i][j] = (f32x4){0.f, 0.f, 0.f, 0.f};

    const u16* bP0;
    const u16* bP1;
    int dOff[4];
    float4 wv;

    auto setupSub = [&](int sn) {
        const u16* Bb = Wt + (size_t)sn * CDIM * CDIM;
        bP0 = Bb + (size_t)(n0 + rB0) * CDIM + cB0 * 8;
        bP1 = Bb + (size_t)(n0 + rB1) * CDIM + cB1 * 8;
        int4 iv = idxz[sn * 4096 + m0 + rA];
        wv = w4z[sn * 4096 + m0 + rA];
        dOff[0] = (iv.x + cA * 8) * 2;
        dOff[1] = (iv.y + cA * 8) * 2;
        dOff[2] = (iv.z + cA * 8) * 2;
        dOff[3] = (iv.w + cA * 8) * 2;
    };

    auto blend4 = [&](const uint4* L) -> uint4 {
        auto bl = [&](unsigned a, unsigned b, unsigned c2, unsigned d) -> unsigned {
            float lo = fmaf(wv.x, lof(a), fmaf(wv.y, lof(b), fmaf(wv.z, lof(c2), wv.w * lof(d))));
            float hi = fmaf(wv.x, hif(a), fmaf(wv.y, hif(b), fmaf(wv.z, hif(c2), wv.w * hif(d))));
            // dst = (hi & 0xffff0000) | (lo >> 16) in one v_perm_b32
            return __builtin_amdgcn_perm(__float_as_uint(hi), __float_as_uint(lo), 0x07060302u);
        };
        uint4 o;
        o.x = bl(L[0].x, L[1].x, L[2].x, L[3].x);
        o.y = bl(L[0].y, L[1].y, L[2].y, L[3].y);
        o.z = bl(L[0].z, L[1].z, L[2].z, L[3].z);
        o.w = bl(L[0].w, L[1].w, L[2].w, L[3].w);
        return o;
    };

    setupSub(0);
    int stagedSub = 0;

    {   // prologue: stage step 0 into buf 0
        uint4 L[4];
#pragma unroll
        for (int k = 0; k < 4; k++)
            L[k] = *(const uint4*)((const char*)Az + dOff[k]);
        gl16(bP0, &Bs[0][wid * 512]);
        gl16(bP1, &Bs[0][4096 + wid * 512]);
        uint4 o = blend4(L);
        *(uint4*)&As[0][t * 8] = o;
    }

    for (int s = 0; s < 216; ++s) {
        const int cur = s & 1;
        const int nxt = cur ^ 1;
        __syncthreads();
        const bool hasN = (s + 1 < 216);
        uint4 L[4];
        if (hasN) {
            int kn = (s + 1) - stagedSub * 24;
            if (kn == 24) { setupSub(++stagedSub); kn = 0; }
            const int cb = kn * 64;  // byte advance along K
#pragma unroll
            for (int k = 0; k < 4; k++)
                L[k] = *(const uint4*)((const char*)Az + dOff[k] + cb);
            gl16(bP0 + kn * 32, &Bs[nxt][wid * 512]);
            gl16(bP1 + kn * 32, &Bs[nxt][4096 + wid * 512]);
        }
        short8 af[4];
#pragma unroll
        for (int i = 0; i < 4; i++) {
            int rr = wrow + i * 16 + lm;
            af[i] = *(const short8*)&As[cur][rr * 32 + ((quad ^ swz(rr)) * 8)];
        }
#pragma unroll
        for (int j = 0; j < 4; j++) {
            int rr = wcol + j * 16 + lm;
            short8 bf = *(const short8*)&Bs[cur][rr * 32 + ((quad ^ swz(rr)) * 8)];
#pragma unroll
            for (int i = 0; i < 4; i++)
                acc[i][j] = __builtin_amdgcn_mfma_f32_16x16x32_bf16(af[i], bf, acc[i][j], 0, 0, 0);
        }
        if (hasN) {
            uint4 o = blend4(L);
            *(uint4*)&As[nxt][t * 8] = o;
        }
    }

    u16* outz = outb + (size_t)z * HW * CDIM;
#pragma unroll
    for (int j = 0; j < 4; j++) {
        int gc = n0 + wcol + j * 16 + lm;
        float bv = bias[gc];
#pragma unroll
        for (int i = 0; i < 4; i++)
#pragma unroll
            for (int r = 0; r < 4; r++) {
                int gr = m0 + wrow + i * 16 + quad * 4 + r;
                outz[(size_t)gr * CDIM + gc] = f2bf(acc[i][j][r] + bv);
            }
    }
}

// ---------------------------------------------------------------- prep kernels
struct Ptr5 { const float* p[5]; };

__global__ void k_prep_xpad(Ptr5 xs, u16* __restrict__ xpad) {
    int z = blockIdx.y;
    int pidx = blockIdx.x;
    int ph = pidx / 66, pw = pidx - ph * 66;
    int e0 = threadIdx.x * 4;
    u16* d = xpad + ((size_t)z * PPIX + pidx) * CDIM + e0;
    if (ph == 0 || ph == 65 || pw == 0 || pw == 65) {
        *(uint2*)d = make_uint2(0, 0);
        return;
    }
    const float* s = xs.p[z] + ((size_t)((ph - 1) * 64 + (pw - 1))) * CDIM + e0;
    float4 v = *(const float4*)s;
    u16 o[4] = {f2bf(v.x), f2bf(v.y), f2bf(v.z), f2bf(v.w)};
    *(uint2*)d = *(uint2*)o;
}

__global__ void k_prep_wt(const float* __restrict__ cw, u16* __restrict__ Wt) {
    int o = blockIdx.x;
    for (int c = threadIdx.x; c < 768; c += 256) {
        const float* s = cw + ((size_t)o * 768 + c) * 9;
#pragma unroll
        for (int k = 0; k < 9; k++)
            Wt[(size_t)k * 768 * 768 + (size_t)o * 768 + c] = f2bf(s[k]);
    }
}

struct WbP { const float* src[9]; u16* dst[9]; int n[9]; };

__global__ void k_prep_wb(WbP wp) {
    int m = blockIdx.y;
    int i = (blockIdx.x * 256 + threadIdx.x) * 4;
    if (i >= wp.n[m]) return;
    float4 v = *(const float4*)(wp.src[m] + i);
    u16* d = wp.dst[m] + i;
    d[0] = f2bf(v.x); d[1] = f2bf(v.y); d[2] = f2bf(v.z); d[3] = f2bf(v.w);
}

// ---------------------------------------------------------------- offset / mask sample prep
__device__ __forceinline__ int cidx(int y, int x) {
    int yc = min(max(y, 0), 63), xc = min(max(x, 0), 63);
    return ((yc + 1) * 66 + (xc + 1)) * CDIM;
}
__device__ __forceinline__ float cval(int y, int x) {
    return (y >= 0 && y < 64 && x >= 0 && x < 64) ? 1.f : 0.f;
}

// softmax over the 9 logits of the ORIGINAL pixel P folded in (torch raw-reshape
// semantics: mask flat index k*4096+p belongs to pixel (k*4096+p)/9, slot %9).
__global__ void k_offmask2(const float* __restrict__ offs, const float* __restrict__ mlog,
                           int4* __restrict__ idx4o, float4* __restrict__ w4o) {
    int id = blockIdx.x * 256 + threadIdx.x;
    int z = id / 36864, r = id % 36864, k = r >> 12, p = r & 4095;
    const float* ofz = offs + ((size_t)z * HW + p) * 18;
    float dy = ofz[2 * k], dx = ofz[2 * k + 1];
    int flat = k * 4096 + p;
    int P = flat / 9, jj = flat - P * 9;
    const float* ml = mlog + (size_t)z * 36864 + (size_t)P * 9;
    float l[9], mx = -1e30f;
#pragma unroll
    for (int i2 = 0; i2 < 9; i2++) { l[i2] = ml[i2]; mx = fmaxf(mx, l[i2]); }
    float sum = 0.f;
#pragma unroll
    for (int i2 = 0; i2 < 9; i2++) sum += expf(l[i2] - mx);
    float mk = expf(l[jj] - mx) / sum;
    int h = p >> 6, w = p & 63;
    float py = (float)(h - 1 + k / 3) + dy;
    float px = (float)(w - 1 + k % 3) + dx;
    float y0f = floorf(py), x0f = floorf(px);
    int y0 = (int)y0f, x0 = (int)x0f;
    float wy1 = py - y0f, wx1 = px - x0f, wy0 = 1.f - wy1, wx0 = 1.f - wx1;
    idx4o[id] = make_int4(cidx(y0, x0), cidx(y0, x0 + 1), cidx(y0 + 1, x0), cidx(y0 + 1, x0 + 1));
    w4o[id] = make_float4(wy0 * wx0 * cval(y0, x0) * mk, wy0 * wx1 * cval(y0, x0 + 1) * mk,
                          wy1 * wx0 * cval(y0 + 1, x0) * mk, wy1 * wx1 * cval(y0 + 1, x0 + 1) * mk);
}

// ---------------------------------------------------------------- batchnorm
__global__ void k_bnstats2(const u16* __restrict__ dout, float* __restrict__ pb1,
                           float* __restrict__ pb2) {
    const int z = blockIdx.z, seg = blockIdx.y;
    const int cx = threadIdx.x & 7, py = threadIdx.x >> 3;   // 8 cx x 32 py
    const int c0 = blockIdx.x * 64 + cx * 8;
    const u16* base = dout + (size_t)z * HW * CDIM + (size_t)(seg * 1024) * CDIM + c0;
    float s1[8] = {0.f, 0.f, 0.f, 0.f, 0.f, 0.f, 0.f, 0.f};
    float s2[8] = {0.f, 0.f, 0.f, 0.f, 0.f, 0.f, 0.f, 0.f};
    for (int p = py; p < 1024; p += 32) {
        uint4 v = *(const uint4*)(base + (size_t)p * CDIM);
        const u16* u = (const u16*)&v;
#pragma unroll
        for (int e = 0; e < 8; e++) {
            float f = bf2f(u[e]);
            s1[e] += f; s2[e] += f * f;
        }
    }
    __shared__ float l1[32][64], l2[32][64];
#pragma unroll
    for (int e = 0; e < 8; e++) {
        l1[py][cx * 8 + e] = s1[e];
        l2[py][cx * 8 + e] = s2[e];
    }
    __syncthreads();
    if (threadIdx.x < 64) {
        float a = 0.f, b = 0.f;
        for (int y = 0; y < 32; y++) { a += l1[y][threadIdx.x]; b += l2[y][threadIdx.x]; }
        int ch = blockIdx.x * 64 + threadIdx.x;
        pb1[(z * 4 + seg) * 768 + ch] = a;
        pb2[(z * 4 + seg) * 768 + ch] = b;
    }
}

__global__ void k_bnfinal(const float* __restrict__ pb1, const float* __restrict__ pb2,
                          float* __restrict__ mu, float* __restrict__ rs) {
    int i = blockIdx.x * 256 + threadIdx.x;
    if (i >= 3840) return;
    int z = i / 768, ch = i % 768;
    float a = 0.f, b = 0.f;
#pragma unroll
    for (int s = 0; s < 4; s++) {
        a += pb1[(z * 4 + s) * 768 + ch];
        b += pb2[(z * 4 + s) * 768 + ch];
    }
    float m = a / 4096.f;
    float var = b / 4096.f - m * m;
    mu[i] = m;
    rs[i] = rsqrtf(var + 1e-5f);
}

__global__ void k_bnapply(const u16* __restrict__ dout, const float* __restrict__ mu,
                          const float* __restrict__ rs, const float* __restrict__ g,
                          const float* __restrict__ b, u16* __restrict__ blk) {
    size_t i = ((size_t)blockIdx.x * 256 + threadIdx.x) * 8;
    int c = (int)(i % CDIM);
    int z = (int)(i / ((size_t)HW * CDIM));
    const float* muz = mu + z * 768;
    const float* rsz = rs + z * 768;
    uint4 in = *(const uint4*)(dout + i);
    const u16* u = (const u16*)&in;
    u16 o[8];
#pragma unroll
    for (int e = 0; e < 8; e++) {
        int ce = c + e;
        float v = (bf2f(u[e]) - muz[ce]) * rsz[ce] * g[ce] + b[ce];
        o[e] = f2bf(fmaxf(v, 0.f));
    }
    *(uint4*)(blk + i) = *(uint4*)o;
}

// ---------------------------------------------------------------- CAM
__global__ void k_q(const float* __restrict__ X, const float* __restrict__ chq,
                    float* __restrict__ q) {
    int wid = threadIdx.x >> 6, lane = threadIdx.x & 63;
    int p = blockIdx.x * 4 + wid;
    const float* xr = X + (size_t)p * CDIM;
    float s = 0.f;
#pragma unroll
    for (int j = 0; j < 12; j++) s += xr[lane + 64 * j] * chq[lane + 64 * j];
#pragma unroll
    for (int o = 32; o > 0; o >>= 1) s += __shfl_xor(s, o, 64);
    if (lane == 0) q[p] = s;
}

__global__ void k_soft4096(const float* __restrict__ q, float* __restrict__ sqn,
                           float* __restrict__ xq) {
    __shared__ float red[4];
    int tid = threadIdx.x, lane = tid & 63, wid = tid >> 6;
    float m = -1e30f;
    for (int i = tid; i < 4096; i += 256) m = fmaxf(m, q[i]);
    for (int o = 32; o > 0; o >>= 1) m = fmaxf(m, __shfl_xor(m, o, 64));
    if (lane == 0) red[wid] = m;
    __syncthreads();
    float bm = fmaxf(fmaxf(red[0], red[1]), fmaxf(red[2], red[3]));
    __syncthreads();
    float s = 0.f;
    for (int i = tid; i < 4096; i += 256) {
        float e = expf(q[i] - bm);
        sqn[i] = e; s += e;
    }
    for (int o = 32; o > 0; o >>= 1) s += __shfl_xor(s, o, 64);
    if (lane == 0) red[wid] = s;
    __syncthreads();
    float inv = 1.f / (red[0] + red[1] + red[2] + red[3]);
    for (int i = tid; i < 4096; i += 256) sqn[i] *= inv;
    for (int c = tid; c < 768; c += 256) xq[c] = 0.f;
}

__global__ void k_xq(const float* __restrict__ X, const float* __restrict__ sqn,
                     float* __restrict__ xq) {
    int p0 = blockIdx.x * 128;
    for (int c = threadIdx.x; c < 768; c += 256) {
        float a = 0.f;
        for (int p = p0; p < p0 + 128; p++) a += sqn[p] * X[(size_t)p * CDIM + c];
        atomicAdd(&xq[c], a);
    }
}

// wvq[o] = chv[o][:] . xq   (384 rows, wave per row)
__global__ void k_gemv384(const float* __restrict__ chv, const float* __restrict__ xq,
                          float* __restrict__ wvq) {
    int wid = threadIdx.x >> 6, lane = threadIdx.x & 63;
    int o = blockIdx.x * 4 + wid;
    const float* r = chv + (size_t)o * 768;
    float s = 0.f;
#pragma unroll
    for (int j = 0; j < 12; j++) s += r[lane + 64 * j] * xq[lane + 64 * j];
#pragma unroll
    for (int off = 32; off > 0; off >>= 1) s += __shfl_xor(s, off, 64);
    if (lane == 0) wvq[o] = s;
}

// wzv[c] = chz[c][:] . wvq   (768 rows, wave per row)
__global__ void k_gemv768(const float* __restrict__ chz, const float* __restrict__ wvq,
                          float* __restrict__ wzv) {
    int wid = threadIdx.x >> 6, lane = threadIdx.x & 63;
    int c = blockIdx.x * 4 + wid;
    const float* r = chz + (size_t)c * 384;
    float s = 0.f;
#pragma unroll
    for (int j = 0; j < 6; j++) s += r[lane + 64 * j] * wvq[lane + 64 * j];
#pragma unroll
    for (int off = 32; off > 0; off >>= 1) s += __shfl_xor(s, off, 64);
    if (lane == 0) wzv[c] = s;
}

// LN(768) + sigmoid -> sgate
__global__ void k_lngate(const float* __restrict__ wzv, const float* __restrict__ lng,
                         const float* __restrict__ lnb, float* __restrict__ sgate) {
    __shared__ float red[8];
    int tid = threadIdx.x, lane = tid & 63, wid = tid >> 6;
    float a = wzv[tid], b = wzv[tid + 256], c = wzv[tid + 512];
    float s1 = a + b + c, s2 = a * a + b * b + c * c;
    for (int o = 32; o > 0; o >>= 1) { s1 += __shfl_xor(s1, o, 64); s2 += __shfl_xor(s2, o, 64); }
    if (lane == 0) { red[wid] = s1; red[4 + wid] = s2; }
    __syncthreads();
    s1 = red[0] + red[1] + red[2] + red[3];
    s2 = red[4] + red[5] + red[6] + red[7];
    float mean = s1 / 768.f, var = s2 / 768.f - mean * mean, rstd = rsqrtf(var + 1e-5f);
    for (int cc = tid; cc < 768; cc += 256) {
        float tv = (wzv[cc] - mean) * rstd * lng[cc] + lnb[cc];
        sgate[cc] = 1.f / (1.f + expf(-tv));
    }
}

__global__ void k_xatt(const float* __restrict__ X, const float* __restrict__ sgate,
                       u16* __restrict__ xatt) {
    size_t i = ((size_t)blockIdx.x * 256 + threadIdx.x) * 4;
    int c = (int)(i % CDIM);
    float4 v = *(const float4*)(X + i);
    u16 o[4] = {f2bf(v.x * sgate[c]), f2bf(v.y * sgate[c + 1]),
                f2bf(v.z * sgate[c + 2]), f2bf(v.w * sgate[c + 3])};
    *(uint2*)(xatt + i) = *(uint2*)o;
}

// column max over P2[4096][384] — 24 blocks x 16 cols, coalesced
__global__ void k_colmax24(const float* __restrict__ P2, float* __restrict__ m2) {
    __shared__ float red[16][17];
    int col = blockIdx.x * 16 + threadIdx.x;
    float m = -1e30f;
    for (int p = threadIdx.y; p < 4096; p += 16) m = fmaxf(m, P2[(size_t)p * 384 + col]);
    red[threadIdx.y][threadIdx.x] = m;
    __syncthreads();
    if (threadIdx.y == 0) {
        for (int y = 1; y < 16; y++) m = fmaxf(m, red[y][threadIdx.x]);
        m2[col] = m;
    }
}

// softmax over 384 -> sq2
__global__ void k_sm384(const float* __restrict__ m2, float* __restrict__ sq2) {
    __shared__ float red[6];
    int tid = threadIdx.x, lane = tid & 63, wid = tid >> 6;
    float v = m2[tid];
    float m = v;
    for (int o = 32; o > 0; o >>= 1) m = fmaxf(m, __shfl_xor(m, o, 64));
    if (lane == 0) red[wid] = m;
    __syncthreads();
    m = red[0];
    for (int w = 1; w < 6; w++) m = fmaxf(m, red[w]);
    __syncthreads();
    float e = expf(v - m);
    float s = e;
    for (int o = 32; o > 0; o >>= 1) s += __shfl_xor(s, o, 64);
    if (lane == 0) red[wid] = s;
    __syncthreads();
    float tot = 0.f;
    for (int w = 0; w < 6; w++) tot += red[w];
    sq2[tid] = e / tot;
}

// sv[c] = sum_o sq2[o] * spv[o][c]  — 12 blocks x 64 cols, 4-way o-split
__global__ void k_sv(const float* __restrict__ sq2, const float* __restrict__ spv,
                     float* __restrict__ sv) {
    __shared__ float part[4][64];
    int c = blockIdx.x * 64 + (threadIdx.x & 63);
    int seg = threadIdx.x >> 6;
    float a = 0.f;
    for (int o = seg * 96; o < seg * 96 + 96; o++) a += sq2[o] * spv[(size_t)o * 768 + c];
    part[seg][threadIdx.x & 63] = a;
    __syncthreads();
    if (seg == 0) sv[c] = part[0][threadIdx.x] + part[1][threadIdx.x] +
                          part[2][threadIdx.x] + part[3][threadIdx.x];
}

__global__ void k_final(const float* __restrict__ X, const float* __restrict__ x5,
                        const float* __restrict__ sgate, const float* __restrict__ sv,
                        const float* __restrict__ ng, const float* __restrict__ nb,
                        float* __restrict__ out) {
    int wid = threadIdx.x >> 6, lane = threadIdx.x & 63;
    int p = blockIdx.x * 4 + wid;
    const float* xr = X + (size_t)p * CDIM;
    const float* x5r = x5 + (size_t)p * CDIM;
    float xa[12];
    float d = 0.f;
#pragma unroll
    for (int j = 0; j < 12; j++) {
        int c = lane + 64 * j;
        float a = xr[c] * sgate[c];
        xa[j] = a;
        d += sv[c] * a;
    }
#pragma unroll
    for (int o = 32; o > 0; o >>= 1) d += __shfl_xor(d, o, 64);
    float wz2 = 1.f / (1.f + expf(-d));
    float s1 = 0.f, s2 = 0.f;
#pragma unroll
    for (int j = 0; j < 12; j++) {
        int c = lane + 64 * j;
        float y = wz2 * xa[j] + xr[c] + x5r[c];
        xa[j] = y;
        s1 += y; s2 += y * y;
    }
#pragma unroll
    for (int o = 32; o > 0; o >>= 1) { s1 += __shfl_xor(s1, o, 64); s2 += __shfl_xor(s2, o, 64); }
    float mean = s1 / 768.f, var = s2 / 768.f - mean * mean, rstd = rsqrtf(var + 1e-5f);
#pragma unroll
    for (int j = 0; j < 12; j++) {
        int c = lane + 64 * j;
        out[(size_t)p * CDIM + c] = (xa[j] - mean) * rstd * ng[c] + nb[c];
    }
}

// ---------------------------------------------------------------- launch
extern "C" void kernel_launch(void* const* d_in, const int* in_sizes, int n_in,
                              void* d_out, int out_size, void* d_ws, size_t ws_size,
                              hipStream_t stream) {
    const float* xin[5];
    for (int i = 0; i < 5; i++) xin[i] = (const float*)d_in[i];
    const float* conv_w = (const float*)d_in[5];
    const float* conv_b = (const float*)d_in[6];
    const float* off_w = (const float*)d_in[7];
    const float* off_b = (const float*)d_in[8];
    const float* msk_w = (const float*)d_in[9];
    const float* msk_b = (const float*)d_in[10];
    const float* bn_g = (const float*)d_in[11];
    const float* bn_b = (const float*)d_in[12];
    const float* chq_w = (const float*)d_in[13];
    const float* chv_w = (const float*)d_in[14];
    const float* chz_w = (const float*)d_in[15];
    const float* ln_g = (const float*)d_in[16];
    const float* ln_b = (const float*)d_in[17];
    const float* spq_w = (const float*)d_in[18];
    const float* spv_w = (const float*)d_in[19];
    const float* wsrc[8];
    for (int i = 0; i < 8; i++) wsrc[i] = (const float*)d_in[20 + i];
    const float* norm_g = (const float*)d_in[28];
    const float* norm_b = (const float*)d_in[29];
    float* out = (float*)d_out;

    char* wsb = (char*)d_ws;
    size_t off = 0;
    auto take = [&](size_t n) -> char* {
        char* p = wsb + off;
        off = (off + n + 255) & ~(size_t)255;
        return p;
    };
    u16* xpad = (u16*)take(5ll * PPIX * CDIM * 2);
    u16* Wt = (u16*)take(9ll * CDIM * CDIM * 2);
    u16* omblk = (u16*)take(5ll * HW * CDIM * 2);
    float* offs = (float*)take(5ll * HW * 18 * 4);
    float* mlog = (float*)take(5ll * 36864 * 4);
    int4* idx4 = (int4*)take(5ll * 9 * 4096 * 16);
    float4* w4 = (float4*)take(5ll * 9 * 4096 * 16);
    u16* dout = (u16*)take(5ll * HW * CDIM * 2);
    u16* wb = (u16*)take(1790ll * 768 * 2);
    u16* OMW = (u16*)take(9ll * 32 * 768 * 2);
    float* bb = (float*)take(32 * 4);
    float* Xcat = (float*)take((size_t)HW * CDIM * 4);
    float* mu = (float*)take(5 * 768 * 4);
    float* rs = (float*)take(5 * 768 * 4);
    float* pb1 = (float*)take(5 * 4 * 768 * 4);
    float* pb2 = (float*)take(5 * 4 * 768 * 4);
    float* qv = (float*)take(4096 * 4);
    float* sqn = (float*)take(4096 * 4);
    float* xq = (float*)take(768 * 4);
    float* wvq = (float*)take(384 * 4);
    float* wzv = (float*)take(768 * 4);
    float* sgate = (float*)take(768 * 4);
    float* m2 = (float*)take(384 * 4);
    float* sq2 = (float*)take(384 * 4);
    float* sv = (float*)take(768 * 4);
    u16* xatt = dout;
    float* P2 = (float*)((char*)dout + 8388608);
    u16* blk = omblk;
    (void)ws_size; (void)in_sizes; (void)n_in; (void)out_size;

    int rows[9] = {30, 100, 150, 150, 220, 220, 268, 268, 384};
    int roff[9]; int acc = 0;
    for (int i = 0; i < 9; i++) { roff[i] = acc; acc += rows[i]; }
    u16* spqb = wb + (size_t)roff[8] * 768;

    WbP wp;
    for (int i = 0; i < 8; i++) { wp.src[i] = wsrc[i]; wp.dst[i] = wb + (size_t)roff[i] * 768; wp.n[i] = rows[i] * 768; }
    wp.src[8] = spq_w; wp.dst[8] = spqb; wp.n[8] = rows[8] * 768;

    ProjP pp;
    pp.b1[0] = wb + (size_t)roff[0] * 768; pp.b2[0] = nullptr;
    pp.b1[1] = wb + (size_t)roff[1] * 768; pp.b2[1] = nullptr;
    pp.b1[2] = wb + (size_t)roff[2] * 768; pp.b2[2] = wb + (size_t)roff[3] * 768;
    pp.b1[3] = wb + (size_t)roff[4] * 768; pp.b2[3] = wb + (size_t)roff[5] * 768;
    pp.b1[4] = wb + (size_t)roff[6] * 768; pp.b2[4] = wb + (size_t)roff[7] * 768;
    int chs[5] = {30, 100, 150, 220, 268};
    int cof[5] = {0, 30, 130, 280, 500};
    for (int i = 0; i < 5; i++) { pp.ch[i] = chs[i]; pp.choff[i] = cof[i]; }
    ProjP pdum = {};

    Ptr5 xs;
    for (int i = 0; i < 5; i++) xs.p[i] = xin[i];

    // ---- prep ----
    k_prep_xpad<<<dim3(PPIX, 5), 192, 0, stream>>>(xs, xpad);
    k_prep_wt<<<dim3(768), 256, 0, stream>>>(conv_w, Wt);
    k_prep_wb<<<dim3(288, 9), 256, 0, stream>>>(wp);
    k_fold<<<dim3(3, 9, 3), 256, 0, stream>>>(Wt, off_w, msk_w, OMW);
    k_bias27<<<dim3(7), 256, 0, stream>>>(off_w, msk_w, conv_b, off_b, msk_b, bb);

    // ---- heavy path ----
    k_convOM<<<dim3(32, 1, 5), 512, 0, stream>>>(xpad, OMW, bb, offs, mlog);
    k_offmask2<<<dim3(720), 256, 0, stream>>>(offs, mlog, idx4, w4);
    k_gdef<<<dim3(480), 512, 0, stream>>>(xpad, Wt, idx4, w4, conv_b, dout);
    k_bnstats2<<<dim3(12, 4, 5), 256, 0, stream>>>(dout, pb1, pb2);
    k_bnfinal<<<dim3(15), 256, 0, stream>>>(pb1, pb2, mu, rs);
    k_bnapply<<<dim3(7680), 256, 0, stream>>>(dout, mu, rs, bn_g, bn_b, blk);
    k_gemm128<G_PROJ><<<dim3(32, 3, 5), 256, 0, stream>>>(xpad, blk, nullptr, nullptr,
                                                          nullptr, Xcat, pp);

    // ---- CAM ----
    k_q<<<dim3(1024), 256, 0, stream>>>(Xcat, chq_w, qv);
    k_soft4096<<<dim3(1), 256, 0, stream>>>(qv, sqn, xq);
    k_xq<<<dim3(32), 256, 0, stream>>>(Xcat, sqn, xq);
    k_gemv384<<<dim3(96), 256, 0, stream>>>(chv_w, xq, wvq);
    k_gemv768<<<dim3(192), 256, 0, stream>>>(chz_w, wvq, wzv);
    k_lngate<<<dim3(1), 256, 0, stream>>>(wzv, ln_g, ln_b, sgate);
    k_xatt<<<dim3(3072), 256, 0, stream>>>(Xcat, sgate, xatt);
    k_gemm128<G_SPAT><<<dim3(32, 3, 1), 256, 0, stream>>>(xpad, xatt, spqb, nullptr,
                                                          nullptr, P2, pdum);
    k_colmax24<<<dim3(24), dim3(16, 16), 0, stream>>>(P2, m2);
    k_sm384<<<dim3(1), 384, 0, stream>>>(m2, sq2);
    k_sv<<<dim3(12), 256, 0, stream>>>(sq2, spv_w, sv);

    // ---- residual + final LayerNorm ----
    k_final<<<dim3(1024), 256, 0, stream>>>(Xcat, xin[4], sgate, sv, norm_g, norm_b, out);
}

// Round 9
// 821.603 us; speedup vs baseline: 1.2249x; 1.0465x over previous
//
#include <hip/hip_runtime.h>
#include <cstdint>
#include <cstddef>

#define HW 4096
#define CDIM 768
#define PPIX 4356   // 66*66 padded pixels

typedef unsigned short u16;
typedef __attribute__((ext_vector_type(8))) short short8;
typedef __attribute__((ext_vector_type(4))) float f32x4;

__device__ __forceinline__ float bf2f(u16 u) { return __uint_as_float(((unsigned)u) << 16); }
__device__ __forceinline__ u16 f2bf(float f) {
    unsigned u = __float_as_uint(f);
    unsigned r = (u + 0x7fffu + ((u >> 16) & 1u)) >> 16;
    return (u16)r;
}
__device__ __forceinline__ float lof(unsigned u) { return __uint_as_float(u << 16); }
__device__ __forceinline__ float hif(unsigned u) { return __uint_as_float(u & 0xffff0000u); }
__device__ __forceinline__ int swz(int r) { return ((r >> 1) ^ (r >> 3)) & 3; }

__device__ __forceinline__ void gl16(const u16* g, u16* l) {
    __builtin_amdgcn_global_load_lds(
        (const __attribute__((address_space(1))) unsigned int*)g,
        (__attribute__((address_space(3))) unsigned int*)l, 16, 0, 0);
}

enum GMode { G_CONV = 0, G_PROJ = 2, G_SPAT = 3 };

struct ProjP {
    const u16* b1[5];
    const u16* b2[5];
    int ch[5];
    int choff[5];
};

// ---------------------------------------------------------------- 128x128 GEMM
// m97-shape: single LDS buffer (16KB), 2 barriers/step, 4 blocks/CU.
// Used for PROJ / SPAT (small-N) only.
template <int MODE>
__launch_bounds__(256, 4)
__global__ void k_gemm128(const u16* __restrict__ xpad, const u16* __restrict__ blkA,
                          const u16* __restrict__ Wt, const float* __restrict__ bias,
                          u16* __restrict__ outb, float* __restrict__ outf, ProjP pp) {
    const int z = blockIdx.z;
    const int m0 = blockIdx.x * 128;
    const int n0 = blockIdx.y * 128;

    int Nrows, ntap, choff = 0, ldo = CDIM;
    const u16 *Az = nullptr, *Ac = nullptr, *B1 = nullptr, *B2 = nullptr;
    if constexpr (MODE == G_CONV) {
        Az = xpad + (size_t)z * PPIX * CDIM; B1 = Wt; Nrows = 768; ntap = 9;
    } else if constexpr (MODE == G_PROJ) {
        Ac = blkA + (size_t)z * HW * CDIM;
        Az = xpad + (size_t)z * PPIX * CDIM;
        B1 = pp.b1[z]; B2 = pp.b2[z];
        Nrows = pp.ch[z]; choff = pp.choff[z];
        ntap = B2 ? 2 : 1;
        if (n0 >= Nrows) return;
    } else { // G_SPAT
        Ac = blkA; B1 = Wt; Nrows = 384; ntap = 1; ldo = 384;
    }

    __shared__ __align__(16) u16 As[128 * 32];
    __shared__ __align__(16) u16 Bs[128 * 32];

    const int t = threadIdx.x;
    const int lane = t & 63;
    const int wid = t >> 6;
    const int wrow = (wid >> 1) * 64, wcol = (wid & 1) * 64;
    const int lm = lane & 15;
    const int quad = lane >> 4;

    const int rS = t >> 2;
    const int cs0 = (t & 3) ^ swz(rS);
    const int cs1 = (t & 3) ^ swz(64 + rS);

    // A base pointers (element units)
    const u16 *a0 = nullptr, *a1 = nullptr, *a0x = nullptr, *a1x = nullptr;
    if constexpr (MODE == G_CONV) {
        int p0 = m0 + rS, p1 = m0 + 64 + rS;
        a0 = Az + (size_t)(((p0 >> 6)) * 66 + (p0 & 63)) * CDIM + cs0 * 8;
        a1 = Az + (size_t)(((p1 >> 6)) * 66 + (p1 & 63)) * CDIM + cs1 * 8;
    } else if constexpr (MODE == G_PROJ) {
        int p0 = m0 + rS, p1 = m0 + 64 + rS;
        a0 = Ac + (size_t)p0 * CDIM + cs0 * 8;
        a1 = Ac + (size_t)p1 * CDIM + cs1 * 8;
        a0x = Az + (size_t)(((p0 >> 6) + 1) * 66 + (p0 & 63) + 1) * CDIM + cs0 * 8;
        a1x = Az + (size_t)(((p1 >> 6) + 1) * 66 + (p1 & 63) + 1) * CDIM + cs1 * 8;
    } else {
        a0 = Ac + (size_t)(m0 + rS) * CDIM + cs0 * 8;
        a1 = Ac + (size_t)(m0 + 64 + rS) * CDIM + cs1 * 8;
    }
    // B base pointers
    const u16* b0 = B1 + (size_t)(n0 + rS) * CDIM + cs0 * 8;
    const u16* b1p = B1 + (size_t)(n0 + 64 + rS) * CDIM + cs1 * 8;
    const u16 *c0 = nullptr, *c1 = nullptr;
    if constexpr (MODE == G_PROJ) {
        if (B2) {
            c0 = B2 + (size_t)(n0 + rS) * CDIM + cs0 * 8;
            c1 = B2 + (size_t)(n0 + 64 + rS) * CDIM + cs1 * 8;
        }
    }

    u16* dA0 = &As[(0 * 4 + wid) * 512];
    u16* dA1 = &As[(1 * 4 + wid) * 512];
    u16* dB0 = &Bs[(0 * 4 + wid) * 512];
    u16* dB1 = &Bs[(1 * 4 + wid) * 512];

    f32x4 acc[4][4];
#pragma unroll
    for (int i = 0; i < 4; i++)
#pragma unroll
        for (int j = 0; j < 4; j++) acc[i][j] = (f32x4){0.f, 0.f, 0.f, 0.f};

    const int totS = ntap * 24;
    int tap = 0;
    int tA = 0, tB = 0, kO = 0;

    for (int s = 0; s < totS; ++s) {
        __syncthreads();
        if constexpr (MODE == G_CONV) {
            gl16(a0 + tA + kO, dA0);
            gl16(a1 + tA + kO, dA1);
            gl16(b0 + tB + kO, dB0);
            gl16(b1p + tB + kO, dB1);
        } else if constexpr (MODE == G_PROJ) {
            if (tap == 0) {
                gl16(a0 + kO, dA0);
                gl16(a1 + kO, dA1);
                gl16(b0 + kO, dB0);
                gl16(b1p + kO, dB1);
            } else {
                gl16(a0x + kO, dA0);
                gl16(a1x + kO, dA1);
                gl16(c0 + kO, dB0);
                gl16(c1 + kO, dB1);
            }
        } else {
            gl16(a0 + kO, dA0);
            gl16(a1 + kO, dA1);
            gl16(b0 + kO, dB0);
            gl16(b1p + kO, dB1);
        }
        __syncthreads();
        short8 af[4], bf[4];
#pragma unroll
        for (int i = 0; i < 4; i++) {
            int rr = wrow + i * 16 + lm;
            af[i] = *(const short8*)&As[rr * 32 + ((quad ^ swz(rr)) * 8)];
        }
#pragma unroll
        for (int j = 0; j < 4; j++) {
            int rr = wcol + j * 16 + lm;
            bf[j] = *(const short8*)&Bs[rr * 32 + ((quad ^ swz(rr)) * 8)];
        }
#pragma unroll
        for (int i = 0; i < 4; i++)
#pragma unroll
            for (int j = 0; j < 4; j++)
                acc[i][j] = __builtin_amdgcn_mfma_f32_16x16x32_bf16(af[i], bf[j], acc[i][j], 0, 0, 0);
        // advance (tap fastest, then kk)
        tap++;
        if constexpr (MODE == G_CONV) {
            tA += (tap == 3 || tap == 6) ? 64 * CDIM : CDIM;
            tB += CDIM * CDIM;
            if (tap == 9) { tap = 0; tA = 0; tB = 0; kO += 32; }
        } else {
            if (tap == ntap) { tap = 0; kO += 32; }
        }
    }

    // ---- epilogue ----
    if constexpr (MODE == G_CONV) {
        u16* outz = outb + (size_t)z * HW * CDIM;
#pragma unroll
        for (int j = 0; j < 4; j++) {
            int gc = n0 + wcol + j * 16 + lm;
            float bv = bias[gc];
#pragma unroll
            for (int i = 0; i < 4; i++)
#pragma unroll
                for (int r = 0; r < 4; r++) {
                    int gr = m0 + wrow + i * 16 + quad * 4 + r;
                    outz[(size_t)gr * CDIM + gc] = f2bf(acc[i][j][r] + bv);
                }
        }
    } else {
#pragma unroll
        for (int j = 0; j < 4; j++) {
            int gc = n0 + wcol + j * 16 + lm;
            if (gc < Nrows) {
#pragma unroll
                for (int i = 0; i < 4; i++)
#pragma unroll
                    for (int r = 0; r < 4; r++) {
                        int gr = m0 + wrow + i * 16 + quad * 4 + r;
                        outf[(size_t)gr * ldo + choff + gc] = acc[i][j][r];
                    }
            }
        }
    }
}

// XCD-aware bijective swizzle for 480-block GEMMs (480 % 8 == 0, 60/XCD).
__device__ __forceinline__ void xcd_decode(int bid, int& m0, int& n0, int& z) {
    int work = (bid & 7) * 60 + (bid >> 3);
    z = work / 96;
    int rem = work - z * 96;
    n0 = (rem >> 5) * 256;
    m0 = (rem & 31) * 128;
}

// ---------------------------------------------------------------- folded offset/mask weights
// OMW[t][q][c] = sum_o OW27[q][o] * Wt[t][o][c]  (q<18: off_w row, else msk_w).
// OW staged in LDS in 256-o chunks (9.2KB — 64KB static LDS limit, R7 lesson).
__global__ void k_fold(const u16* __restrict__ Wt, const float* __restrict__ off_w,
                       const float* __restrict__ msk_w, u16* __restrict__ OMW) {
    const int cb = blockIdx.x, tp = blockIdx.y, qg = blockIdx.z;
    const int q0 = qg * 9;
    __shared__ float ow[256 * 9];
    const int c = cb * 256 + threadIdx.x;
    const u16* wcol = Wt + (size_t)tp * 768 * 768 + c;
    float acc[9];
#pragma unroll
    for (int qi = 0; qi < 9; qi++) acc[qi] = 0.f;
    for (int ob = 0; ob < 768; ob += 256) {
        __syncthreads();
#pragma unroll
        for (int qi = 0; qi < 9; qi++) {
            int q = q0 + qi;
            const float* src = (q < 18) ? (off_w + (size_t)q * 768)
                                        : (msk_w + (size_t)(q - 18) * 768);
            ow[threadIdx.x * 9 + qi] = src[ob + threadIdx.x];
        }
        __syncthreads();
#pragma unroll 4
        for (int oo = 0; oo < 256; oo++) {
            float w = bf2f(wcol[(size_t)(ob + oo) * 768]);
#pragma unroll
            for (int qi = 0; qi < 9; qi++) acc[qi] = fmaf(w, ow[oo * 9 + qi], acc[qi]);
        }
    }
#pragma unroll
    for (int qi = 0; qi < 9; qi++)
        OMW[((size_t)tp * 32 + q0 + qi) * 768 + c] = f2bf(acc[qi]);
    if (qg == 2) {
        for (int q = 27; q < 32; q++) OMW[((size_t)tp * 32 + q) * 768 + c] = 0;
    }
}

// bb[q] = OW27[q] . conv_b + (off_b|msk_b)[q]   (27 rows, wave per row)
__global__ void k_bias27(const float* __restrict__ off_w, const float* __restrict__ msk_w,
                         const float* __restrict__ conv_b, const float* __restrict__ off_b,
                         const float* __restrict__ msk_b, float* __restrict__ bb) {
    int wid = threadIdx.x >> 6, lane = threadIdx.x & 63;
    int q = blockIdx.x * 4 + wid;
    if (q >= 27) return;
    const float* r = (q < 18) ? (off_w + (size_t)q * 768) : (msk_w + (size_t)(q - 18) * 768);
    float s = 0.f;
#pragma unroll
    for (int j = 0; j < 12; j++) s += r[lane + 64 * j] * conv_b[lane + 64 * j];
#pragma unroll
    for (int o = 32; o > 0; o >>= 1) s += __shfl_xor(s, o, 64);
    if (lane == 0) bb[q] = s + ((q < 18) ? off_b[q] : msk_b[q - 18]);
}

// ---------------------------------------------------------------- thin offset/mask conv
// Tap-split 3-way (taps 3p..3p+2 per block, 72 steps) -> 480 blocks (~2/CU);
// convOM was latency-bound at 160 blocks x 216 steps (R8 lesson). Blocks
// write f32 partials pOM[z][part][4096][32]; k_omsum folds bias + sum.
__launch_bounds__(512, 4)
__global__ void k_convOM(const u16* __restrict__ xpad, const u16* __restrict__ OMW,
                         float* __restrict__ pOM) {
    const int z = blockIdx.z;
    const int part = blockIdx.y;          // tap group: 3*part .. 3*part+2 (same dy)
    const int m0 = blockIdx.x * 128;
    const u16* Az = xpad + (size_t)z * PPIX * CDIM + (size_t)part * 66 * CDIM;

    __shared__ __align__(16) u16 As[2][128 * 32];
    __shared__ __align__(16) u16 Bs[2][32 * 32];

    const int t = threadIdx.x;
    const int lane = t & 63;
    const int wid = t >> 6;
    const int lm = lane & 15;
    const int quad = lane >> 4;

    const int rA = t >> 2;
    const int cA = (t & 3) ^ swz(rA);
    const int p0 = m0 + rA;
    const u16* aB = Az + (size_t)((p0 >> 6) * 66 + (p0 & 63)) * CDIM + cA * 8;

    // B rows 0..31 staged by threads 0..127 (waves 0,1 — wave-uniform branch)
    const int rB = t >> 2;
    const int cB = (t & 3) ^ swz(rB);
    const u16* bB = OMW + (size_t)(part * 3) * 32 * 768 + (size_t)rB * 768 + cB * 8;

    f32x4 acc[2];
    acc[0] = (f32x4){0.f, 0.f, 0.f, 0.f};
    acc[1] = (f32x4){0.f, 0.f, 0.f, 0.f};

    gl16(aB, &As[0][wid * 512]);
    if (t < 128) gl16(bB, &Bs[0][wid * 512]);

    int tloc = 0, tA = 0, tB = 0, kO = 0;
    for (int s = 0; s < 72; ++s) {
        const int cur = s & 1, nxt = cur ^ 1;
        __syncthreads();
        const bool hasN = (s + 1 < 72);
        if (hasN) {
            // advance within group: dx 0->1->2 (same dy), then kk++
            tloc++;
            tA += CDIM;
            tB += 32 * 768;
            if (tloc == 3) { tloc = 0; tA = 0; tB = 0; kO += 32; }
            gl16(aB + tA + kO, &As[nxt][wid * 512]);
            if (t < 128) gl16(bB + tB + kO, &Bs[nxt][wid * 512]);
        }
        int ar = wid * 16 + lm;
        short8 af = *(const short8*)&As[cur][ar * 32 + ((quad ^ swz(ar)) * 8)];
#pragma unroll
        for (int j = 0; j < 2; j++) {
            int rr = j * 16 + lm;
            short8 bf = *(const short8*)&Bs[cur][rr * 32 + ((quad ^ swz(rr)) * 8)];
            acc[j] = __builtin_amdgcn_mfma_f32_16x16x32_bf16(af, bf, acc[j], 0, 0, 0);
        }
    }

    float* outp = pOM + (((size_t)z * 3 + part) * HW) * 32;
#pragma unroll
    for (int j = 0; j < 2; j++) {
        int gc = j * 16 + lm;
#pragma unroll
        for (int r = 0; r < 4; r++) {
            int gr = m0 + wid * 16 + quad * 4 + r;
            outp[(size_t)gr * 32 + gc] = acc[j][r];
        }
    }
}

// sum 3 tap-group partials + folded bias -> offs / mlog (layouts unchanged)
__global__ void k_omsum(const float* __restrict__ pOM, const float* __restrict__ bb,
                        float* __restrict__ offs, float* __restrict__ mlog) {
    int id = blockIdx.x * 256 + threadIdx.x;   // over 5*4096*32
    int q = id & 31;
    int p = (id >> 5) & 4095;
    int z = id >> 17;
    if (q >= 27) return;
    const float* base = pOM + (((size_t)z * 3) * HW + p) * 32 + q;
    float v = base[0] + base[(size_t)HW * 32] + base[(size_t)2 * HW * 32] + bb[q];
    if (q < 18) offs[((size_t)z * HW + p) * 18 + q] = v;
    else mlog[(size_t)z * 36864 + (size_t)p * 9 + (q - 18)] = v;
}

// ---------------------------------------------------------------- deform GEMM (128x256, dbuf)
// R1/R4-proven schedule: scalar fmaf blend + v_perm pack, linear t*8 As
// write, 32-elem rows. Do NOT restructure the blend dataflow (R3 lesson).
// Occupancy is REGISTER-limited: 64 VGPR + 64 AGPR = 128 unified regs ->
// 16 waves/CU = 2 blocks, regardless of grid (R5 lesson — K-split was null).
__launch_bounds__(512, 4)
__global__ void k_gdef(const u16* __restrict__ xpad, const u16* __restrict__ Wt,
                       const int4* __restrict__ idx4, const float4* __restrict__ w4,
                       const float* __restrict__ bias, u16* __restrict__ outb) {
    int m0, n0, z;
    xcd_decode(blockIdx.x, m0, n0, z);
    const u16* Az = xpad + (size_t)z * PPIX * CDIM;
    const int4* idxz = idx4 + (size_t)z * 9 * 4096;
    const float4* w4z = w4 + (size_t)z * 9 * 4096;

    __shared__ __align__(16) u16 As[2][128 * 32];
    __shared__ __align__(16) u16 Bs[2][256 * 32];

    const int t = threadIdx.x;
    const int lane = t & 63;
    const int wid = t >> 6;
    const int wrow = (wid >> 2) * 64, wcol = (wid & 3) * 64;
    const int lm = lane & 15;
    const int quad = lane >> 4;

    // staging coords: one 8-elem chunk of A per thread, two of B
    const int rA = t >> 2;
    const int cA = (t & 3) ^ swz(rA);
    const int rB0 = t >> 2;
    const int cB0 = (t & 3) ^ swz(rB0);
    const int rB1 = 128 + (t >> 2);
    const int cB1 = (t & 3) ^ swz(rB1);

    f32x4 acc[4][4];
#pragma unroll
    for (int i = 0; i < 4; i++)
#pragma unroll
        for (int j = 0; j < 4; j++) acc[i][j] = (f32x4){0.f, 0.f, 0.f, 0.f};

    const u16* bP0;
    const u16* bP1;
    int dOff[4];
    float4 wv;

    auto setupSub = [&](int sn) {
        const u16* Bb = Wt + (size_t)sn * CDIM * CDIM;
        bP0 = Bb + (size_t)(n0 + rB0) * CDIM + cB0 * 8;
        bP1 = Bb + (size_t)(n0 + rB1) * CDIM + cB1 * 8;
        int4 iv = idxz[sn * 4096 + m0 + rA];
        wv = w4z[sn * 4096 + m0 + rA];
        dOff[0] = (iv.x + cA * 8) * 2;
        dOff[1] = (iv.y + cA * 8) * 2;
        dOff[2] = (iv.z + cA * 8) * 2;
        dOff[3] = (iv.w + cA * 8) * 2;
    };

    auto blend4 = [&](const uint4* L) -> uint4 {
        auto bl = [&](unsigned a, unsigned b, unsigned c2, unsigned d) -> unsigned {
            float lo = fmaf(wv.x, lof(a), fmaf(wv.y, lof(b), fmaf(wv.z, lof(c2), wv.w * lof(d))));
            float hi = fmaf(wv.x, hif(a), fmaf(wv.y, hif(b), fmaf(wv.z, hif(c2), wv.w * hif(d))));
            // dst = (hi & 0xffff0000) | (lo >> 16) in one v_perm_b32
            return __builtin_amdgcn_perm(__float_as_uint(hi), __float_as_uint(lo), 0x07060302u);
        };
        uint4 o;
        o.x = bl(L[0].x, L[1].x, L[2].x, L[3].x);
        o.y = bl(L[0].y, L[1].y, L[2].y, L[3].y);
        o.z = bl(L[0].z, L[1].z, L[2].z, L[3].z);
        o.w = bl(L[0].w, L[1].w, L[2].w, L[3].w);
        return o;
    };

    setupSub(0);
    int stagedSub = 0;

    {   // prologue: stage step 0 into buf 0
        uint4 L[4];
#pragma unroll
        for (int k = 0; k < 4; k++)
            L[k] = *(const uint4*)((const char*)Az + dOff[k]);
        gl16(bP0, &Bs[0][wid * 512]);
        gl16(bP1, &Bs[0][4096 + wid * 512]);
        uint4 o = blend4(L);
        *(uint4*)&As[0][t * 8] = o;
    }

    for (int s = 0; s < 216; ++s) {
        const int cur = s & 1;
        const int nxt = cur ^ 1;
        __syncthreads();
        const bool hasN = (s + 1 < 216);
        uint4 L[4];
        if (hasN) {
            int kn = (s + 1) - stagedSub * 24;
            if (kn == 24) { setupSub(++stagedSub); kn = 0; }
            const int cb = kn * 64;  // byte advance along K
#pragma unroll
            for (int k = 0; k < 4; k++)
                L[k] = *(const uint4*)((const char*)Az + dOff[k] + cb);
            gl16(bP0 + kn * 32, &Bs[nxt][wid * 512]);
            gl16(bP1 + kn * 32, &Bs[nxt][4096 + wid * 512]);
        }
        short8 af[4];
#pragma unroll
        for (int i = 0; i < 4; i++) {
            int rr = wrow + i * 16 + lm;
            af[i] = *(const short8*)&As[cur][rr * 32 + ((quad ^ swz(rr)) * 8)];
        }
#pragma unroll
        for (int j = 0; j < 4; j++) {
            int rr = wcol + j * 16 + lm;
            short8 bf = *(const short8*)&Bs[cur][rr * 32 + ((quad ^ swz(rr)) * 8)];
#pragma unroll
            for (int i = 0; i < 4; i++)
                acc[i][j] = __builtin_amdgcn_mfma_f32_16x16x32_bf16(af[i], bf, acc[i][j], 0, 0, 0);
        }
        if (hasN) {
            uint4 o = blend4(L);
            *(uint4*)&As[nxt][t * 8] = o;
        }
    }

    u16* outz = outb + (size_t)z * HW * CDIM;
#pragma unroll
    for (int j = 0; j < 4; j++) {
        int gc = n0 + wcol + j * 16 + lm;
        float bv = bias[gc];
#pragma unroll
        for (int i = 0; i < 4; i++)
#pragma unroll
            for (int r = 0; r < 4; r++) {
                int gr = m0 + wrow + i * 16 + quad * 4 + r;
                outz[(size_t)gr * CDIM + gc] = f2bf(acc[i][j][r] + bv);
            }
    }
}

// ---------------------------------------------------------------- prep kernels
struct Ptr5 { const float* p[5]; };

__global__ void k_prep_xpad(Ptr5 xs, u16* __restrict__ xpad) {
    int z = blockIdx.y;
    int pidx = blockIdx.x;
    int ph = pidx / 66, pw = pidx - ph * 66;
    int e0 = threadIdx.x * 4;
    u16* d = xpad + ((size_t)z * PPIX + pidx) * CDIM + e0;
    if (ph == 0 || ph == 65 || pw == 0 || pw == 65) {
        *(uint2*)d = make_uint2(0, 0);
        return;
    }
    const float* s = xs.p[z] + ((size_t)((ph - 1) * 64 + (pw - 1))) * CDIM + e0;
    float4 v = *(const float4*)s;
    u16 o[4] = {f2bf(v.x), f2bf(v.y), f2bf(v.z), f2bf(v.w)};
    *(uint2*)d = *(uint2*)o;
}

__global__ void k_prep_wt(const float* __restrict__ cw, u16* __restrict__ Wt) {
    int o = blockIdx.x;
    for (int c = threadIdx.x; c < 768; c += 256) {
        const float* s = cw + ((size_t)o * 768 + c) * 9;
#pragma unroll
        for (int k = 0; k < 9; k++)
            Wt[(size_t)k * 768 * 768 + (size_t)o * 768 + c] = f2bf(s[k]);
    }
}

struct WbP { const float* src[9]; u16* dst[9]; int n[9]; };

__global__ void k_prep_wb(WbP wp) {
    int m = blockIdx.y;
    int i = (blockIdx.x * 256 + threadIdx.x) * 4;
    if (i >= wp.n[m]) return;
    float4 v = *(const float4*)(wp.src[m] + i);
    u16* d = wp.dst[m] + i;
    d[0] = f2bf(v.x); d[1] = f2bf(v.y); d[2] = f2bf(v.z); d[3] = f2bf(v.w);
}

// ---------------------------------------------------------------- offset / mask sample prep
__device__ __forceinline__ int cidx(int y, int x) {
    int yc = min(max(y, 0), 63), xc = min(max(x, 0), 63);
    return ((yc + 1) * 66 + (xc + 1)) * CDIM;
}
__device__ __forceinline__ float cval(int y, int x) {
    return (y >= 0 && y < 64 && x >= 0 && x < 64) ? 1.f : 0.f;
}

// softmax over the 9 logits of the ORIGINAL pixel P folded in (torch raw-reshape
// semantics: mask flat index k*4096+p belongs to pixel (k*4096+p)/9, slot %9).
__global__ void k_offmask2(const float* __restrict__ offs, const float* __restrict__ mlog,
                           int4* __restrict__ idx4o, float4* __restrict__ w4o) {
    int id = blockIdx.x * 256 + threadIdx.x;
    int z = id / 36864, r = id % 36864, k = r >> 12, p = r & 4095;
    const float* ofz = offs + ((size_t)z * HW + p) * 18;
    float dy = ofz[2 * k], dx = ofz[2 * k + 1];
    int flat = k * 4096 + p;
    int P = flat / 9, jj = flat - P * 9;
    const float* ml = mlog + (size_t)z * 36864 + (size_t)P * 9;
    float l[9], mx = -1e30f;
#pragma unroll
    for (int i2 = 0; i2 < 9; i2++) { l[i2] = ml[i2]; mx = fmaxf(mx, l[i2]); }
    float sum = 0.f;
#pragma unroll
    for (int i2 = 0; i2 < 9; i2++) sum += expf(l[i2] - mx);
    float mk = expf(l[jj] - mx) / sum;
    int h = p >> 6, w = p & 63;
    float py = (float)(h - 1 + k / 3) + dy;
    float px = (float)(w - 1 + k % 3) + dx;
    float y0f = floorf(py), x0f = floorf(px);
    int y0 = (int)y0f, x0 = (int)x0f;
    float wy1 = py - y0f, wx1 = px - x0f, wy0 = 1.f - wy1, wx0 = 1.f - wx1;
    idx4o[id] = make_int4(cidx(y0, x0), cidx(y0, x0 + 1), cidx(y0 + 1, x0), cidx(y0 + 1, x0 + 1));
    w4o[id] = make_float4(wy0 * wx0 * cval(y0, x0) * mk, wy0 * wx1 * cval(y0, x0 + 1) * mk,
                          wy1 * wx0 * cval(y0 + 1, x0) * mk, wy1 * wx1 * cval(y0 + 1, x0 + 1) * mk);
}

// ---------------------------------------------------------------- batchnorm
__global__ void k_bnstats2(const u16* __restrict__ dout, float* __restrict__ pb1,
                           float* __restrict__ pb2) {
    const int z = blockIdx.z, seg = blockIdx.y;
    const int cx = threadIdx.x & 7, py = threadIdx.x >> 3;   // 8 cx x 32 py
    const int c0 = blockIdx.x * 64 + cx * 8;
    const u16* base = dout + (size_t)z * HW * CDIM + (size_t)(seg * 1024) * CDIM + c0;
    float s1[8] = {0.f, 0.f, 0.f, 0.f, 0.f, 0.f, 0.f, 0.f};
    float s2[8] = {0.f, 0.f, 0.f, 0.f, 0.f, 0.f, 0.f, 0.f};
    for (int p = py; p < 1024; p += 32) {
        uint4 v = *(const uint4*)(base + (size_t)p * CDIM);
        const u16* u = (const u16*)&v;
#pragma unroll
        for (int e = 0; e < 8; e++) {
            float f = bf2f(u[e]);
            s1[e] += f; s2[e] += f * f;
        }
    }
    __shared__ float l1[32][64], l2[32][64];
#pragma unroll
    for (int e = 0; e < 8; e++) {
        l1[py][cx * 8 + e] = s1[e];
        l2[py][cx * 8 + e] = s2[e];
    }
    __syncthreads();
    if (threadIdx.x < 64) {
        float a = 0.f, b = 0.f;
        for (int y = 0; y < 32; y++) { a += l1[y][threadIdx.x]; b += l2[y][threadIdx.x]; }
        int ch = blockIdx.x * 64 + threadIdx.x;
        pb1[(z * 4 + seg) * 768 + ch] = a;
        pb2[(z * 4 + seg) * 768 + ch] = b;
    }
}

__global__ void k_bnfinal(const float* __restrict__ pb1, const float* __restrict__ pb2,
                          float* __restrict__ mu, float* __restrict__ rs) {
    int i = blockIdx.x * 256 + threadIdx.x;
    if (i >= 3840) return;
    int z = i / 768, ch = i % 768;
    float a = 0.f, b = 0.f;
#pragma unroll
    for (int s = 0; s < 4; s++) {
        a += pb1[(z * 4 + s) * 768 + ch];
        b += pb2[(z * 4 + s) * 768 + ch];
    }
    float m = a / 4096.f;
    float var = b / 4096.f - m * m;
    mu[i] = m;
    rs[i] = rsqrtf(var + 1e-5f);
}

__global__ void k_bnapply(const u16* __restrict__ dout, const float* __restrict__ mu,
                          const float* __restrict__ rs, const float* __restrict__ g,
                          const float* __restrict__ b, u16* __restrict__ blk) {
    size_t i = ((size_t)blockIdx.x * 256 + threadIdx.x) * 8;
    int c = (int)(i % CDIM);
    int z = (int)(i / ((size_t)HW * CDIM));
    const float* muz = mu + z * 768;
    const float* rsz = rs + z * 768;
    uint4 in = *(const uint4*)(dout + i);
    const u16* u = (const u16*)&in;
    u16 o[8];
#pragma unroll
    for (int e = 0; e < 8; e++) {
        int ce = c + e;
        float v = (bf2f(u[e]) - muz[ce]) * rsz[ce] * g[ce] + b[ce];
        o[e] = f2bf(fmaxf(v, 0.f));
    }
    *(uint4*)(blk + i) = *(uint4*)o;
}

// ---------------------------------------------------------------- CAM
__global__ void k_q(const float* __restrict__ X, const float* __restrict__ chq,
                    float* __restrict__ q) {
    int wid = threadIdx.x >> 6, lane = threadIdx.x & 63;
    int p = blockIdx.x * 4 + wid;
    const float* xr = X + (size_t)p * CDIM;
    float s = 0.f;
#pragma unroll
    for (int j = 0; j < 12; j++) s += xr[lane + 64 * j] * chq[lane + 64 * j];
#pragma unroll
    for (int o = 32; o > 0; o >>= 1) s += __shfl_xor(s, o, 64);
    if (lane == 0) q[p] = s;
}

__global__ void k_soft4096(const float* __restrict__ q, float* __restrict__ sqn,
                           float* __restrict__ xq) {
    __shared__ float red[4];
    int tid = threadIdx.x, lane = tid & 63, wid = tid >> 6;
    float m = -1e30f;
    for (int i = tid; i < 4096; i += 256) m = fmaxf(m, q[i]);
    for (int o = 32; o > 0; o >>= 1) m = fmaxf(m, __shfl_xor(m, o, 64));
    if (lane == 0) red[wid] = m;
    __syncthreads();
    float bm = fmaxf(fmaxf(red[0], red[1]), fmaxf(red[2], red[3]));
    __syncthreads();
    float s = 0.f;
    for (int i = tid; i < 4096; i += 256) {
        float e = expf(q[i] - bm);
        sqn[i] = e; s += e;
    }
    for (int o = 32; o > 0; o >>= 1) s += __shfl_xor(s, o, 64);
    if (lane == 0) red[wid] = s;
    __syncthreads();
    float inv = 1.f / (red[0] + red[1] + red[2] + red[3]);
    for (int i = tid; i < 4096; i += 256) sqn[i] *= inv;
    for (int c = tid; c < 768; c += 256) xq[c] = 0.f;
}

__global__ void k_xq(const float* __restrict__ X, const float* __restrict__ sqn,
                     float* __restrict__ xq) {
    int p0 = blockIdx.x * 128;
    for (int c = threadIdx.x; c < 768; c += 256) {
        float a = 0.f;
        for (int p = p0; p < p0 + 128; p++) a += sqn[p] * X[(size_t)p * CDIM + c];
        atomicAdd(&xq[c], a);
    }
}

// wvq[o] = chv[o][:] . xq   (384 rows, wave per row)
__global__ void k_gemv384(const float* __restrict__ chv, const float* __restrict__ xq,
                          float* __restrict__ wvq) {
    int wid = threadIdx.x >> 6, lane = threadIdx.x & 63;
    int o = blockIdx.x * 4 + wid;
    const float* r = chv + (size_t)o * 768;
    float s = 0.f;
#pragma unroll
    for (int j = 0; j < 12; j++) s += r[lane + 64 * j] * xq[lane + 64 * j];
#pragma unroll
    for (int off = 32; off > 0; off >>= 1) s += __shfl_xor(s, off, 64);
    if (lane == 0) wvq[o] = s;
}

// wzv[c] = chz[c][:] . wvq   (768 rows, wave per row)
__global__ void k_gemv768(const float* __restrict__ chz, const float* __restrict__ wvq,
                          float* __restrict__ wzv) {
    int wid = threadIdx.x >> 6, lane = threadIdx.x & 63;
    int c = blockIdx.x * 4 + wid;
    const float* r = chz + (size_t)c * 384;
    float s = 0.f;
#pragma unroll
    for (int j = 0; j < 6; j++) s += r[lane + 64 * j] * wvq[lane + 64 * j];
#pragma unroll
    for (int off = 32; off > 0; off >>= 1) s += __shfl_xor(s, off, 64);
    if (lane == 0) wzv[c] = s;
}

// LN(768) + sigmoid -> sgate
__global__ void k_lngate(const float* __restrict__ wzv, const float* __restrict__ lng,
                         const float* __restrict__ lnb, float* __restrict__ sgate) {
    __shared__ float red[8];
    int tid = threadIdx.x, lane = tid & 63, wid = tid >> 6;
    float a = wzv[tid], b = wzv[tid + 256], c = wzv[tid + 512];
    float s1 = a + b + c, s2 = a * a + b * b + c * c;
    for (int o = 32; o > 0; o >>= 1) { s1 += __shfl_xor(s1, o, 64); s2 += __shfl_xor(s2, o, 64); }
    if (lane == 0) { red[wid] = s1; red[4 + wid] = s2; }
    __syncthreads();
    s1 = red[0] + red[1] + red[2] + red[3];
    s2 = red[4] + red[5] + red[6] + red[7];
    float mean = s1 / 768.f, var = s2 / 768.f - mean * mean, rstd = rsqrtf(var + 1e-5f);
    for (int cc = tid; cc < 768; cc += 256) {
        float tv = (wzv[cc] - mean) * rstd * lng[cc] + lnb[cc];
        sgate[cc] = 1.f / (1.f + expf(-tv));
    }
}

__global__ void k_xatt(const float* __restrict__ X, const float* __restrict__ sgate,
                       u16* __restrict__ xatt) {
    size_t i = ((size_t)blockIdx.x * 256 + threadIdx.x) * 4;
    int c = (int)(i % CDIM);
    float4 v = *(const float4*)(X + i);
    u16 o[4] = {f2bf(v.x * sgate[c]), f2bf(v.y * sgate[c + 1]),
                f2bf(v.z * sgate[c + 2]), f2bf(v.w * sgate[c + 3])};
    *(uint2*)(xatt + i) = *(uint2*)o;
}

// column max over P2[4096][384] — 24 blocks x 16 cols, coalesced
__global__ void k_colmax24(const float* __restrict__ P2, float* __restrict__ m2) {
    __shared__ float red[16][17];
    int col = blockIdx.x * 16 + threadIdx.x;
    float m = -1e30f;
    for (int p = threadIdx.y; p < 4096; p += 16) m = fmaxf(m, P2[(size_t)p * 384 + col]);
    red[threadIdx.y][threadIdx.x] = m;
    __syncthreads();
    if (threadIdx.y == 0) {
        for (int y = 1; y < 16; y++) m = fmaxf(m, red[y][threadIdx.x]);
        m2[col] = m;
    }
}

// softmax over 384 -> sq2
__global__ void k_sm384(const float* __restrict__ m2, float* __restrict__ sq2) {
    __shared__ float red[6];
    int tid = threadIdx.x, lane = tid & 63, wid = tid >> 6;
    float v = m2[tid];
    float m = v;
    for (int o = 32; o > 0; o >>= 1) m = fmaxf(m, __shfl_xor(m, o, 64));
    if (lane == 0) red[wid] = m;
    __syncthreads();
    m = red[0];
    for (int w = 1; w < 6; w++) m = fmaxf(m, red[w]);
    __syncthreads();
    float e = expf(v - m);
    float s = e;
    for (int o = 32; o > 0; o >>= 1) s += __shfl_xor(s, o, 64);
    if (lane == 0) red[wid] = s;
    __syncthreads();
    float tot = 0.f;
    for (int w = 0; w < 6; w++) tot += red[w];
    sq2[tid] = e / tot;
}

// sv[c] = sum_o sq2[o] * spv[o][c]  — 12 blocks x 64 cols, 4-way o-split
__global__ void k_sv(const float* __restrict__ sq2, const float* __restrict__ spv,
                     float* __restrict__ sv) {
    __shared__ float part[4][64];
    int c = blockIdx.x * 64 + (threadIdx.x & 63);
    int seg = threadIdx.x >> 6;
    float a = 0.f;
    for (int o = seg * 96; o < seg * 96 + 96; o++) a += sq2[o] * spv[(size_t)o * 768 + c];
    part[seg][threadIdx.x & 63] = a;
    __syncthreads();
    if (seg == 0) sv[c] = part[0][threadIdx.x] + part[1][threadIdx.x] +
                          part[2][threadIdx.x] + part[3][threadIdx.x];
}

__global__ void k_final(const float* __restrict__ X, const float* __restrict__ x5,
                        const float* __restrict__ sgate, const float* __restrict__ sv,
                        const float* __restrict__ ng, const float* __restrict__ nb,
                        float* __restrict__ out) {
    int wid = threadIdx.x >> 6, lane = threadIdx.x & 63;
    int p = blockIdx.x * 4 + wid;
    const float* xr = X + (size_t)p * CDIM;
    const float* x5r = x5 + (size_t)p * CDIM;
    float xa[12];
    float d = 0.f;
#pragma unroll
    for (int j = 0; j < 12; j++) {
        int c = lane + 64 * j;
        float a = xr[c] * sgate[c];
        xa[j] = a;
        d += sv[c] * a;
    }
#pragma unroll
    for (int o = 32; o > 0; o >>= 1) d += __shfl_xor(d, o, 64);
    float wz2 = 1.f / (1.f + expf(-d));
    float s1 = 0.f, s2 = 0.f;
#pragma unroll
    for (int j = 0; j < 12; j++) {
        int c = lane + 64 * j;
        float y = wz2 * xa[j] + xr[c] + x5r[c];
        xa[j] = y;
        s1 += y; s2 += y * y;
    }
#pragma unroll
    for (int o = 32; o > 0; o >>= 1) { s1 += __shfl_xor(s1, o, 64); s2 += __shfl_xor(s2, o, 64); }
    float mean = s1 / 768.f, var = s2 / 768.f - mean * mean, rstd = rsqrtf(var + 1e-5f);
#pragma unroll
    for (int j = 0; j < 12; j++) {
        int c = lane + 64 * j;
        out[(size_t)p * CDIM + c] = (xa[j] - mean) * rstd * ng[c] + nb[c];
    }
}

// ---------------------------------------------------------------- launch
extern "C" void kernel_launch(void* const* d_in, const int* in_sizes, int n_in,
                              void* d_out, int out_size, void* d_ws, size_t ws_size,
                              hipStream_t stream) {
    const float* xin[5];
    for (int i = 0; i < 5; i++) xin[i] = (const float*)d_in[i];
    const float* conv_w = (const float*)d_in[5];
    const float* conv_b = (const float*)d_in[6];
    const float* off_w = (const float*)d_in[7];
    const float* off_b = (const float*)d_in[8];
    const float* msk_w = (const float*)d_in[9];
    const float* msk_b = (const float*)d_in[10];
    const float* bn_g = (const float*)d_in[11];
    const float* bn_b = (const float*)d_in[12];
    const float* chq_w = (const float*)d_in[13];
    const float* chv_w = (const float*)d_in[14];
    const float* chz_w = (const float*)d_in[15];
    const float* ln_g = (const float*)d_in[16];
    const float* ln_b = (const float*)d_in[17];
    const float* spq_w = (const float*)d_in[18];
    const float* spv_w = (const float*)d_in[19];
    const float* wsrc[8];
    for (int i = 0; i < 8; i++) wsrc[i] = (const float*)d_in[20 + i];
    const float* norm_g = (const float*)d_in[28];
    const float* norm_b = (const float*)d_in[29];
    float* out = (float*)d_out;

    char* wsb = (char*)d_ws;
    size_t off = 0;
    auto take = [&](size_t n) -> char* {
        char* p = wsb + off;
        off = (off + n + 255) & ~(size_t)255;
        return p;
    };
    u16* xpad = (u16*)take(5ll * PPIX * CDIM * 2);
    u16* Wt = (u16*)take(9ll * CDIM * CDIM * 2);
    u16* omblk = (u16*)take(5ll * HW * CDIM * 2);
    float* offs = (float*)take(5ll * HW * 18 * 4);
    float* mlog = (float*)take(5ll * 36864 * 4);
    int4* idx4 = (int4*)take(5ll * 9 * 4096 * 16);
    float4* w4 = (float4*)take(5ll * 9 * 4096 * 16);
    u16* dout = (u16*)take(5ll * HW * CDIM * 2);
    u16* wb = (u16*)take(1790ll * 768 * 2);
    u16* OMW = (u16*)take(9ll * 32 * 768 * 2);
    float* bb = (float*)take(32 * 4);
    float* pOM = (float*)take(5ll * 3 * HW * 32 * 4);
    float* Xcat = (float*)take((size_t)HW * CDIM * 4);
    float* mu = (float*)take(5 * 768 * 4);
    float* rs = (float*)take(5 * 768 * 4);
    float* pb1 = (float*)take(5 * 4 * 768 * 4);
    float* pb2 = (float*)take(5 * 4 * 768 * 4);
    float* qv = (float*)take(4096 * 4);
    float* sqn = (float*)take(4096 * 4);
    float* xq = (float*)take(768 * 4);
    float* wvq = (float*)take(384 * 4);
    float* wzv = (float*)take(768 * 4);
    float* sgate = (float*)take(768 * 4);
    float* m2 = (float*)take(384 * 4);
    float* sq2 = (float*)take(384 * 4);
    float* sv = (float*)take(768 * 4);
    u16* xatt = dout;
    float* P2 = (float*)((char*)dout + 8388608);
    u16* blk = omblk;
    (void)ws_size; (void)in_sizes; (void)n_in; (void)out_size;

    int rows[9] = {30, 100, 150, 150, 220, 220, 268, 268, 384};
    int roff[9]; int acc = 0;
    for (int i = 0; i < 9; i++) { roff[i] = acc; acc += rows[i]; }
    u16* spqb = wb + (size_t)roff[8] * 768;

    WbP wp;
    for (int i = 0; i < 8; i++) { wp.src[i] = wsrc[i]; wp.dst[i] = wb + (size_t)roff[i] * 768; wp.n[i] = rows[i] * 768; }
    wp.src[8] = spq_w; wp.dst[8] = spqb; wp.n[8] = rows[8] * 768;

    ProjP pp;
    pp.b1[0] = wb + (size_t)roff[0] * 768; pp.b2[0] = nullptr;
    pp.b1[1] = wb + (size_t)roff[1] * 768; pp.b2[1] = nullptr;
    pp.b1[2] = wb + (size_t)roff[2] * 768; pp.b2[2] = wb + (size_t)roff[3] * 768;
    pp.b1[3] = wb + (size_t)roff[4] * 768; pp.b2[3] = wb + (size_t)roff[5] * 768;
    pp.b1[4] = wb + (size_t)roff[6] * 768; pp.b2[4] = wb + (size_t)roff[7] * 768;
    int chs[5] = {30, 100, 150, 220, 268};
    int cof[5] = {0, 30, 130, 280, 500};
    for (int i = 0; i < 5; i++) { pp.ch[i] = chs[i]; pp.choff[i] = cof[i]; }
    ProjP pdum = {};

    Ptr5 xs;
    for (int i = 0; i < 5; i++) xs.p[i] = xin[i];

    // ---- prep ----
    k_prep_xpad<<<dim3(PPIX, 5), 192, 0, stream>>>(xs, xpad);
    k_prep_wt<<<dim3(768), 256, 0, stream>>>(conv_w, Wt);
    k_prep_wb<<<dim3(288, 9), 256, 0, stream>>>(wp);
    k_fold<<<dim3(3, 9, 3), 256, 0, stream>>>(Wt, off_w, msk_w, OMW);
    k_bias27<<<dim3(7), 256, 0, stream>>>(off_w, msk_w, conv_b, off_b, msk_b, bb);

    // ---- heavy path ----
    k_convOM<<<dim3(32, 3, 5), 512, 0, stream>>>(xpad, OMW, pOM);
    k_omsum<<<dim3(2560), 256, 0, stream>>>(pOM, bb, offs, mlog);
    k_offmask2<<<dim3(720), 256, 0, stream>>>(offs, mlog, idx4, w4);
    k_gdef<<<dim3(480), 512, 0, stream>>>(xpad, Wt, idx4, w4, conv_b, dout);
    k_bnstats2<<<dim3(12, 4, 5), 256, 0, stream>>>(dout, pb1, pb2);
    k_bnfinal<<<dim3(15), 256, 0, stream>>>(pb1, pb2, mu, rs);
    k_bnapply<<<dim3(7680), 256, 0, stream>>>(dout, mu, rs, bn_g, bn_b, blk);
    k_gemm128<G_PROJ><<<dim3(32, 3, 5), 256, 0, stream>>>(xpad, blk, nullptr, nullptr,
                                                          nullptr, Xcat, pp);

    // ---- CAM ----
    k_q<<<dim3(1024), 256, 0, stream>>>(Xcat, chq_w, qv);
    k_soft4096<<<dim3(1), 256, 0, stream>>>(qv, sqn, xq);
    k_xq<<<dim3(32), 256, 0, stream>>>(Xcat, sqn, xq);
    k_gemv384<<<dim3(96), 256, 0, stream>>>(chv_w, xq, wvq);
    k_gemv768<<<dim3(192), 256, 0, stream>>>(chz_w, wvq, wzv);
    k_lngate<<<dim3(1), 256, 0, stream>>>(wzv, ln_g, ln_b, sgate);
    k_xatt<<<dim3(3072), 256, 0, stream>>>(Xcat, sgate, xatt);
    k_gemm128<G_SPAT><<<dim3(32, 3, 1), 256, 0, stream>>>(xpad, xatt, spqb, nullptr,
                                                          nullptr, P2, pdum);
    k_colmax24<<<dim3(24), dim3(16, 16), 0, stream>>>(P2, m2);
    k_sm384<<<dim3(1), 384, 0, stream>>>(m2, sq2);
    k_sv<<<dim3(12), 256, 0, stream>>>(sq2, spv_w, sv);

    // ---- residual + final LayerNorm ----
    k_final<<<dim3(1024), 256, 0, stream>>>(Xcat, xin[4], sgate, sv, norm_g, norm_b, out);
}

// Round 10
// 800.612 us; speedup vs baseline: 1.2570x; 1.0262x over previous
//
#include <hip/hip_runtime.h>
#include <cstdint>
#include <cstddef>

#define HW 4096
#define CDIM 768
#define PPIX 4356   // 66*66 padded pixels

typedef unsigned short u16;
typedef __attribute__((ext_vector_type(8))) short short8;
typedef __attribute__((ext_vector_type(4))) float f32x4;

__device__ __forceinline__ float bf2f(u16 u) { return __uint_as_float(((unsigned)u) << 16); }
__device__ __forceinline__ u16 f2bf(float f) {
    unsigned u = __float_as_uint(f);
    unsigned r = (u + 0x7fffu + ((u >> 16) & 1u)) >> 16;
    return (u16)r;
}
__device__ __forceinline__ float lof(unsigned u) { return __uint_as_float(u << 16); }
__device__ __forceinline__ float hif(unsigned u) { return __uint_as_float(u & 0xffff0000u); }
__device__ __forceinline__ int swz(int r) { return ((r >> 1) ^ (r >> 3)) & 3; }

__device__ __forceinline__ void gl16(const u16* g, u16* l) {
    __builtin_amdgcn_global_load_lds(
        (const __attribute__((address_space(1))) unsigned int*)g,
        (__attribute__((address_space(3))) unsigned int*)l, 16, 0, 0);
}

enum GMode { G_CONV = 0, G_PROJ = 2, G_SPAT = 3 };

struct ProjP {
    const u16* b1[5];
    const u16* b2[5];
    int ch[5];
    int choff[5];
};

// ---------------------------------------------------------------- 128x128 GEMM
// m97-shape: single LDS buffer (16KB), 2 barriers/step, 4 blocks/CU.
// Used for PROJ / SPAT (small-N) only.
template <int MODE>
__launch_bounds__(256, 4)
__global__ void k_gemm128(const u16* __restrict__ xpad, const u16* __restrict__ blkA,
                          const u16* __restrict__ Wt, const float* __restrict__ bias,
                          u16* __restrict__ outb, float* __restrict__ outf, ProjP pp) {
    const int z = blockIdx.z;
    const int m0 = blockIdx.x * 128;
    const int n0 = blockIdx.y * 128;

    int Nrows, ntap, choff = 0, ldo = CDIM;
    const u16 *Az = nullptr, *Ac = nullptr, *B1 = nullptr, *B2 = nullptr;
    if constexpr (MODE == G_CONV) {
        Az = xpad + (size_t)z * PPIX * CDIM; B1 = Wt; Nrows = 768; ntap = 9;
    } else if constexpr (MODE == G_PROJ) {
        Ac = blkA + (size_t)z * HW * CDIM;
        Az = xpad + (size_t)z * PPIX * CDIM;
        B1 = pp.b1[z]; B2 = pp.b2[z];
        Nrows = pp.ch[z]; choff = pp.choff[z];
        ntap = B2 ? 2 : 1;
        if (n0 >= Nrows) return;
    } else { // G_SPAT
        Ac = blkA; B1 = Wt; Nrows = 384; ntap = 1; ldo = 384;
    }

    __shared__ __align__(16) u16 As[128 * 32];
    __shared__ __align__(16) u16 Bs[128 * 32];

    const int t = threadIdx.x;
    const int lane = t & 63;
    const int wid = t >> 6;
    const int wrow = (wid >> 1) * 64, wcol = (wid & 1) * 64;
    const int lm = lane & 15;
    const int quad = lane >> 4;

    const int rS = t >> 2;
    const int cs0 = (t & 3) ^ swz(rS);
    const int cs1 = (t & 3) ^ swz(64 + rS);

    // A base pointers (element units)
    const u16 *a0 = nullptr, *a1 = nullptr, *a0x = nullptr, *a1x = nullptr;
    if constexpr (MODE == G_CONV) {
        int p0 = m0 + rS, p1 = m0 + 64 + rS;
        a0 = Az + (size_t)(((p0 >> 6)) * 66 + (p0 & 63)) * CDIM + cs0 * 8;
        a1 = Az + (size_t)(((p1 >> 6)) * 66 + (p1 & 63)) * CDIM + cs1 * 8;
    } else if constexpr (MODE == G_PROJ) {
        int p0 = m0 + rS, p1 = m0 + 64 + rS;
        a0 = Ac + (size_t)p0 * CDIM + cs0 * 8;
        a1 = Ac + (size_t)p1 * CDIM + cs1 * 8;
        a0x = Az + (size_t)(((p0 >> 6) + 1) * 66 + (p0 & 63) + 1) * CDIM + cs0 * 8;
        a1x = Az + (size_t)(((p1 >> 6) + 1) * 66 + (p1 & 63) + 1) * CDIM + cs1 * 8;
    } else {
        a0 = Ac + (size_t)(m0 + rS) * CDIM + cs0 * 8;
        a1 = Ac + (size_t)(m0 + 64 + rS) * CDIM + cs1 * 8;
    }
    // B base pointers
    const u16* b0 = B1 + (size_t)(n0 + rS) * CDIM + cs0 * 8;
    const u16* b1p = B1 + (size_t)(n0 + 64 + rS) * CDIM + cs1 * 8;
    const u16 *c0 = nullptr, *c1 = nullptr;
    if constexpr (MODE == G_PROJ) {
        if (B2) {
            c0 = B2 + (size_t)(n0 + rS) * CDIM + cs0 * 8;
            c1 = B2 + (size_t)(n0 + 64 + rS) * CDIM + cs1 * 8;
        }
    }

    u16* dA0 = &As[(0 * 4 + wid) * 512];
    u16* dA1 = &As[(1 * 4 + wid) * 512];
    u16* dB0 = &Bs[(0 * 4 + wid) * 512];
    u16* dB1 = &Bs[(1 * 4 + wid) * 512];

    f32x4 acc[4][4];
#pragma unroll
    for (int i = 0; i < 4; i++)
#pragma unroll
        for (int j = 0; j < 4; j++) acc[i][j] = (f32x4){0.f, 0.f, 0.f, 0.f};

    const int totS = ntap * 24;
    int tap = 0;
    int tA = 0, tB = 0, kO = 0;

    for (int s = 0; s < totS; ++s) {
        __syncthreads();
        if constexpr (MODE == G_CONV) {
            gl16(a0 + tA + kO, dA0);
            gl16(a1 + tA + kO, dA1);
            gl16(b0 + tB + kO, dB0);
            gl16(b1p + tB + kO, dB1);
        } else if constexpr (MODE == G_PROJ) {
            if (tap == 0) {
                gl16(a0 + kO, dA0);
                gl16(a1 + kO, dA1);
                gl16(b0 + kO, dB0);
                gl16(b1p + kO, dB1);
            } else {
                gl16(a0x + kO, dA0);
                gl16(a1x + kO, dA1);
                gl16(c0 + kO, dB0);
                gl16(c1 + kO, dB1);
            }
        } else {
            gl16(a0 + kO, dA0);
            gl16(a1 + kO, dA1);
            gl16(b0 + kO, dB0);
            gl16(b1p + kO, dB1);
        }
        __syncthreads();
        short8 af[4], bf[4];
#pragma unroll
        for (int i = 0; i < 4; i++) {
            int rr = wrow + i * 16 + lm;
            af[i] = *(const short8*)&As[rr * 32 + ((quad ^ swz(rr)) * 8)];
        }
#pragma unroll
        for (int j = 0; j < 4; j++) {
            int rr = wcol + j * 16 + lm;
            bf[j] = *(const short8*)&Bs[rr * 32 + ((quad ^ swz(rr)) * 8)];
        }
#pragma unroll
        for (int i = 0; i < 4; i++)
#pragma unroll
            for (int j = 0; j < 4; j++)
                acc[i][j] = __builtin_amdgcn_mfma_f32_16x16x32_bf16(af[i], bf[j], acc[i][j], 0, 0, 0);
        // advance (tap fastest, then kk)
        tap++;
        if constexpr (MODE == G_CONV) {
            tA += (tap == 3 || tap == 6) ? 64 * CDIM : CDIM;
            tB += CDIM * CDIM;
            if (tap == 9) { tap = 0; tA = 0; tB = 0; kO += 32; }
        } else {
            if (tap == ntap) { tap = 0; kO += 32; }
        }
    }

    // ---- epilogue ----
    if constexpr (MODE == G_CONV) {
        u16* outz = outb + (size_t)z * HW * CDIM;
#pragma unroll
        for (int j = 0; j < 4; j++) {
            int gc = n0 + wcol + j * 16 + lm;
            float bv = bias[gc];
#pragma unroll
            for (int i = 0; i < 4; i++)
#pragma unroll
                for (int r = 0; r < 4; r++) {
                    int gr = m0 + wrow + i * 16 + quad * 4 + r;
                    outz[(size_t)gr * CDIM + gc] = f2bf(acc[i][j][r] + bv);
                }
        }
    } else {
#pragma unroll
        for (int j = 0; j < 4; j++) {
            int gc = n0 + wcol + j * 16 + lm;
            if (gc < Nrows) {
#pragma unroll
                for (int i = 0; i < 4; i++)
#pragma unroll
                    for (int r = 0; r < 4; r++) {
                        int gr = m0 + wrow + i * 16 + quad * 4 + r;
                        outf[(size_t)gr * ldo + choff + gc] = acc[i][j][r];
                    }
            }
        }
    }
}

// XCD-aware bijective swizzle for 480-block GEMMs (480 % 8 == 0, 60/XCD).
__device__ __forceinline__ void xcd_decode(int bid, int& m0, int& n0, int& z) {
    int work = (bid & 7) * 60 + (bid >> 3);
    z = work / 96;
    int rem = work - z * 96;
    n0 = (rem >> 5) * 256;
    m0 = (rem & 31) * 128;
}

// ---------------------------------------------------------------- folded offset/mask weights
// OMW[t][q][c] = sum_o OW27[q][o] * Wt[t][o][c]  (q<18: off_w row, else msk_w).
// OW staged in LDS in 256-o chunks (9.2KB — 64KB static LDS limit, R7 lesson).
__global__ void k_fold(const u16* __restrict__ Wt, const float* __restrict__ off_w,
                       const float* __restrict__ msk_w, u16* __restrict__ OMW) {
    const int cb = blockIdx.x, tp = blockIdx.y, qg = blockIdx.z;
    const int q0 = qg * 9;
    __shared__ float ow[256 * 9];
    const int c = cb * 256 + threadIdx.x;
    const u16* wcol = Wt + (size_t)tp * 768 * 768 + c;
    float acc[9];
#pragma unroll
    for (int qi = 0; qi < 9; qi++) acc[qi] = 0.f;
    for (int ob = 0; ob < 768; ob += 256) {
        __syncthreads();
#pragma unroll
        for (int qi = 0; qi < 9; qi++) {
            int q = q0 + qi;
            const float* src = (q < 18) ? (off_w + (size_t)q * 768)
                                        : (msk_w + (size_t)(q - 18) * 768);
            ow[threadIdx.x * 9 + qi] = src[ob + threadIdx.x];
        }
        __syncthreads();
#pragma unroll 4
        for (int oo = 0; oo < 256; oo++) {
            float w = bf2f(wcol[(size_t)(ob + oo) * 768]);
#pragma unroll
            for (int qi = 0; qi < 9; qi++) acc[qi] = fmaf(w, ow[oo * 9 + qi], acc[qi]);
        }
    }
#pragma unroll
    for (int qi = 0; qi < 9; qi++)
        OMW[((size_t)tp * 32 + q0 + qi) * 768 + c] = f2bf(acc[qi]);
    if (qg == 2) {
        for (int q = 27; q < 32; q++) OMW[((size_t)tp * 32 + q) * 768 + c] = 0;
    }
}

// bb[q] = OW27[q] . conv_b + (off_b|msk_b)[q]   (27 rows, wave per row)
__global__ void k_bias27(const float* __restrict__ off_w, const float* __restrict__ msk_w,
                         const float* __restrict__ conv_b, const float* __restrict__ off_b,
                         const float* __restrict__ msk_b, float* __restrict__ bb) {
    int wid = threadIdx.x >> 6, lane = threadIdx.x & 63;
    int q = blockIdx.x * 4 + wid;
    if (q >= 27) return;
    const float* r = (q < 18) ? (off_w + (size_t)q * 768) : (msk_w + (size_t)(q - 18) * 768);
    float s = 0.f;
#pragma unroll
    for (int j = 0; j < 12; j++) s += r[lane + 64 * j] * conv_b[lane + 64 * j];
#pragma unroll
    for (int o = 32; o > 0; o >>= 1) s += __shfl_xor(s, o, 64);
    if (lane == 0) bb[q] = s + ((q < 18) ? off_b[q] : msk_b[q - 18]);
}

// ---------------------------------------------------------------- thin offset/mask conv
// Tap-split 3-way (taps 3p..3p+2 per block, 72 steps) -> 480 blocks (~2/CU).
// Blocks write f32 partials pOM[z][part][4096][32]; summed in k_offmask2.
__launch_bounds__(512, 4)
__global__ void k_convOM(const u16* __restrict__ xpad, const u16* __restrict__ OMW,
                         float* __restrict__ pOM) {
    const int z = blockIdx.z;
    const int part = blockIdx.y;          // tap group: 3*part .. 3*part+2 (same dy)
    const int m0 = blockIdx.x * 128;
    const u16* Az = xpad + (size_t)z * PPIX * CDIM + (size_t)part * 66 * CDIM;

    __shared__ __align__(16) u16 As[2][128 * 32];
    __shared__ __align__(16) u16 Bs[2][32 * 32];

    const int t = threadIdx.x;
    const int lane = t & 63;
    const int wid = t >> 6;
    const int lm = lane & 15;
    const int quad = lane >> 4;

    const int rA = t >> 2;
    const int cA = (t & 3) ^ swz(rA);
    const int p0 = m0 + rA;
    const u16* aB = Az + (size_t)((p0 >> 6) * 66 + (p0 & 63)) * CDIM + cA * 8;

    // B rows 0..31 staged by threads 0..127 (waves 0,1 — wave-uniform branch)
    const int rB = t >> 2;
    const int cB = (t & 3) ^ swz(rB);
    const u16* bB = OMW + (size_t)(part * 3) * 32 * 768 + (size_t)rB * 768 + cB * 8;

    f32x4 acc[2];
    acc[0] = (f32x4){0.f, 0.f, 0.f, 0.f};
    acc[1] = (f32x4){0.f, 0.f, 0.f, 0.f};

    gl16(aB, &As[0][wid * 512]);
    if (t < 128) gl16(bB, &Bs[0][wid * 512]);

    int tloc = 0, tA = 0, tB = 0, kO = 0;
    for (int s = 0; s < 72; ++s) {
        const int cur = s & 1, nxt = cur ^ 1;
        __syncthreads();
        const bool hasN = (s + 1 < 72);
        if (hasN) {
            // advance within group: dx 0->1->2 (same dy), then kk++
            tloc++;
            tA += CDIM;
            tB += 32 * 768;
            if (tloc == 3) { tloc = 0; tA = 0; tB = 0; kO += 32; }
            gl16(aB + tA + kO, &As[nxt][wid * 512]);
            if (t < 128) gl16(bB + tB + kO, &Bs[nxt][wid * 512]);
        }
        int ar = wid * 16 + lm;
        short8 af = *(const short8*)&As[cur][ar * 32 + ((quad ^ swz(ar)) * 8)];
#pragma unroll
        for (int j = 0; j < 2; j++) {
            int rr = j * 16 + lm;
            short8 bf = *(const short8*)&Bs[cur][rr * 32 + ((quad ^ swz(rr)) * 8)];
            acc[j] = __builtin_amdgcn_mfma_f32_16x16x32_bf16(af, bf, acc[j], 0, 0, 0);
        }
    }

    float* outp = pOM + (((size_t)z * 3 + part) * HW) * 32;
#pragma unroll
    for (int j = 0; j < 2; j++) {
        int gc = j * 16 + lm;
#pragma unroll
        for (int r = 0; r < 4; r++) {
            int gr = m0 + wid * 16 + quad * 4 + r;
            outp[(size_t)gr * 32 + gc] = acc[j][r];
        }
    }
}

// ---------------------------------------------------------------- deform GEMM (128x256, dbuf)
// R1/R4-proven schedule: scalar fmaf blend + v_perm pack, linear t*8 As
// write, 32-elem rows. Do NOT restructure the blend dataflow (R3 lesson).
// Occupancy is REGISTER-limited: 64 VGPR + 64 AGPR = 128 unified regs ->
// 16 waves/CU = 2 blocks, regardless of grid (R5 lesson — K-split was null).
// Epilogue fuses BN partial stats (f32 pre-rounding) -> pb1/pb2 atomics;
// pb zeroed by k_offmask2 (completes earlier in stream order).
__launch_bounds__(512, 4)
__global__ void k_gdef(const u16* __restrict__ xpad, const u16* __restrict__ Wt,
                       const int4* __restrict__ idx4, const float4* __restrict__ w4,
                       const float* __restrict__ bias, u16* __restrict__ outb,
                       float* __restrict__ pb1, float* __restrict__ pb2) {
    int m0, n0, z;
    xcd_decode(blockIdx.x, m0, n0, z);
    const u16* Az = xpad + (size_t)z * PPIX * CDIM;
    const int4* idxz = idx4 + (size_t)z * 9 * 4096;
    const float4* w4z = w4 + (size_t)z * 9 * 4096;

    __shared__ __align__(16) u16 As[2][128 * 32];
    __shared__ __align__(16) u16 Bs[2][256 * 32];
    __shared__ float r1[256], r2[256];

    const int t = threadIdx.x;
    const int lane = t & 63;
    const int wid = t >> 6;
    const int wrow = (wid >> 2) * 64, wcol = (wid & 3) * 64;
    const int lm = lane & 15;
    const int quad = lane >> 4;

    // staging coords: one 8-elem chunk of A per thread, two of B
    const int rA = t >> 2;
    const int cA = (t & 3) ^ swz(rA);
    const int rB0 = t >> 2;
    const int cB0 = (t & 3) ^ swz(rB0);
    const int rB1 = 128 + (t >> 2);
    const int cB1 = (t & 3) ^ swz(rB1);

    f32x4 acc[4][4];
#pragma unroll
    for (int i = 0; i < 4; i++)
#pragma unroll
        for (int j = 0; j < 4; j++) acc[i][j] = (f32x4){0.f, 0.f, 0.f, 0.f};

    const u16* bP0;
    const u16* bP1;
    int dOff[4];
    float4 wv;

    auto setupSub = [&](int sn) {
        const u16* Bb = Wt + (size_t)sn * CDIM * CDIM;
        bP0 = Bb + (size_t)(n0 + rB0) * CDIM + cB0 * 8;
        bP1 = Bb + (size_t)(n0 + rB1) * CDIM + cB1 * 8;
        int4 iv = idxz[sn * 4096 + m0 + rA];
        wv = w4z[sn * 4096 + m0 + rA];
        dOff[0] = (iv.x + cA * 8) * 2;
        dOff[1] = (iv.y + cA * 8) * 2;
        dOff[2] = (iv.z + cA * 8) * 2;
        dOff[3] = (iv.w + cA * 8) * 2;
    };

    auto blend4 = [&](const uint4* L) -> uint4 {
        auto bl = [&](unsigned a, unsigned b, unsigned c2, unsigned d) -> unsigned {
            float lo = fmaf(wv.x, lof(a), fmaf(wv.y, lof(b), fmaf(wv.z, lof(c2), wv.w * lof(d))));
            float hi = fmaf(wv.x, hif(a), fmaf(wv.y, hif(b), fmaf(wv.z, hif(c2), wv.w * hif(d))));
            // dst = (hi & 0xffff0000) | (lo >> 16) in one v_perm_b32
            return __builtin_amdgcn_perm(__float_as_uint(hi), __float_as_uint(lo), 0x07060302u);
        };
        uint4 o;
        o.x = bl(L[0].x, L[1].x, L[2].x, L[3].x);
        o.y = bl(L[0].y, L[1].y, L[2].y, L[3].y);
        o.z = bl(L[0].z, L[1].z, L[2].z, L[3].z);
        o.w = bl(L[0].w, L[1].w, L[2].w, L[3].w);
        return o;
    };

    setupSub(0);
    int stagedSub = 0;

    {   // prologue: stage step 0 into buf 0
        uint4 L[4];
#pragma unroll
        for (int k = 0; k < 4; k++)
            L[k] = *(const uint4*)((const char*)Az + dOff[k]);
        gl16(bP0, &Bs[0][wid * 512]);
        gl16(bP1, &Bs[0][4096 + wid * 512]);
        uint4 o = blend4(L);
        *(uint4*)&As[0][t * 8] = o;
    }

    for (int s = 0; s < 216; ++s) {
        const int cur = s & 1;
        const int nxt = cur ^ 1;
        __syncthreads();
        const bool hasN = (s + 1 < 216);
        uint4 L[4];
        if (hasN) {
            int kn = (s + 1) - stagedSub * 24;
            if (kn == 24) { setupSub(++stagedSub); kn = 0; }
            const int cb = kn * 64;  // byte advance along K
#pragma unroll
            for (int k = 0; k < 4; k++)
                L[k] = *(const uint4*)((const char*)Az + dOff[k] + cb);
            gl16(bP0 + kn * 32, &Bs[nxt][wid * 512]);
            gl16(bP1 + kn * 32, &Bs[nxt][4096 + wid * 512]);
        }
        short8 af[4];
#pragma unroll
        for (int i = 0; i < 4; i++) {
            int rr = wrow + i * 16 + lm;
            af[i] = *(const short8*)&As[cur][rr * 32 + ((quad ^ swz(rr)) * 8)];
        }
#pragma unroll
        for (int j = 0; j < 4; j++) {
            int rr = wcol + j * 16 + lm;
            short8 bf = *(const short8*)&Bs[cur][rr * 32 + ((quad ^ swz(rr)) * 8)];
#pragma unroll
            for (int i = 0; i < 4; i++)
                acc[i][j] = __builtin_amdgcn_mfma_f32_16x16x32_bf16(af[i], bf, acc[i][j], 0, 0, 0);
        }
        if (hasN) {
            uint4 o = blend4(L);
            *(uint4*)&As[nxt][t * 8] = o;
        }
    }

    // ---- epilogue: store + fused BN partial stats ----
    if (t < 256) { r1[t] = 0.f; r2[t] = 0.f; }
    __syncthreads();
    u16* outz = outb + (size_t)z * HW * CDIM;
#pragma unroll
    for (int j = 0; j < 4; j++) {
        int gc = n0 + wcol + j * 16 + lm;
        float bv = bias[gc];
        float s1 = 0.f, s2 = 0.f;
#pragma unroll
        for (int i = 0; i < 4; i++)
#pragma unroll
            for (int r = 0; r < 4; r++) {
                int gr = m0 + wrow + i * 16 + quad * 4 + r;
                float v = acc[i][j][r] + bv;
                outz[(size_t)gr * CDIM + gc] = f2bf(v);
                s1 += v;
                s2 += v * v;
            }
        atomicAdd(&r1[wcol + j * 16 + lm], s1);
        atomicAdd(&r2[wcol + j * 16 + lm], s2);
    }
    __syncthreads();
    if (t < 256) {
        atomicAdd(&pb1[z * 768 + n0 + t], r1[t]);
        atomicAdd(&pb2[z * 768 + n0 + t], r2[t]);
    }
}

// ---------------------------------------------------------------- prep kernels
struct Ptr5 { const float* p[5]; };

__global__ void k_prep_xpad(Ptr5 xs, u16* __restrict__ xpad) {
    int z = blockIdx.y;
    int pidx = blockIdx.x;
    int ph = pidx / 66, pw = pidx - ph * 66;
    int e0 = threadIdx.x * 4;
    u16* d = xpad + ((size_t)z * PPIX + pidx) * CDIM + e0;
    if (ph == 0 || ph == 65 || pw == 0 || pw == 65) {
        *(uint2*)d = make_uint2(0, 0);
        return;
    }
    const float* s = xs.p[z] + ((size_t)((ph - 1) * 64 + (pw - 1))) * CDIM + e0;
    float4 v = *(const float4*)s;
    u16 o[4] = {f2bf(v.x), f2bf(v.y), f2bf(v.z), f2bf(v.w)};
    *(uint2*)d = *(uint2*)o;
}

__global__ void k_prep_wt(const float* __restrict__ cw, u16* __restrict__ Wt) {
    int o = blockIdx.x;
    for (int c = threadIdx.x; c < 768; c += 256) {
        const float* s = cw + ((size_t)o * 768 + c) * 9;
#pragma unroll
        for (int k = 0; k < 9; k++)
            Wt[(size_t)k * 768 * 768 + (size_t)o * 768 + c] = f2bf(s[k]);
    }
}

struct WbP { const float* src[9]; u16* dst[9]; int n[9]; };

__global__ void k_prep_wb(WbP wp) {
    int m = blockIdx.y;
    int i = (blockIdx.x * 256 + threadIdx.x) * 4;
    if (i >= wp.n[m]) return;
    float4 v = *(const float4*)(wp.src[m] + i);
    u16* d = wp.dst[m] + i;
    d[0] = f2bf(v.x); d[1] = f2bf(v.y); d[2] = f2bf(v.z); d[3] = f2bf(v.w);
}

// ---------------------------------------------------------------- offset / mask sample prep
__device__ __forceinline__ int cidx(int y, int x) {
    int yc = min(max(y, 0), 63), xc = min(max(x, 0), 63);
    return ((yc + 1) * 66 + (xc + 1)) * CDIM;
}
__device__ __forceinline__ float cval(int y, int x) {
    return (y >= 0 && y < 64 && x >= 0 && x < 64) ? 1.f : 0.f;
}

// Reads the 3 tap-group partials + folded bias directly (omsum fused in).
// Softmax over the 9 logits of the ORIGINAL pixel P (torch raw-reshape
// semantics: mask flat index k*4096+p belongs to pixel (k*4096+p)/9, slot %9).
// Block 0 zeroes pb1/pb2 for k_gdef's fused BN stats (stream order).
__global__ void k_offmask2(const float* __restrict__ pOM, const float* __restrict__ bb,
                           float* __restrict__ pb1, float* __restrict__ pb2,
                           int4* __restrict__ idx4o, float4* __restrict__ w4o) {
    if (blockIdx.x == 0) {
        for (int i = threadIdx.x; i < 3840; i += 256) { pb1[i] = 0.f; pb2[i] = 0.f; }
    }
    int id = blockIdx.x * 256 + threadIdx.x;
    int z = id / 36864, r = id % 36864, k = r >> 12, p = r & 4095;
    const size_t ps = (size_t)HW * 32;   // part stride
    const float* P0 = pOM + (size_t)z * 3 * ps + (size_t)p * 32;
    float dy = P0[2 * k] + P0[ps + 2 * k] + P0[2 * ps + 2 * k] + bb[2 * k];
    float dx = P0[2 * k + 1] + P0[ps + 2 * k + 1] + P0[2 * ps + 2 * k + 1] + bb[2 * k + 1];
    int flat = k * 4096 + p;
    int P = flat / 9, jj = flat - P * 9;
    const float* Q0 = pOM + (size_t)z * 3 * ps + (size_t)P * 32 + 18;
    float l[9], mx = -1e30f;
#pragma unroll
    for (int i2 = 0; i2 < 9; i2++) {
        l[i2] = Q0[i2] + Q0[ps + i2] + Q0[2 * ps + i2] + bb[18 + i2];
        mx = fmaxf(mx, l[i2]);
    }
    float sum = 0.f;
#pragma unroll
    for (int i2 = 0; i2 < 9; i2++) sum += expf(l[i2] - mx);
    float mk = expf(l[jj] - mx) / sum;
    int h = p >> 6, w = p & 63;
    float py = (float)(h - 1 + k / 3) + dy;
    float px = (float)(w - 1 + k % 3) + dx;
    float y0f = floorf(py), x0f = floorf(px);
    int y0 = (int)y0f, x0 = (int)x0f;
    float wy1 = py - y0f, wx1 = px - x0f, wy0 = 1.f - wy1, wx0 = 1.f - wx1;
    idx4o[id] = make_int4(cidx(y0, x0), cidx(y0, x0 + 1), cidx(y0 + 1, x0), cidx(y0 + 1, x0 + 1));
    w4o[id] = make_float4(wy0 * wx0 * cval(y0, x0) * mk, wy0 * wx1 * cval(y0, x0 + 1) * mk,
                          wy1 * wx0 * cval(y0 + 1, x0) * mk, wy1 * wx1 * cval(y0 + 1, x0 + 1) * mk);
}

// ---------------------------------------------------------------- batchnorm
// stats now fused into k_gdef epilogue (pb1/pb2 = full sums over 4096 rows).
__global__ void k_bnfinal(const float* __restrict__ pb1, const float* __restrict__ pb2,
                          float* __restrict__ mu, float* __restrict__ rs) {
    int i = blockIdx.x * 256 + threadIdx.x;
    if (i >= 3840) return;
    float a = pb1[i];
    float b = pb2[i];
    float m = a / 4096.f;
    float var = b / 4096.f - m * m;
    mu[i] = m;
    rs[i] = rsqrtf(var + 1e-5f);
}

__global__ void k_bnapply(const u16* __restrict__ dout, const float* __restrict__ mu,
                          const float* __restrict__ rs, const float* __restrict__ g,
                          const float* __restrict__ b, u16* __restrict__ blk) {
    size_t i = ((size_t)blockIdx.x * 256 + threadIdx.x) * 8;
    int c = (int)(i % CDIM);
    int z = (int)(i / ((size_t)HW * CDIM));
    const float* muz = mu + z * 768;
    const float* rsz = rs + z * 768;
    uint4 in = *(const uint4*)(dout + i);
    const u16* u = (const u16*)&in;
    u16 o[8];
#pragma unroll
    for (int e = 0; e < 8; e++) {
        int ce = c + e;
        float v = (bf2f(u[e]) - muz[ce]) * rsz[ce] * g[ce] + b[ce];
        o[e] = f2bf(fmaxf(v, 0.f));
    }
    *(uint4*)(blk + i) = *(uint4*)o;
}

// ---------------------------------------------------------------- CAM
// k_q also zeroes xq (block 0) for k_xq's atomics (stream order).
__global__ void k_q(const float* __restrict__ X, const float* __restrict__ chq,
                    float* __restrict__ q, float* __restrict__ xq) {
    if (blockIdx.x == 0) {
        for (int c = threadIdx.x; c < 768; c += 256) xq[c] = 0.f;
    }
    int wid = threadIdx.x >> 6, lane = threadIdx.x & 63;
    int p = blockIdx.x * 4 + wid;
    const float* xr = X + (size_t)p * CDIM;
    float s = 0.f;
#pragma unroll
    for (int j = 0; j < 12; j++) s += xr[lane + 64 * j] * chq[lane + 64 * j];
#pragma unroll
    for (int o = 32; o > 0; o >>= 1) s += __shfl_xor(s, o, 64);
    if (lane == 0) q[p] = s;
}

// fused softmax(4096) + xq accumulation: each block recomputes max/denominator
// from qv (16KB, L2-hot, identical reduction order to old k_soft4096).
__global__ void k_xq(const float* __restrict__ X, const float* __restrict__ qv,
                     float* __restrict__ xq) {
    __shared__ float red[8];
    __shared__ float sq[128];
    int tid = threadIdx.x, lane = tid & 63, wid = tid >> 6;
    float m = -1e30f;
    for (int i = tid; i < 4096; i += 256) m = fmaxf(m, qv[i]);
    for (int o = 32; o > 0; o >>= 1) m = fmaxf(m, __shfl_xor(m, o, 64));
    if (lane == 0) red[wid] = m;
    __syncthreads();
    float bm = fmaxf(fmaxf(red[0], red[1]), fmaxf(red[2], red[3]));
    float s = 0.f;
    for (int i = tid; i < 4096; i += 256) s += expf(qv[i] - bm);
    for (int o = 32; o > 0; o >>= 1) s += __shfl_xor(s, o, 64);
    if (lane == 0) red[4 + wid] = s;
    __syncthreads();
    float inv = 1.f / (red[4] + red[5] + red[6] + red[7]);
    int p0 = blockIdx.x * 128;
    if (tid < 128) sq[tid] = expf(qv[p0 + tid] - bm) * inv;
    __syncthreads();
    for (int c = tid; c < 768; c += 256) {
        float a = 0.f;
        for (int p = 0; p < 128; p++) a += sq[p] * X[(size_t)(p0 + p) * CDIM + c];
        atomicAdd(&xq[c], a);
    }
}

// wvq[o] = chv[o][:] . xq   (384 rows, wave per row)
__global__ void k_gemv384(const float* __restrict__ chv, const float* __restrict__ xq,
                          float* __restrict__ wvq) {
    int wid = threadIdx.x >> 6, lane = threadIdx.x & 63;
    int o = blockIdx.x * 4 + wid;
    const float* r = chv + (size_t)o * 768;
    float s = 0.f;
#pragma unroll
    for (int j = 0; j < 12; j++) s += r[lane + 64 * j] * xq[lane + 64 * j];
#pragma unroll
    for (int off = 32; off > 0; off >>= 1) s += __shfl_xor(s, off, 64);
    if (lane == 0) wvq[o] = s;
}

// wzv[c] = chz[c][:] . wvq   (768 rows, wave per row)
__global__ void k_gemv768(const float* __restrict__ chz, const float* __restrict__ wvq,
                          float* __restrict__ wzv) {
    int wid = threadIdx.x >> 6, lane = threadIdx.x & 63;
    int c = blockIdx.x * 4 + wid;
    const float* r = chz + (size_t)c * 384;
    float s = 0.f;
#pragma unroll
    for (int j = 0; j < 6; j++) s += r[lane + 64 * j] * wvq[lane + 64 * j];
#pragma unroll
    for (int off = 32; off > 0; off >>= 1) s += __shfl_xor(s, off, 64);
    if (lane == 0) wzv[c] = s;
}

// LN(768) + sigmoid -> sgate
__global__ void k_lngate(const float* __restrict__ wzv, const float* __restrict__ lng,
                         const float* __restrict__ lnb, float* __restrict__ sgate) {
    __shared__ float red[8];
    int tid = threadIdx.x, lane = tid & 63, wid = tid >> 6;
    float a = wzv[tid], b = wzv[tid + 256], c = wzv[tid + 512];
    float s1 = a + b + c, s2 = a * a + b * b + c * c;
    for (int o = 32; o > 0; o >>= 1) { s1 += __shfl_xor(s1, o, 64); s2 += __shfl_xor(s2, o, 64); }
    if (lane == 0) { red[wid] = s1; red[4 + wid] = s2; }
    __syncthreads();
    s1 = red[0] + red[1] + red[2] + red[3];
    s2 = red[4] + red[5] + red[6] + red[7];
    float mean = s1 / 768.f, var = s2 / 768.f - mean * mean, rstd = rsqrtf(var + 1e-5f);
    for (int cc = tid; cc < 768; cc += 256) {
        float tv = (wzv[cc] - mean) * rstd * lng[cc] + lnb[cc];
        sgate[cc] = 1.f / (1.f + expf(-tv));
    }
}

__global__ void k_xatt(const float* __restrict__ X, const float* __restrict__ sgate,
                       u16* __restrict__ xatt) {
    size_t i = ((size_t)blockIdx.x * 256 + threadIdx.x) * 4;
    int c = (int)(i % CDIM);
    float4 v = *(const float4*)(X + i);
    u16 o[4] = {f2bf(v.x * sgate[c]), f2bf(v.y * sgate[c + 1]),
                f2bf(v.z * sgate[c + 2]), f2bf(v.w * sgate[c + 3])};
    *(uint2*)(xatt + i) = *(uint2*)o;
}

// column max over P2[4096][384] — 24 blocks x 16 cols, coalesced
__global__ void k_colmax24(const float* __restrict__ P2, float* __restrict__ m2) {
    __shared__ float red[16][17];
    int col = blockIdx.x * 16 + threadIdx.x;
    float m = -1e30f;
    for (int p = threadIdx.y; p < 4096; p += 16) m = fmaxf(m, P2[(size_t)p * 384 + col]);
    red[threadIdx.y][threadIdx.x] = m;
    __syncthreads();
    if (threadIdx.y == 0) {
        for (int y = 1; y < 16; y++) m = fmaxf(m, red[y][threadIdx.x]);
        m2[col] = m;
    }
}

// sv[c] = sum_o softmax384(m2)[o] * spv[o][c] — sm384 fused (recomputed per block)
__global__ void k_sv(const float* __restrict__ m2, const float* __restrict__ spv,
                     float* __restrict__ sv) {
    __shared__ float part[4][64];
    __shared__ float red[8];
    __shared__ float sq2l[384];
    int tid = threadIdx.x, lane = tid & 63, wid = tid >> 6;
    float x1 = m2[tid];
    float x2 = (tid < 128) ? m2[tid + 256] : -1e30f;
    float m = fmaxf(x1, x2);
    for (int o = 32; o > 0; o >>= 1) m = fmaxf(m, __shfl_xor(m, o, 64));
    if (lane == 0) red[wid] = m;
    __syncthreads();
    m = fmaxf(fmaxf(red[0], red[1]), fmaxf(red[2], red[3]));
    float e1 = expf(x1 - m);
    float e2 = (tid < 128) ? expf(x2 - m) : 0.f;
    float s = e1 + e2;
    for (int o = 32; o > 0; o >>= 1) s += __shfl_xor(s, o, 64);
    if (lane == 0) red[4 + wid] = s;
    __syncthreads();
    float inv = 1.f / (red[4] + red[5] + red[6] + red[7]);
    sq2l[tid] = e1 * inv;
    if (tid < 128) sq2l[tid + 256] = e2 * inv;
    __syncthreads();
    int c = blockIdx.x * 64 + (tid & 63);
    int seg = tid >> 6;
    float a = 0.f;
    for (int o = seg * 96; o < seg * 96 + 96; o++) a += sq2l[o] * spv[(size_t)o * 768 + c];
    part[seg][tid & 63] = a;
    __syncthreads();
    if (seg == 0) sv[c] = part[0][tid] + part[1][tid] + part[2][tid] + part[3][tid];
}

__global__ void k_final(const float* __restrict__ X, const float* __restrict__ x5,
                        const float* __restrict__ sgate, const float* __restrict__ sv,
                        const float* __restrict__ ng, const float* __restrict__ nb,
                        float* __restrict__ out) {
    int wid = threadIdx.x >> 6, lane = threadIdx.x & 63;
    int p = blockIdx.x * 4 + wid;
    const float* xr = X + (size_t)p * CDIM;
    const float* x5r = x5 + (size_t)p * CDIM;
    float xa[12];
    float d = 0.f;
#pragma unroll
    for (int j = 0; j < 12; j++) {
        int c = lane + 64 * j;
        float a = xr[c] * sgate[c];
        xa[j] = a;
        d += sv[c] * a;
    }
#pragma unroll
    for (int o = 32; o > 0; o >>= 1) d += __shfl_xor(d, o, 64);
    float wz2 = 1.f / (1.f + expf(-d));
    float s1 = 0.f, s2 = 0.f;
#pragma unroll
    for (int j = 0; j < 12; j++) {
        int c = lane + 64 * j;
        float y = wz2 * xa[j] + xr[c] + x5r[c];
        xa[j] = y;
        s1 += y; s2 += y * y;
    }
#pragma unroll
    for (int o = 32; o > 0; o >>= 1) { s1 += __shfl_xor(s1, o, 64); s2 += __shfl_xor(s2, o, 64); }
    float mean = s1 / 768.f, var = s2 / 768.f - mean * mean, rstd = rsqrtf(var + 1e-5f);
#pragma unroll
    for (int j = 0; j < 12; j++) {
        int c = lane + 64 * j;
        out[(size_t)p * CDIM + c] = (xa[j] - mean) * rstd * ng[c] + nb[c];
    }
}

// ---------------------------------------------------------------- launch
extern "C" void kernel_launch(void* const* d_in, const int* in_sizes, int n_in,
                              void* d_out, int out_size, void* d_ws, size_t ws_size,
                              hipStream_t stream) {
    const float* xin[5];
    for (int i = 0; i < 5; i++) xin[i] = (const float*)d_in[i];
    const float* conv_w = (const float*)d_in[5];
    const float* conv_b = (const float*)d_in[6];
    const float* off_w = (const float*)d_in[7];
    const float* off_b = (const float*)d_in[8];
    const float* msk_w = (const float*)d_in[9];
    const float* msk_b = (const float*)d_in[10];
    const float* bn_g = (const float*)d_in[11];
    const float* bn_b = (const float*)d_in[12];
    const float* chq_w = (const float*)d_in[13];
    const float* chv_w = (const float*)d_in[14];
    const float* chz_w = (const float*)d_in[15];
    const float* ln_g = (const float*)d_in[16];
    const float* ln_b = (const float*)d_in[17];
    const float* spq_w = (const float*)d_in[18];
    const float* spv_w = (const float*)d_in[19];
    const float* wsrc[8];
    for (int i = 0; i < 8; i++) wsrc[i] = (const float*)d_in[20 + i];
    const float* norm_g = (const float*)d_in[28];
    const float* norm_b = (const float*)d_in[29];
    float* out = (float*)d_out;

    char* wsb = (char*)d_ws;
    size_t off = 0;
    auto take = [&](size_t n) -> char* {
        char* p = wsb + off;
        off = (off + n + 255) & ~(size_t)255;
        return p;
    };
    u16* xpad = (u16*)take(5ll * PPIX * CDIM * 2);
    u16* Wt = (u16*)take(9ll * CDIM * CDIM * 2);
    u16* omblk = (u16*)take(5ll * HW * CDIM * 2);
    int4* idx4 = (int4*)take(5ll * 9 * 4096 * 16);
    float4* w4 = (float4*)take(5ll * 9 * 4096 * 16);
    u16* dout = (u16*)take(5ll * HW * CDIM * 2);
    u16* wb = (u16*)take(1790ll * 768 * 2);
    u16* OMW = (u16*)take(9ll * 32 * 768 * 2);
    float* bb = (float*)take(32 * 4);
    float* pOM = (float*)take(5ll * 3 * HW * 32 * 4);
    float* Xcat = (float*)take((size_t)HW * CDIM * 4);
    float* mu = (float*)take(5 * 768 * 4);
    float* rs = (float*)take(5 * 768 * 4);
    float* pb1 = (float*)take(5 * 768 * 4);
    float* pb2 = (float*)take(5 * 768 * 4);
    float* qv = (float*)take(4096 * 4);
    float* xq = (float*)take(768 * 4);
    float* wvq = (float*)take(384 * 4);
    float* wzv = (float*)take(768 * 4);
    float* sgate = (float*)take(768 * 4);
    float* m2 = (float*)take(384 * 4);
    float* sv = (float*)take(768 * 4);
    u16* xatt = dout;
    float* P2 = (float*)((char*)dout + 8388608);
    u16* blk = omblk;
    (void)ws_size; (void)in_sizes; (void)n_in; (void)out_size;

    int rows[9] = {30, 100, 150, 150, 220, 220, 268, 268, 384};
    int roff[9]; int acc = 0;
    for (int i = 0; i < 9; i++) { roff[i] = acc; acc += rows[i]; }
    u16* spqb = wb + (size_t)roff[8] * 768;

    WbP wp;
    for (int i = 0; i < 8; i++) { wp.src[i] = wsrc[i]; wp.dst[i] = wb + (size_t)roff[i] * 768; wp.n[i] = rows[i] * 768; }
    wp.src[8] = spq_w; wp.dst[8] = spqb; wp.n[8] = rows[8] * 768;

    ProjP pp;
    pp.b1[0] = wb + (size_t)roff[0] * 768; pp.b2[0] = nullptr;
    pp.b1[1] = wb + (size_t)roff[1] * 768; pp.b2[1] = nullptr;
    pp.b1[2] = wb + (size_t)roff[2] * 768; pp.b2[2] = wb + (size_t)roff[3] * 768;
    pp.b1[3] = wb + (size_t)roff[4] * 768; pp.b2[3] = wb + (size_t)roff[5] * 768;
    pp.b1[4] = wb + (size_t)roff[6] * 768; pp.b2[4] = wb + (size_t)roff[7] * 768;
    int chs[5] = {30, 100, 150, 220, 268};
    int cof[5] = {0, 30, 130, 280, 500};
    for (int i = 0; i < 5; i++) { pp.ch[i] = chs[i]; pp.choff[i] = cof[i]; }
    ProjP pdum = {};

    Ptr5 xs;
    for (int i = 0; i < 5; i++) xs.p[i] = xin[i];

    // ---- prep ----
    k_prep_xpad<<<dim3(PPIX, 5), 192, 0, stream>>>(xs, xpad);
    k_prep_wt<<<dim3(768), 256, 0, stream>>>(conv_w, Wt);
    k_prep_wb<<<dim3(288, 9), 256, 0, stream>>>(wp);
    k_fold<<<dim3(3, 9, 3), 256, 0, stream>>>(Wt, off_w, msk_w, OMW);
    k_bias27<<<dim3(7), 256, 0, stream>>>(off_w, msk_w, conv_b, off_b, msk_b, bb);

    // ---- heavy path ----
    k_convOM<<<dim3(32, 3, 5), 512, 0, stream>>>(xpad, OMW, pOM);
    k_offmask2<<<dim3(720), 256, 0, stream>>>(pOM, bb, pb1, pb2, idx4, w4);
    k_gdef<<<dim3(480), 512, 0, stream>>>(xpad, Wt, idx4, w4, conv_b, dout, pb1, pb2);
    k_bnfinal<<<dim3(15), 256, 0, stream>>>(pb1, pb2, mu, rs);
    k_bnapply<<<dim3(7680), 256, 0, stream>>>(dout, mu, rs, bn_g, bn_b, blk);
    k_gemm128<G_PROJ><<<dim3(32, 3, 5), 256, 0, stream>>>(xpad, blk, nullptr, nullptr,
                                                          nullptr, Xcat, pp);

    // ---- CAM ----
    k_q<<<dim3(1024), 256, 0, stream>>>(Xcat, chq_w, qv, xq);
    k_xq<<<dim3(32), 256, 0, stream>>>(Xcat, qv, xq);
    k_gemv384<<<dim3(96), 256, 0, stream>>>(chv_w, xq, wvq);
    k_gemv768<<<dim3(192), 256, 0, stream>>>(chz_w, wvq, wzv);
    k_lngate<<<dim3(1), 256, 0, stream>>>(wzv, ln_g, ln_b, sgate);
    k_xatt<<<dim3(3072), 256, 0, stream>>>(Xcat, sgate, xatt);
    k_gemm128<G_SPAT><<<dim3(32, 3, 1), 256, 0, stream>>>(xpad, xatt, spqb, nullptr,
                                                          nullptr, P2, pdum);
    k_colmax24<<<dim3(24), dim3(16, 16), 0, stream>>>(P2, m2);
    k_sv<<<dim3(12), 256, 0, stream>>>(m2, spv_w, sv);

    // ---- residual + final LayerNorm ----
    k_final<<<dim3(1024), 256, 0, stream>>>(Xcat, xin[4], sgate, sv, norm_g, norm_b, out);
}